// Round 5
// baseline (5962.460 us; speedup 1.0000x reference)
//
#include <hip/hip_runtime.h>
#include <math.h>

#define B_TOT 16384
#define CELLS 36
#define YDIM 252       // 7*6*6
#define FEATY 256      // padded y-only feature block (252 -> 256)
#define FEATS 192      // padded static block (36 cond + 128 emb = 164 -> 192)
#define HDIM 2048
#define EMB_DIM 128
#define KSTEPS 50

typedef unsigned short ushort_t;
typedef __attribute__((ext_vector_type(8))) short short8v;
typedef __attribute__((ext_vector_type(4))) float float4v;

__device__ __forceinline__ float clip01(float x){ return fminf(fmaxf(x, 0.f), 1.f); }
__device__ __forceinline__ float tanh_fast(float u){
  float e = __expf(2.f * u);
  return 1.f - 2.f / (e + 1.f);
}
__device__ __forceinline__ float gelu_f(float x){
  float u = 0.7978845608028654f * (x + 0.044715f * x * x * x);
  return 0.5f * x * (1.f + tanh_fast(u));
}
__device__ __forceinline__ float dgelu_f(float x){
  float x2 = x * x;
  float u = 0.7978845608028654f * (x + 0.044715f * x2 * x);
  float t = tanh_fast(u);
  return 0.5f * (1.f + t) + 0.5f * x * (1.f - t * t) * 0.7978845608028654f * (1.f + 0.134145f * x2);
}
__device__ __forceinline__ float clipmask(float y){ return (y == 0.f || y == 1.f) ? 0.5f : 1.f; }
__device__ __forceinline__ ushort_t f2bf(float x){
  union { float f; unsigned u; } v; v.f = x;
  unsigned r = v.u + 0x7fffu + ((v.u >> 16) & 1u);
  return (ushort_t)(r >> 16);
}
__device__ __forceinline__ float bf2f(ushort_t h){
  union { unsigned u; float f; } v; v.u = ((unsigned)h) << 16; return v.f;
}
__device__ __forceinline__ void load_lds16(const void* g, void* l){
  __builtin_amdgcn_global_load_lds((const __attribute__((address_space(1))) unsigned int*)g,
                                   (__attribute__((address_space(3))) unsigned int*)l, 16, 0, 0);
}
// m204 bijective XCD swizzle
__device__ __forceinline__ void xcd_swizzle(int GX, int GY, int& bx, int& by){
  int nwg = GX * GY;
  int orig = by * GX + bx;
  int q = nwg >> 3, r = nwg & 7;
  int xcd = orig & 7, loc = orig >> 3;
  int lin = (xcd < r ? xcd * (q + 1) : r * (q + 1) + (xcd - r) * q) + loc;
  bx = lin % GX; by = lin / GX;
}

// ---------------- small kernels ----------------
__global__ void k_zero_acc(double* acc){ acc[0] = 0.0; acc[1] = 0.0; acc[2] = 0.0; }

__global__ void k_sigma(const int* __restrict__ k_idx, float* __restrict__ sigma_b){
  int b = blockIdx.x * blockDim.x + threadIdx.x;
  if (b >= B_TOT) return;
  int i = (KSTEPS - 1) - k_idx[b];
  float t = (float)i / (float)(KSTEPS - 1);
  float ang = (1.f - t) * 1.57079632679489662f;
  float c = cosf(ang);
  sigma_b[b] = 0.01f + 0.94f * c * c;
}

__global__ void k_cast(const float* __restrict__ in, ushort_t* __restrict__ out, int n){
  int gid = blockIdx.x * blockDim.x + threadIdx.x;
  if (gid < n) out[gid] = f2bf(in[gid]);
}
// W1yT[h][c] = W1[c][h] for c<252 (padded to 256)
__global__ void k_w1yt(const float* __restrict__ W1, ushort_t* __restrict__ W1yT){
  int gid = blockIdx.x * blockDim.x + threadIdx.x;
  if (gid >= HDIM * FEATY) return;
  int h = gid >> 8, c = gid & 255;
  W1yT[gid] = (c < YDIM) ? f2bf(W1[(size_t)c * HDIM + h]) : (ushort_t)0;
}
// W1sT[h][c] = W1[252+c][h] for c<164 (padded to 192)
__global__ void k_w1st(const float* __restrict__ W1, ushort_t* __restrict__ W1sT){
  int gid = blockIdx.x * blockDim.x + threadIdx.x;
  if (gid >= HDIM * FEATS) return;
  int h = gid / FEATS, c = gid - h * FEATS;
  W1sT[gid] = (c < CELLS + EMB_DIM) ? f2bf(W1[(size_t)(YDIM + c) * HDIM + h]) : (ushort_t)0;
}
// tiled transpose: W2T[n][k] = W2[k][n]
__global__ __launch_bounds__(256) void k_w2t(const float* __restrict__ W2, ushort_t* __restrict__ W2T){
  __shared__ float tile[32][33];
  int x0 = blockIdx.x << 5, y0 = blockIdx.y << 5;
  int tx = threadIdx.x & 31, ty = threadIdx.x >> 5;
#pragma unroll
  for (int i = 0; i < 4; ++i)
    tile[ty + i * 8][tx] = W2[(size_t)(y0 + ty + i * 8) * HDIM + (x0 + tx)];
  __syncthreads();
#pragma unroll
  for (int i = 0; i < 4; ++i)
    W2T[(size_t)(x0 + ty + i * 8) * HDIM + (y0 + tx)] = f2bf(tile[tx][ty + i * 8]);
}

// static features (per chunk): statf[i][c] = [cond(36) | emb(128) | 0-pad]
__global__ void k_statf(const float* __restrict__ cond, const float* __restrict__ k_emb,
                        const int* __restrict__ k_idx, ushort_t* __restrict__ statf, int Mc){
  int gid = blockIdx.x * blockDim.x + threadIdx.x;
  if (gid >= Mc * FEATS) return;
  int i = gid / FEATS, c = gid - i * FEATS;
  float v = 0.f;
  if (c < CELLS) v = cond[(size_t)i * CELLS + c];
  else if (c < CELLS + EMB_DIM) v = k_emb[(size_t)k_idx[i] * EMB_DIM + (c - CELLS)];
  statf[gid] = f2bf(v);
}
// zero feat pad cols 252..255 (once per launch; no later writer touches them)
__global__ void k_zfp(ushort_t* __restrict__ feat, int Mc){
  int gid = blockIdx.x * blockDim.x + threadIdx.x;
  if (gid >= Mc * 4) return;
  feat[(size_t)(gid >> 2) * FEATY + YDIM + (gid & 3)] = 0;
}

// noise + direct feat write (stride 256)
__global__ void k_noise(const float* __restrict__ y, const float* __restrict__ eps,
                        const float* __restrict__ sigma_b, float* __restrict__ out,
                        ushort_t* __restrict__ feat, int Mc){
  int gid = blockIdx.x * blockDim.x + threadIdx.x;
  if (gid >= Mc * CELLS) return;
  int i = gid / CELLS, cell = gid - i * CELLS;
  float sigma = sigma_b[i];
  float sq = sqrtf(fmaxf(1.f - sigma * sigma, 1e-8f));
  const float* yp = y + (size_t)i * YDIM + cell;
  const float* ep = eps + (size_t)i * YDIM + cell;
  float yh[7];
#pragma unroll
  for (int ch = 0; ch < 7; ++ch){
    float e = ep[ch * CELLS] * 0.1f;
    yh[ch] = clip01(sq * yp[ch * CELLS] + sigma * e);
  }
  bool filled = yh[0] > 0.5f;
  float s = 0.f;
#pragma unroll
  for (int ch = 1; ch < 7; ++ch) s += yh[ch];
  float* op = out + (size_t)i * YDIM + cell;
  ushort_t* fp = feat + (size_t)i * FEATY + cell;
  op[0] = yh[0];
  fp[0] = f2bf(yh[0]);
#pragma unroll
  for (int ch = 1; ch < 7; ++ch){
    float v = yh[ch];
    if (filled) v = v / (s + 1e-8f);
    v = clip01(v);
    op[ch * CELLS] = v;
    fp[ch * CELLS] = f2bf(v);
  }
}

// y_neg init + feat write
__global__ void k_makeneg(const float* __restrict__ y_true, const float* __restrict__ sel,
                          const float* __restrict__ rv, float* __restrict__ y_neg,
                          ushort_t* __restrict__ feat, int b0, int Mc){
  int w = (blockIdx.x * blockDim.x + threadIdx.x) >> 6;
  int lane = threadIdx.x & 63;
  if (w >= Mc) return;
  int b = b0 + w;
  int c = lane;
  bool active = c < CELLS;
  float yt0 = active ? y_true[(size_t)b * YDIM + c] : 0.f;
  bool filled = active && (yt0 > 0.5f);
  unsigned long long bal = __ballot(filled);
  int n_filled = __popcll(bal);
  int num_c = (int)floorf((float)n_filled * 0.3f);
  int idx = num_c - 1; if (idx < 0) idx = 0;
  float score = filled ? sel[(size_t)b * CELLS + c] : 2.0f;
  int cnt_lt = 0, cnt_le = 0;
  for (int l = 0; l < CELLS; ++l){
    float sv = __shfl(score, l);
    cnt_lt += (sv < score);
    cnt_le += (sv <= score);
  }
  float cand = (active && cnt_lt <= idx && idx < cnt_le) ? score : 3.4e38f;
  for (int off = 32; off; off >>= 1) cand = fminf(cand, __shfl_xor(cand, off));
  float thr = (num_c > 0) ? cand : -1.0f;
  bool corrupt = filled && (score <= thr);
  if (active){
    float rvv[6]; float rsum = 0.f;
#pragma unroll
    for (int ch = 0; ch < 6; ++ch){ rvv[ch] = rv[(size_t)b * (6 * CELLS) + ch * CELLS + c]; rsum += rvv[ch]; }
    float v0 = corrupt ? 0.f : yt0;
    y_neg[(size_t)w * YDIM + c] = v0;
    feat[(size_t)w * FEATY + c] = f2bf(clip01(v0));
#pragma unroll
    for (int ch = 0; ch < 6; ++ch){
      float val = corrupt ? rvv[ch] / rsum : y_true[(size_t)b * YDIM + (ch + 1) * CELLS + c];
      y_neg[(size_t)w * YDIM + (ch + 1) * CELLS + c] = val;
      feat[(size_t)w * FEATY + (ch + 1) * CELLS + c] = f2bf(clip01(val));
    }
  }
}

// e[i] = b3 + sum_x e_part[x][i]
__global__ void k_esum(const float* __restrict__ e_part, const float* __restrict__ b3,
                       float* __restrict__ e_out, int Mc){
  int i = blockIdx.x * blockDim.x + threadIdx.x;
  if (i >= Mc) return;
  float s = b3[0];
#pragma unroll
  for (int x = 0; x < 8; ++x) s += e_part[(size_t)x * Mc + i];
  e_out[i] = s;
}

__global__ __launch_bounds__(256) void k_contrast(const float* __restrict__ e_pos, const float* __restrict__ e_neg,
                           double* __restrict__ acc){
  double con = 0.0, reg = 0.0;
  for (int b = blockIdx.x * blockDim.x + threadIdx.x; b < B_TOT; b += gridDim.x * blockDim.x){
    float ep = e_pos[b], en = e_neg[b];
    float a = -ep, bb = -en;
    float m = fmaxf(a, bb);
    float lse = m + logf(expf(a - m) + expf(bb - m));
    con += (double)(ep + lse);
    reg += (double)ep + (double)en;
  }
  for (int off = 32; off; off >>= 1){ con += __shfl_down(con, off); reg += __shfl_down(reg, off); }
  __shared__ double wc[4], wr[4];
  int lane = threadIdx.x & 63, wid = threadIdx.x >> 6;
  if (lane == 0){ wc[wid] = con; wr[wid] = reg; }
  __syncthreads();
  if (threadIdx.x == 0){
    atomicAdd(&acc[1], (wc[0] + wc[1]) + (wc[2] + wc[3]));
    atomicAdd(&acc[2], (wr[0] + wr[1]) + (wr[2] + wr[3]));
  }
}

__global__ void k_finalize(const double* __restrict__ acc, float* __restrict__ out){
  double mse = acc[0] / (double)((long long)B_TOT * YDIM);
  double con = acc[1] / (double)B_TOT;
  double reg = acc[2] / (double)B_TOT;
  out[0] = (float)(mse + con + 0.01 * reg);
}

// ============ 256x256 8-phase GEMM (T2 swizzle + counted-slack vmcnt + setprio) ============
// C[M,N] = A[M,K]bf16 @ BT[N,K]bf16. 512 threads = 8 waves (2M x 4N). BK=64.
// LDS: linear dest (global_load_lds), XOR slot-swizzle applied to SOURCE col and READ col.
// modes: 0 z1: v += b1[col] + z1s[o]; outA=z1bf, outB=h1=gelu(v)
//        1 z2: v += b2[col]; outB?=dz2=W3*dgelu(v); e_part?=row-sums of gelu(v)*W3
//        2 dz1: v *= dgelu(z1bf[o]); outA
//        3 raw: outA = bf16(v)
#define G256_STAGE(dstBase, srcPtr, p0, k0) \
  _Pragma("unroll") \
  for (int i_ = 0; i_ < 4; ++i_){ \
    int rb_ = (i_ << 6) + (w << 3); \
    load_lds16((const char*)(srcPtr) + (((size_t)((p0) + rb_ + rsub)) * K + (k0) + csw) * 2, \
               (char*)(dstBase) + (rb_ << 7) + (lane << 4)); \
  }

__global__ __launch_bounds__(512, 1) void gemm256(
    const ushort_t* __restrict__ A, const ushort_t* __restrict__ BT,
    int N, int K, int mode,
    const float* __restrict__ bias, const float* __restrict__ W3,
    const ushort_t* __restrict__ z1s, const ushort_t* __restrict__ z1bf,
    ushort_t* __restrict__ outA, ushort_t* __restrict__ outB,
    float* __restrict__ e_part, int Mrows){
  __shared__ __align__(16) ushort_t As[2][256 * 64];
  __shared__ __align__(16) ushort_t Bs[2][256 * 64];
  __shared__ float e_lds[256];
  const int t = threadIdx.x, lane = t & 63, w = t >> 6;
  int bx = blockIdx.x, by = blockIdx.y;
  xcd_swizzle(gridDim.x, gridDim.y, bx, by);
  const int m0 = by << 8, n0 = bx << 8;
  const int fr = lane & 15, kg = lane >> 4;
  const int wr = (w >> 2) << 7, wc = (w & 3) << 6;
  const int rsub = lane >> 3;
  const int csw = ((lane & 7) ^ rsub) << 3;   // source col swizzle (ushorts)
  const int frs = fr & 7;                     // read-side swizzle bits
  const int NT = K >> 6;

  float4v acc[8][4];
#pragma unroll
  for (int m = 0; m < 8; ++m)
#pragma unroll
    for (int n = 0; n < 4; ++n) acc[m][n] = (float4v)0.f;

  G256_STAGE(&As[0][0], A, m0, 0);
  G256_STAGE(&Bs[0][0], BT, n0, 0);
  asm volatile("s_waitcnt vmcnt(0)" ::: "memory");
  __builtin_amdgcn_s_barrier();
  __builtin_amdgcn_sched_barrier(0);

  for (int kt = 0; kt < NT; ++kt){
    const int cur = kt & 1, nxt = cur ^ 1;
    const bool pf = (kt + 1 < NT);
    const int kn = (kt + 1) << 6;
    short8v bfr[4][2];
#pragma unroll
    for (int q = 0; q < 4; ++q){
      short8v afr[2][2];
      if (q == 0){
#pragma unroll
        for (int n_ = 0; n_ < 4; ++n_)
#pragma unroll
          for (int kk_ = 0; kk_ < 2; ++kk_)
            bfr[n_][kk_] = *(const short8v*)&Bs[cur][((wc + (n_ << 4) + fr) << 6) + ((((kk_ << 2) + kg) ^ frs) << 3)];
        if (pf){ G256_STAGE(&As[nxt][0], A, m0, kn); }
      } else if (q == 1){
        if (pf){ G256_STAGE(&Bs[nxt][0], BT, n0, kn); }
      }
#pragma unroll
      for (int i_ = 0; i_ < 2; ++i_)
#pragma unroll
        for (int kk_ = 0; kk_ < 2; ++kk_)
          afr[i_][kk_] = *(const short8v*)&As[cur][((wr + (((q << 1) + i_) << 4) + fr) << 6) + ((((kk_ << 2) + kg) ^ frs) << 3)];
      __builtin_amdgcn_sched_barrier(0);
      __builtin_amdgcn_s_barrier();
      asm volatile("s_waitcnt lgkmcnt(0)" ::: "memory");
      __builtin_amdgcn_sched_barrier(0);
      __builtin_amdgcn_s_setprio(1);
#pragma unroll
      for (int i = 0; i < 2; ++i)
#pragma unroll
        for (int n = 0; n < 4; ++n)
#pragma unroll
          for (int kk = 0; kk < 2; ++kk)
            acc[(q << 1) + i][n] =
                __builtin_amdgcn_mfma_f32_16x16x32_bf16(afr[i][kk], bfr[n][kk], acc[(q << 1) + i][n], 0, 0, 0);
      __builtin_amdgcn_s_setprio(0);
      __builtin_amdgcn_sched_barrier(0);
      if (q < 3) __builtin_amdgcn_s_barrier();
    }
    asm volatile("s_waitcnt vmcnt(0)" ::: "memory");
    __builtin_amdgcn_s_barrier();
    __builtin_amdgcn_sched_barrier(0);
  }

  const bool do_e = (mode == 1) && (e_part != nullptr);
  if (do_e){
    if (t < 256) e_lds[t] = 0.f;
    __syncthreads();
  }
#pragma unroll
  for (int m = 0; m < 8; ++m){
#pragma unroll
    for (int j = 0; j < 4; ++j){
      const int rloc = wr + (m << 4) + (kg << 2) + j;
      const int row = m0 + rloc;
      float pe = 0.f;
#pragma unroll
      for (int n = 0; n < 4; ++n){
        const int col = n0 + wc + (n << 4) + fr;
        float v = acc[m][n][j];
        const size_t o = (size_t)row * N + col;
        if (mode == 0){
          v += bias[col] + bf2f(z1s[o]);
          outA[o] = f2bf(v);
          outB[o] = f2bf(gelu_f(v));
        } else if (mode == 1){
          v += bias[col];
          if (outB) outB[o] = f2bf(W3[col] * dgelu_f(v));
          if (do_e) pe += gelu_f(v) * W3[col];
        } else if (mode == 2){
          v *= dgelu_f(bf2f(z1bf[o]));
          outA[o] = f2bf(v);
        } else {
          outA[o] = f2bf(v);
        }
      }
      if (do_e){
        pe += __shfl_xor(pe, 1); pe += __shfl_xor(pe, 2);
        pe += __shfl_xor(pe, 4); pe += __shfl_xor(pe, 8);
        if (fr == 0) atomicAdd(&e_lds[rloc], pe);
      }
    }
  }
  if (do_e){
    __syncthreads();
    if (t < 256) e_part[(size_t)bx * Mrows + m0 + t] = e_lds[t];
  }
}

// ============ dy GEMM (128x128, full K) with fused mse / refine-update epilogue ============
#define DY_STAGE(Asl_, Bsl_, k0_) do { \
  _Pragma("unroll") \
  for (int i_ = 0; i_ < 4; ++i_){ \
    int c_ = i_ * 4 + w; \
    int r_ = c_ * 8 + rsub; \
    load_lds16((const char*)A + ((size_t)(m0 + r_) * K + (k0_)) * 2 + cb, (char*)(Asl_) + c_ * 1024 + lane * 16); \
    load_lds16((const char*)BT + ((size_t)(n0 + r_) * K + (k0_)) * 2 + cb, (char*)(Bsl_) + c_ * 1024 + lane * 16); \
  } } while (0)

#define DY_MFMA(Asl_, Bsl_) do { \
  _Pragma("unroll") \
  for (int kk = 0; kk < 2; ++kk){ \
    int kb = kk * 32 + kg * 8; \
    short8v a[4], b[4]; \
    _Pragma("unroll") \
    for (int m = 0; m < 4; ++m) a[m] = *(const short8v*)&(Asl_)[(wr + m * 16 + fr) * 64 + kb]; \
    _Pragma("unroll") \
    for (int n = 0; n < 4; ++n) b[n] = *(const short8v*)&(Bsl_)[(wc + n * 16 + fr) * 64 + kb]; \
    _Pragma("unroll") \
    for (int m = 0; m < 4; ++m) \
      _Pragma("unroll") \
      for (int n = 0; n < 4; ++n) \
        acc[m][n] = __builtin_amdgcn_mfma_f32_16x16x32_bf16(a[m], b[n], acc[m][n], 0, 0, 0); \
  } } while (0)

__global__ __launch_bounds__(256) void gemm_dy2(
    const ushort_t* __restrict__ A, const ushort_t* __restrict__ BT, int upd,
    float* __restrict__ yneg, ushort_t* __restrict__ feat,
    const float* __restrict__ yhat, const float* __restrict__ y_true,
    const float* __restrict__ sigma_b, double* __restrict__ acc_g){
  __shared__ __align__(16) ushort_t Asl[2][128 * 64];
  __shared__ __align__(16) ushort_t Bsl[2][128 * 64];
  const int K = HDIM;
  const int t = threadIdx.x, lane = t & 63, w = t >> 6;
  int bx = blockIdx.x, by = blockIdx.y;
  xcd_swizzle(gridDim.x, gridDim.y, bx, by);
  const int m0 = by << 7, n0 = bx << 7;
  const int fr = lane & 15, kg = lane >> 4;
  const int rsub = lane >> 3;
  const int cb = (lane & 7) * 16;
  const int wr = (w >> 1) * 64, wc = (w & 1) * 64;

  float4v acc[4][4];
#pragma unroll
  for (int m = 0; m < 4; ++m)
#pragma unroll
    for (int n = 0; n < 4; ++n) acc[m][n] = (float4v)0.f;

  DY_STAGE(Asl[0], Bsl[0], 0);
  __syncthreads();
  int cur = 0;
  for (int k0 = 0; k0 < K; k0 += 64){
    if (k0 + 64 < K) DY_STAGE(Asl[cur ^ 1], Bsl[cur ^ 1], k0 + 64);
    DY_MFMA(Asl[cur], Bsl[cur]);
    __syncthreads();
    cur ^= 1;
  }

  double ms = 0.0;
#pragma unroll
  for (int m = 0; m < 4; ++m){
#pragma unroll
    for (int j = 0; j < 4; ++j){
      int row = m0 + wr + m * 16 + kg * 4 + j;
#pragma unroll
      for (int n = 0; n < 4; ++n){
        int col = n0 + wc + n * 16 + fr;
        if (col < YDIM){
          size_t o = (size_t)row * YDIM + col;
          float g = acc[m][n][j];
          if (upd){
            float y = yneg[o];
            y = clip01(y + 0.15f * g * clipmask(y));
            yneg[o] = y;
            feat[(size_t)row * FEATY + col] = f2bf(y);
          } else {
            float y = yhat[o];
            float score = g * clipmask(y);
            float tgt = (y - y_true[o]) / (sigma_b[row] + 1e-8f);
            float d = score - tgt;
            ms += (double)d * (double)d;
          }
        }
      }
    }
  }
  if (!upd){
    for (int off = 32; off; off >>= 1) ms += __shfl_down(ms, off);
    __shared__ double wsum[4];
    int wid = t >> 6;
    if ((t & 63) == 0) wsum[wid] = ms;
    __syncthreads();
    if (t == 0) atomicAdd(&acc_g[0], (wsum[0] + wsum[1]) + (wsum[2] + wsum[3]));
  }
}

// ---------------- host ----------------
static inline char* carve(char*& p, size_t bytes){
  char* r = p; p += (bytes + 255) & ~(size_t)255; return r;
}

extern "C" void kernel_launch(void* const* d_in, const int* in_sizes, int n_in,
                              void* d_out, int out_size, void* d_ws, size_t ws_size,
                              hipStream_t stream){
  (void)in_sizes; (void)n_in; (void)out_size;
  const float* y_true  = (const float*)d_in[0];
  const float* cond    = (const float*)d_in[1];
  const int*   k_idx   = (const int*)d_in[2];
  const float* eps_pos = (const float*)d_in[3];
  const float* eps_neg = (const float*)d_in[4];
  const float* sel     = (const float*)d_in[5];
  const float* rv      = (const float*)d_in[6];
  const float* W1      = (const float*)d_in[7];
  const float* b1      = (const float*)d_in[8];
  const float* W2      = (const float*)d_in[9];
  const float* b2      = (const float*)d_in[10];
  const float* W3      = (const float*)d_in[11];
  const float* b3      = (const float*)d_in[12];
  const float* k_emb   = (const float*)d_in[13];

  char* p = (char*)d_ws;
  double* accs   = (double*)carve(p, 3 * sizeof(double));
  float* sigma_b = (float*)carve(p, (size_t)B_TOT * 4);
  float* e_pos   = (float*)carve(p, (size_t)B_TOT * 4);
  float* e_neg   = (float*)carve(p, (size_t)B_TOT * 4);
  ushort_t* W1bf = (ushort_t*)carve(p, (size_t)FEATY * HDIM * 2);   // rows 0..255 of W1 (c-major)
  ushort_t* W1yT = (ushort_t*)carve(p, (size_t)HDIM * FEATY * 2);
  ushort_t* W1sT = (ushort_t*)carve(p, (size_t)HDIM * FEATS * 2);
  ushort_t* W2bf = (ushort_t*)carve(p, (size_t)HDIM * HDIM * 2);
  ushort_t* W2T  = (ushort_t*)carve(p, (size_t)HDIM * HDIM * 2);
  size_t fixed = (size_t)(p - (char*)d_ws);

  // per sample: statf 384 + feat 512 + 4 H-planes (z1s,z1bf,h1,dz2) 16384
  //           + e_part 32 + yhat 1008 + yneg 1008 = 19328
  const size_t per_sample = FEATS * 2 + FEATY * 2 + 4 * HDIM * 2 + 8 * 4 + 2 * YDIM * 4;
  int Mc = B_TOT;
  while (Mc > 256 && fixed + (size_t)Mc * per_sample + 65536 > ws_size) Mc >>= 1;

  ushort_t* statf = (ushort_t*)carve(p, (size_t)Mc * FEATS * 2);
  ushort_t* feat  = (ushort_t*)carve(p, (size_t)Mc * FEATY * 2);
  ushort_t* z1s   = (ushort_t*)carve(p, (size_t)Mc * HDIM * 2);
  ushort_t* z1bf  = (ushort_t*)carve(p, (size_t)Mc * HDIM * 2);
  ushort_t* h1    = (ushort_t*)carve(p, (size_t)Mc * HDIM * 2);
  ushort_t* dz2   = (ushort_t*)carve(p, (size_t)Mc * HDIM * 2);
  float* e_part   = (float*)carve(p, (size_t)Mc * 8 * 4);
  float* yhat     = (float*)carve(p, (size_t)Mc * YDIM * 4);
  float* yneg     = (float*)carve(p, (size_t)Mc * YDIM * 4);
  ushort_t* dz1   = h1;   // alias: h1 dead once the z2-GEMM consumed it

  dim3 blk(256);
  k_zero_acc<<<1, 1, 0, stream>>>(accs);
  k_sigma<<<(B_TOT + 255) / 256, blk, 0, stream>>>(k_idx, sigma_b);
  k_cast<<<(FEATY * HDIM + 255) / 256, blk, 0, stream>>>(W1, W1bf, FEATY * HDIM);
  k_w1yt<<<(HDIM * FEATY + 255) / 256, blk, 0, stream>>>(W1, W1yT);
  k_w1st<<<(HDIM * FEATS + 255) / 256, blk, 0, stream>>>(W1, W1sT);
  k_cast<<<(HDIM * HDIM + 255) / 256, blk, 0, stream>>>(W2, W2bf, HDIM * HDIM);
  k_w2t<<<dim3(HDIM / 32, HDIM / 32), blk, 0, stream>>>(W2, W2T);
  k_zfp<<<(Mc * 4 + 255) / 256, blk, 0, stream>>>(feat, Mc);

  auto G = [&](const ushort_t* Ap, const ushort_t* BTp, int K, int mode,
               const float* biasp, ushort_t* oA, ushort_t* oB, float* ep){
    gemm256<<<dim3(HDIM / 256, Mc / 256), dim3(512), 0, stream>>>(
        Ap, BTp, HDIM, K, mode, biasp, W3, z1s, z1bf, oA, oB, ep, Mc);
  };
  auto Gdy = [&](int upd, const float* yh, const float* yt, const float* sg){
    gemm_dy2<<<dim3(2, Mc / 128), blk, 0, stream>>>(
        dz1, W1bf, upd, yneg, feat, yh, yt, sg, accs);
  };

  int nCh = B_TOT / Mc;
  for (int c = 0; c < nCh; ++c){
    int b0 = c * Mc;
    k_statf<<<(Mc * FEATS + 255) / 256, blk, 0, stream>>>(
        cond + (size_t)b0 * CELLS, k_emb, k_idx + b0, statf, Mc);
    G(statf, W1sT, FEATS, 3, nullptr, z1s, nullptr, nullptr);   // z1s = statf @ W1s

    // ---- positive branch
    k_noise<<<(Mc * CELLS + 255) / 256, blk, 0, stream>>>(
        y_true + (size_t)b0 * YDIM, eps_pos + (size_t)b0 * YDIM, sigma_b + b0, yhat, feat, Mc);
    G(feat, W1yT, FEATY, 0, b1, z1bf, h1, nullptr);
    G(h1, W2T, HDIM, 1, b2, nullptr, dz2, e_part);
    k_esum<<<(Mc + 255) / 256, blk, 0, stream>>>(e_part, b3, e_pos + b0, Mc);
    G(dz2, W2bf, HDIM, 2, nullptr, dz1, nullptr, nullptr);
    Gdy(0, yhat, y_true + (size_t)b0 * YDIM, sigma_b + b0);

    // ---- negative branch
    k_makeneg<<<(Mc * 64 + 255) / 256, blk, 0, stream>>>(y_true, sel, rv, yneg, feat, b0, Mc);
    for (int r = 0; r < 5; ++r){
      G(feat, W1yT, FEATY, 0, b1, z1bf, h1, nullptr);
      G(h1, W2T, HDIM, 1, b2, nullptr, dz2, nullptr);
      G(dz2, W2bf, HDIM, 2, nullptr, dz1, nullptr, nullptr);
      Gdy(1, nullptr, nullptr, nullptr);
    }
    k_noise<<<(Mc * CELLS + 255) / 256, blk, 0, stream>>>(
        yneg, eps_neg + (size_t)b0 * YDIM, sigma_b + b0, yhat, feat, Mc);
    G(feat, W1yT, FEATY, 0, b1, z1bf, h1, nullptr);
    G(h1, W2T, HDIM, 1, b2, nullptr, nullptr, e_part);
    k_esum<<<(Mc + 255) / 256, blk, 0, stream>>>(e_part, b3, e_neg + b0, Mc);
  }

  k_contrast<<<64, blk, 0, stream>>>(e_pos, e_neg, accs);
  k_finalize<<<1, 1, 0, stream>>>(accs, (float*)d_out);
}

// Round 6
// 4061.812 us; speedup vs baseline: 1.4679x; 1.4679x over previous
//
#include <hip/hip_runtime.h>
#include <math.h>

#define B_TOT 16384
#define CELLS 36
#define YDIM 252       // 7*6*6
#define FEATP 448      // 416 padded to 448
#define FEAT_REAL 416
#define HDIM 2048
#define EMB_DIM 128
#define KSTEPS 50
#define NPART 16       // e_part slabs = HDIM/128

typedef unsigned short ushort_t;
typedef __attribute__((ext_vector_type(8))) short short8v;
typedef __attribute__((ext_vector_type(4))) float float4v;

__device__ __forceinline__ float clip01(float x){ return fminf(fmaxf(x, 0.f), 1.f); }
__device__ __forceinline__ float tanh_fast(float u){
  float e = __expf(2.f * u);
  return 1.f - 2.f / (e + 1.f);
}
__device__ __forceinline__ float gelu_f(float x){
  float u = 0.7978845608028654f * (x + 0.044715f * x * x * x);
  return 0.5f * x * (1.f + tanh_fast(u));
}
__device__ __forceinline__ float dgelu_f(float x){
  float x2 = x * x;
  float u = 0.7978845608028654f * (x + 0.044715f * x2 * x);
  float t = tanh_fast(u);
  return 0.5f * (1.f + t) + 0.5f * x * (1.f - t * t) * 0.7978845608028654f * (1.f + 0.134145f * x2);
}
__device__ __forceinline__ float clipmask(float y){ return (y == 0.f || y == 1.f) ? 0.5f : 1.f; }
__device__ __forceinline__ ushort_t f2bf(float x){
  union { float f; unsigned u; } v; v.f = x;
  unsigned r = v.u + 0x7fffu + ((v.u >> 16) & 1u);
  return (ushort_t)(r >> 16);
}
__device__ __forceinline__ float bf2f(ushort_t h){
  union { unsigned u; float f; } v; v.u = ((unsigned)h) << 16; return v.f;
}
__device__ __forceinline__ void load_lds16(const void* g, void* l){
  __builtin_amdgcn_global_load_lds((const __attribute__((address_space(1))) unsigned int*)g,
                                   (__attribute__((address_space(3))) unsigned int*)l, 16, 0, 0);
}
__device__ __forceinline__ void store16(ushort_t* dst, const float* x){
  short8v r0, r1;
#pragma unroll
  for (int i = 0; i < 8; ++i){ r0[i] = (short)f2bf(x[i]); r1[i] = (short)f2bf(x[8 + i]); }
  *(short8v*)dst = r0;
  *(short8v*)&dst[8] = r1;
}
// m204 bijective XCD swizzle
__device__ __forceinline__ void xcd_swizzle(int GX, int GY, int& bx, int& by){
  int nwg = GX * GY;
  int orig = by * GX + bx;
  int q = nwg >> 3, r = nwg & 7;
  int xcd = orig & 7, loc = orig >> 3;
  int lin = (xcd < r ? xcd * (q + 1) : r * (q + 1) + (xcd - r) * q) + loc;
  bx = lin % GX; by = lin / GX;
}

// ---------------- small kernels ----------------
__global__ void k_zero_acc(double* acc){ acc[0] = 0.0; acc[1] = 0.0; acc[2] = 0.0; }

__global__ void k_sigma(const int* __restrict__ k_idx, float* __restrict__ sigma_b){
  int b = blockIdx.x * blockDim.x + threadIdx.x;
  if (b >= B_TOT) return;
  int i = (KSTEPS - 1) - k_idx[b];
  float t = (float)i / (float)(KSTEPS - 1);
  float ang = (1.f - t) * 1.57079632679489662f;
  float c = cosf(ang);
  sigma_b[b] = 0.01f + 0.94f * c * c;
}

__global__ void k_cast(const float* __restrict__ in, ushort_t* __restrict__ out, int n){
  int gid = blockIdx.x * blockDim.x + threadIdx.x;
  if (gid < n) out[gid] = f2bf(in[gid]);
}
// W1T[h][f] (f padded to 448)
__global__ void k_w1t(const float* __restrict__ W1, ushort_t* __restrict__ W1T){
  int gid = blockIdx.x * blockDim.x + threadIdx.x;
  if (gid >= HDIM * FEATP) return;
  int h = gid / FEATP, f = gid - h * FEATP;
  W1T[gid] = (f < FEAT_REAL) ? f2bf(W1[(size_t)f * HDIM + h]) : (ushort_t)0;
}
// tiled transpose: W2T[n][k] = W2[k][n]
__global__ __launch_bounds__(256) void k_w2t(const float* __restrict__ W2, ushort_t* __restrict__ W2T){
  __shared__ float tile[32][33];
  int x0 = blockIdx.x << 5, y0 = blockIdx.y << 5;
  int tx = threadIdx.x & 31, ty = threadIdx.x >> 5;
#pragma unroll
  for (int i = 0; i < 4; ++i)
    tile[ty + i * 8][tx] = W2[(size_t)(y0 + ty + i * 8) * HDIM + (x0 + tx)];
  __syncthreads();
#pragma unroll
  for (int i = 0; i < 4; ++i)
    W2T[(size_t)(x0 + ty + i * 8) * HDIM + (y0 + tx)] = f2bf(tile[tx][ty + i * 8]);
}

// static cols of feat: 252..447 (cond, emb, zero pad)
__global__ void k_feat_static(const float* __restrict__ cond, const float* __restrict__ k_emb,
                              const int* __restrict__ k_idx, ushort_t* __restrict__ feat, int Mc){
  int gid = blockIdx.x * blockDim.x + threadIdx.x;
  if (gid >= Mc * 196) return;
  int i = gid / 196, c = gid - i * 196;
  float v;
  if (c < CELLS)            v = cond[(size_t)i * CELLS + c];
  else if (c < CELLS + EMB_DIM) v = k_emb[(size_t)k_idx[i] * EMB_DIM + (c - CELLS)];
  else                      v = 0.f;
  feat[(size_t)i * FEATP + YDIM + c] = f2bf(v);
}

// noise + direct feat write
__global__ void k_noise(const float* __restrict__ y, const float* __restrict__ eps,
                        const float* __restrict__ sigma_b, float* __restrict__ out,
                        ushort_t* __restrict__ feat, int Mc){
  int gid = blockIdx.x * blockDim.x + threadIdx.x;
  if (gid >= Mc * CELLS) return;
  int i = gid / CELLS, cell = gid - i * CELLS;
  float sigma = sigma_b[i];
  float sq = sqrtf(fmaxf(1.f - sigma * sigma, 1e-8f));
  const float* yp = y + (size_t)i * YDIM + cell;
  const float* ep = eps + (size_t)i * YDIM + cell;
  float yh[7];
#pragma unroll
  for (int ch = 0; ch < 7; ++ch){
    float e = ep[ch * CELLS] * 0.1f;
    yh[ch] = clip01(sq * yp[ch * CELLS] + sigma * e);
  }
  bool filled = yh[0] > 0.5f;
  float s = 0.f;
#pragma unroll
  for (int ch = 1; ch < 7; ++ch) s += yh[ch];
  float* op = out + (size_t)i * YDIM + cell;
  ushort_t* fp = feat + (size_t)i * FEATP + cell;
  op[0] = yh[0];
  fp[0] = f2bf(yh[0]);
#pragma unroll
  for (int ch = 1; ch < 7; ++ch){
    float v = yh[ch];
    if (filled) v = v / (s + 1e-8f);
    v = clip01(v);
    op[ch * CELLS] = v;
    fp[ch * CELLS] = f2bf(v);
  }
}

// y_neg init + feat write
__global__ void k_makeneg(const float* __restrict__ y_true, const float* __restrict__ sel,
                          const float* __restrict__ rv, float* __restrict__ y_neg,
                          ushort_t* __restrict__ feat, int b0, int Mc){
  int w = (blockIdx.x * blockDim.x + threadIdx.x) >> 6;
  int lane = threadIdx.x & 63;
  if (w >= Mc) return;
  int b = b0 + w;
  int c = lane;
  bool active = c < CELLS;
  float yt0 = active ? y_true[(size_t)b * YDIM + c] : 0.f;
  bool filled = active && (yt0 > 0.5f);
  unsigned long long bal = __ballot(filled);
  int n_filled = __popcll(bal);
  int num_c = (int)floorf((float)n_filled * 0.3f);
  int idx = num_c - 1; if (idx < 0) idx = 0;
  float score = filled ? sel[(size_t)b * CELLS + c] : 2.0f;
  int cnt_lt = 0, cnt_le = 0;
  for (int l = 0; l < CELLS; ++l){
    float sv = __shfl(score, l);
    cnt_lt += (sv < score);
    cnt_le += (sv <= score);
  }
  float cand = (active && cnt_lt <= idx && idx < cnt_le) ? score : 3.4e38f;
  for (int off = 32; off; off >>= 1) cand = fminf(cand, __shfl_xor(cand, off));
  float thr = (num_c > 0) ? cand : -1.0f;
  bool corrupt = filled && (score <= thr);
  if (active){
    float rvv[6]; float rsum = 0.f;
#pragma unroll
    for (int ch = 0; ch < 6; ++ch){ rvv[ch] = rv[(size_t)b * (6 * CELLS) + ch * CELLS + c]; rsum += rvv[ch]; }
    float v0 = corrupt ? 0.f : yt0;
    y_neg[(size_t)w * YDIM + c] = v0;
    feat[(size_t)w * FEATP + c] = f2bf(clip01(v0));
#pragma unroll
    for (int ch = 0; ch < 6; ++ch){
      float val = corrupt ? rvv[ch] / rsum : y_true[(size_t)b * YDIM + (ch + 1) * CELLS + c];
      y_neg[(size_t)w * YDIM + (ch + 1) * CELLS + c] = val;
      feat[(size_t)w * FEATP + (ch + 1) * CELLS + c] = f2bf(clip01(val));
    }
  }
}

// e[i] = b3 + sum_x e_part[x][i]
__global__ void k_esum(const float* __restrict__ e_part, const float* __restrict__ b3,
                       float* __restrict__ e_out, int Mc){
  int i = blockIdx.x * blockDim.x + threadIdx.x;
  if (i >= Mc) return;
  float s = b3[0];
#pragma unroll
  for (int x = 0; x < NPART; ++x) s += e_part[(size_t)x * Mc + i];
  e_out[i] = s;
}

__global__ __launch_bounds__(256) void k_contrast(const float* __restrict__ e_pos, const float* __restrict__ e_neg,
                           double* __restrict__ acc){
  double con = 0.0, reg = 0.0;
  for (int b = blockIdx.x * blockDim.x + threadIdx.x; b < B_TOT; b += gridDim.x * blockDim.x){
    float ep = e_pos[b], en = e_neg[b];
    float a = -ep, bb = -en;
    float m = fmaxf(a, bb);
    float lse = m + logf(expf(a - m) + expf(bb - m));
    con += (double)(ep + lse);
    reg += (double)ep + (double)en;
  }
  for (int off = 32; off; off >>= 1){ con += __shfl_down(con, off); reg += __shfl_down(reg, off); }
  __shared__ double wc[4], wr[4];
  int lane = threadIdx.x & 63, wid = threadIdx.x >> 6;
  if (lane == 0){ wc[wid] = con; wr[wid] = reg; }
  __syncthreads();
  if (threadIdx.x == 0){
    atomicAdd(&acc[1], (wc[0] + wc[1]) + (wc[2] + wc[3]));
    atomicAdd(&acc[2], (wr[0] + wr[1]) + (wr[2] + wr[3]));
  }
}

__global__ void k_finalize(const double* __restrict__ acc, float* __restrict__ out){
  double mse = acc[0] / (double)((long long)B_TOT * YDIM);
  double con = acc[1] / (double)B_TOT;
  double reg = acc[2] / (double)B_TOT;
  out[0] = (float)(mse + con + 0.01 * reg);
}

// ============ pipelined GEMM: BM=256, BN=128, BK=64, 3 LDS buffers, 2-deep prefetch ============
// C[M,N] = A[M,K]bf16 @ BT[N,K]bf16. 512 thr = 8 waves (4M x 2N), wave tile 64x64.
// Stage: linear LDS dest + XOR-swizzled global source col; reads use matching XOR (rule #21).
// Counted vmcnt: steady wait vmcnt(12) leaves 2 tiles (12 loads) in flight (T4).
// modes: 0 z1: z=v+b1 -> outA=dgz1=bf(dgelu z), outB=h1=bf(gelu z)
//        1 z2: z=v+b2 -> outB?=dz2=bf(W3*dgelu z); e_part?=row sums gelu(z)*W3
//        2 dz1: v *= bf2f(dgz[o]); outA
#define STAGE_A(buf, k0) \
  _Pragma("unroll") \
  for (int i_ = 0; i_ < 4; ++i_){ \
    int rb_ = (i_ << 6) + (w << 3); \
    load_lds16((const char*)A + (((size_t)(m0 + rb_ + rsub)) * K + (k0) + csw) * 2, \
               (char*)(buf) + (rb_ << 7) + (lane << 4)); \
  }
#define STAGE_B(buf, k0) \
  _Pragma("unroll") \
  for (int i_ = 0; i_ < 2; ++i_){ \
    int rb_ = (i_ << 6) + (w << 3); \
    load_lds16((const char*)BT + (((size_t)(n0 + rb_ + rsub)) * K + (k0) + csw) * 2, \
               (char*)(buf) + (rb_ << 7) + (lane << 4)); \
  }

__global__ __launch_bounds__(512, 1) void gemm_p(
    const ushort_t* __restrict__ A, const ushort_t* __restrict__ BT,
    int N, int K, int mode,
    const float* __restrict__ bias, const float* __restrict__ W3,
    const ushort_t* __restrict__ dgz,
    ushort_t* __restrict__ outA, ushort_t* __restrict__ outB,
    float* __restrict__ e_part, int Mrows){
  __shared__ __align__(16) ushort_t As[3][256 * 64];
  __shared__ __align__(16) ushort_t Bs[3][128 * 64];
  const int t = threadIdx.x, lane = t & 63, w = t >> 6;
  int bx = blockIdx.x, by = blockIdx.y;
  xcd_swizzle(gridDim.x, gridDim.y, bx, by);
  const int m0 = by << 8, n0 = bx << 7;
  const int fr = lane & 15, kg = lane >> 4;
  const int frs = fr & 7;
  const int rsub = lane >> 3;
  const int csw = ((lane & 7) ^ rsub) << 3;     // source col swizzle (ushorts)
  const int wr = (w >> 1) << 6, wc = (w & 1) << 6;
  const int NT = K >> 6;

  float4v acc[4][4];
#pragma unroll
  for (int m = 0; m < 4; ++m)
#pragma unroll
    for (int n = 0; n < 4; ++n) acc[m][n] = (float4v)0.f;

  ushort_t *Ac = &As[0][0], *An1 = &As[1][0], *An2 = &As[2][0];
  ushort_t *Bc = &Bs[0][0], *Bn1 = &Bs[1][0], *Bn2 = &Bs[2][0];

  STAGE_A(Ac, 0); STAGE_B(Bc, 0);
  if (NT > 1){ STAGE_A(An1, 64); STAGE_B(Bn1, 64); }

  for (int kt = 0; kt < NT; ++kt){
    if (kt + 2 < NT){
      const int kn = (kt + 2) << 6;
      STAGE_A(An2, kn); STAGE_B(Bn2, kn);
    }
    const int rem = NT - 1 - kt;
    if (rem >= 2)      asm volatile("s_waitcnt vmcnt(12)" ::: "memory");
    else if (rem == 1) asm volatile("s_waitcnt vmcnt(6)" ::: "memory");
    else               asm volatile("s_waitcnt vmcnt(0)" ::: "memory");
    __builtin_amdgcn_s_barrier();
    __builtin_amdgcn_sched_barrier(0);

    short8v a[4][2], b[4][2];
#pragma unroll
    for (int m = 0; m < 4; ++m)
#pragma unroll
      for (int kk = 0; kk < 2; ++kk)
        a[m][kk] = *(const short8v*)&Ac[((wr + (m << 4) + fr) << 6) + ((((kk << 2) + kg) ^ frs) << 3)];
#pragma unroll
    for (int n = 0; n < 4; ++n)
#pragma unroll
      for (int kk = 0; kk < 2; ++kk)
        b[n][kk] = *(const short8v*)&Bc[((wc + (n << 4) + fr) << 6) + ((((kk << 2) + kg) ^ frs) << 3)];
    asm volatile("s_waitcnt lgkmcnt(0)" ::: "memory");
    __builtin_amdgcn_sched_barrier(0);
    __builtin_amdgcn_s_setprio(1);
#pragma unroll
    for (int m = 0; m < 4; ++m)
#pragma unroll
      for (int n = 0; n < 4; ++n)
#pragma unroll
        for (int kk = 0; kk < 2; ++kk)
          acc[m][n] = __builtin_amdgcn_mfma_f32_16x16x32_bf16(a[m][kk], b[n][kk], acc[m][n], 0, 0, 0);
    __builtin_amdgcn_s_setprio(0);
    __builtin_amdgcn_sched_barrier(0);
    __builtin_amdgcn_s_barrier();
    __builtin_amdgcn_sched_barrier(0);
    // rotate buffers
    ushort_t* ta = Ac; Ac = An1; An1 = An2; An2 = ta;
    ushort_t* tb = Bc; Bc = Bn1; Bn1 = Bn2; Bn2 = tb;
  }

  // ---- epilogue: per-wave f32 LDS slice -> coalesced 16B bf16 stores ----
  float* slice = (float*)&As[0][0] + w * (16 * 68);
  float* e_lds = (float*)&Bs[0][0];
  const bool do_e = (mode == 1) && (e_part != nullptr);
  if (do_e){
    if (t < 256) e_lds[t] = 0.f;
    __syncthreads();
  }
  const int rrow = lane >> 2;      // 0..15
  const int rq = lane & 3;         // 16-col group
#pragma unroll
  for (int m = 0; m < 4; ++m){
    if (m) asm volatile("s_waitcnt lgkmcnt(0)" ::: "memory");  // prior reads done before overwrite
#pragma unroll
    for (int j = 0; j < 4; ++j)
#pragma unroll
      for (int n = 0; n < 4; ++n)
        slice[((kg << 2) + j) * 68 + (n << 4) + fr] = acc[m][n][j];
    asm volatile("s_waitcnt lgkmcnt(0)" ::: "memory");
    const int grow = m0 + wr + (m << 4) + rrow;
    const int gcol = n0 + wc + (rq << 4);
    float val[16];
#pragma unroll
    for (int p2 = 0; p2 < 4; ++p2){
      float4 vv = *(const float4*)&slice[rrow * 68 + (rq << 4) + (p2 << 2)];
      val[p2 * 4 + 0] = vv.x; val[p2 * 4 + 1] = vv.y;
      val[p2 * 4 + 2] = vv.z; val[p2 * 4 + 3] = vv.w;
    }
    const size_t ob = (size_t)grow * N + gcol;
    if (mode == 0){
      float o0[16], o1[16];
#pragma unroll
      for (int e = 0; e < 16; ++e){
        float z = val[e] + bias[gcol + e];
        o0[e] = dgelu_f(z);
        o1[e] = gelu_f(z);
      }
      store16(outA + ob, o0);
      store16(outB + ob, o1);
    } else if (mode == 1){
      float pe = 0.f;
      float o0[16];
#pragma unroll
      for (int e = 0; e < 16; ++e){
        float z = val[e] + bias[gcol + e];
        float w3 = W3[gcol + e];
        o0[e] = w3 * dgelu_f(z);
        if (do_e) pe += gelu_f(z) * w3;
      }
      if (outB) store16(outB + ob, o0);
      if (do_e){
        pe += __shfl_xor(pe, 1);
        pe += __shfl_xor(pe, 2);
        if (rq == 0) atomicAdd(&e_lds[wr + (m << 4) + rrow], pe);
      }
    } else {
      float o0[16];
      short8v g0 = *(const short8v*)&dgz[ob];
      short8v g1 = *(const short8v*)&dgz[ob + 8];
#pragma unroll
      for (int e = 0; e < 8; ++e){
        o0[e]     = val[e]     * bf2f((ushort_t)g0[e]);
        o0[8 + e] = val[8 + e] * bf2f((ushort_t)g1[e]);
      }
      store16(outA + ob, o0);
    }
  }
  if (do_e){
    __syncthreads();
    if (t < 256) e_part[(size_t)bx * Mrows + m0 + t] = e_lds[t];
  }
}

// ============ dy GEMM (128x128, full K) with fused mse / refine-update epilogue ============
#define DY_STAGE(Asl_, Bsl_, k0_) do { \
  _Pragma("unroll") \
  for (int i_ = 0; i_ < 4; ++i_){ \
    int c_ = i_ * 4 + w; \
    int r_ = c_ * 8 + rsub; \
    load_lds16((const char*)A + ((size_t)(m0 + r_) * K + (k0_)) * 2 + cb, (char*)(Asl_) + c_ * 1024 + lane * 16); \
    load_lds16((const char*)BT + ((size_t)(n0 + r_) * K + (k0_)) * 2 + cb, (char*)(Bsl_) + c_ * 1024 + lane * 16); \
  } } while (0)

#define DY_MFMA(Asl_, Bsl_) do { \
  _Pragma("unroll") \
  for (int kk = 0; kk < 2; ++kk){ \
    int kb = kk * 32 + kg * 8; \
    short8v a[4], b[4]; \
    _Pragma("unroll") \
    for (int m = 0; m < 4; ++m) a[m] = *(const short8v*)&(Asl_)[(wr + m * 16 + fr) * 64 + kb]; \
    _Pragma("unroll") \
    for (int n = 0; n < 4; ++n) b[n] = *(const short8v*)&(Bsl_)[(wc + n * 16 + fr) * 64 + kb]; \
    _Pragma("unroll") \
    for (int m = 0; m < 4; ++m) \
      _Pragma("unroll") \
      for (int n = 0; n < 4; ++n) \
        acc[m][n] = __builtin_amdgcn_mfma_f32_16x16x32_bf16(a[m], b[n], acc[m][n], 0, 0, 0); \
  } } while (0)

__global__ __launch_bounds__(256) void gemm_dy2(
    const ushort_t* __restrict__ A, const ushort_t* __restrict__ BT, int upd,
    float* __restrict__ yneg, ushort_t* __restrict__ feat,
    const float* __restrict__ yhat, const float* __restrict__ y_true,
    const float* __restrict__ sigma_b, double* __restrict__ acc_g){
  __shared__ __align__(16) ushort_t Asl[2][128 * 64];
  __shared__ __align__(16) ushort_t Bsl[2][128 * 64];
  const int K = HDIM;
  const int t = threadIdx.x, lane = t & 63, w = t >> 6;
  int bx = blockIdx.x, by = blockIdx.y;
  xcd_swizzle(gridDim.x, gridDim.y, bx, by);
  const int m0 = by << 7, n0 = bx << 7;
  const int fr = lane & 15, kg = lane >> 4;
  const int rsub = lane >> 3;
  const int cb = (lane & 7) * 16;
  const int wr = (w >> 1) * 64, wc = (w & 1) * 64;

  float4v acc[4][4];
#pragma unroll
  for (int m = 0; m < 4; ++m)
#pragma unroll
    for (int n = 0; n < 4; ++n) acc[m][n] = (float4v)0.f;

  DY_STAGE(Asl[0], Bsl[0], 0);
  __syncthreads();
  int cur = 0;
  for (int k0 = 0; k0 < K; k0 += 64){
    if (k0 + 64 < K) DY_STAGE(Asl[cur ^ 1], Bsl[cur ^ 1], k0 + 64);
    DY_MFMA(Asl[cur], Bsl[cur]);
    __syncthreads();
    cur ^= 1;
  }

  double ms = 0.0;
#pragma unroll
  for (int m = 0; m < 4; ++m){
#pragma unroll
    for (int j = 0; j < 4; ++j){
      int row = m0 + wr + m * 16 + kg * 4 + j;
#pragma unroll
      for (int n = 0; n < 4; ++n){
        int col = n0 + wc + n * 16 + fr;
        if (col < YDIM){
          size_t o = (size_t)row * YDIM + col;
          float g = acc[m][n][j];
          if (upd){
            float y = yneg[o];
            y = clip01(y + 0.15f * g * clipmask(y));
            yneg[o] = y;
            feat[(size_t)row * FEATP + col] = f2bf(y);
          } else {
            float y = yhat[o];
            float score = g * clipmask(y);
            float tgt = (y - y_true[o]) / (sigma_b[row] + 1e-8f);
            float d = score - tgt;
            ms += (double)d * (double)d;
          }
        }
      }
    }
  }
  if (!upd){
    for (int off = 32; off; off >>= 1) ms += __shfl_down(ms, off);
    __shared__ double wsum[4];
    int wid = t >> 6;
    if ((t & 63) == 0) wsum[wid] = ms;
    __syncthreads();
    if (t == 0) atomicAdd(&acc_g[0], (wsum[0] + wsum[1]) + (wsum[2] + wsum[3]));
  }
}

// ---------------- host ----------------
static inline char* carve(char*& p, size_t bytes){
  char* r = p; p += (bytes + 255) & ~(size_t)255; return r;
}

extern "C" void kernel_launch(void* const* d_in, const int* in_sizes, int n_in,
                              void* d_out, int out_size, void* d_ws, size_t ws_size,
                              hipStream_t stream){
  (void)in_sizes; (void)n_in; (void)out_size;
  const float* y_true  = (const float*)d_in[0];
  const float* cond    = (const float*)d_in[1];
  const int*   k_idx   = (const int*)d_in[2];
  const float* eps_pos = (const float*)d_in[3];
  const float* eps_neg = (const float*)d_in[4];
  const float* sel     = (const float*)d_in[5];
  const float* rv      = (const float*)d_in[6];
  const float* W1      = (const float*)d_in[7];
  const float* b1      = (const float*)d_in[8];
  const float* W2      = (const float*)d_in[9];
  const float* b2      = (const float*)d_in[10];
  const float* W3      = (const float*)d_in[11];
  const float* b3      = (const float*)d_in[12];
  const float* k_emb   = (const float*)d_in[13];

  char* p = (char*)d_ws;
  double* accs   = (double*)carve(p, 3 * sizeof(double));
  float* sigma_b = (float*)carve(p, (size_t)B_TOT * 4);
  float* e_pos   = (float*)carve(p, (size_t)B_TOT * 4);
  float* e_neg   = (float*)carve(p, (size_t)B_TOT * 4);
  ushort_t* W1bf = (ushort_t*)carve(p, (size_t)256 * HDIM * 2);   // rows 0..255 of W1 (dy B^T; cols>=252 discarded)
  ushort_t* W1T  = (ushort_t*)carve(p, (size_t)HDIM * FEATP * 2);
  ushort_t* W2bf = (ushort_t*)carve(p, (size_t)HDIM * HDIM * 2);
  ushort_t* W2T  = (ushort_t*)carve(p, (size_t)HDIM * HDIM * 2);
  size_t fixed = (size_t)(p - (char*)d_ws);

  // per sample: feat 896 + 3 H-planes (dgz1,h1,dz2) 12288 + e_part 64 + yhat/yneg 2016
  const size_t per_sample = FEATP * 2 + 3 * HDIM * 2 + NPART * 4 + 2 * YDIM * 4;
  int Mc = B_TOT;
  while (Mc > 256 && fixed + (size_t)Mc * per_sample + 65536 > ws_size) Mc >>= 1;

  ushort_t* feat = (ushort_t*)carve(p, (size_t)Mc * FEATP * 2);
  ushort_t* dgz1 = (ushort_t*)carve(p, (size_t)Mc * HDIM * 2);
  ushort_t* h1   = (ushort_t*)carve(p, (size_t)Mc * HDIM * 2);
  ushort_t* dz2  = (ushort_t*)carve(p, (size_t)Mc * HDIM * 2);
  float* e_part  = (float*)carve(p, (size_t)Mc * NPART * 4);
  float* yhat    = (float*)carve(p, (size_t)Mc * YDIM * 4);
  float* yneg    = (float*)carve(p, (size_t)Mc * YDIM * 4);
  ushort_t* dz1  = h1;   // alias: h1 dead once the z2-GEMM consumed it

  dim3 blk(256);
  k_zero_acc<<<1, 1, 0, stream>>>(accs);
  k_sigma<<<(B_TOT + 255) / 256, blk, 0, stream>>>(k_idx, sigma_b);
  k_cast<<<(256 * HDIM + 255) / 256, blk, 0, stream>>>(W1, W1bf, 256 * HDIM);
  k_w1t<<<(HDIM * FEATP + 255) / 256, blk, 0, stream>>>(W1, W1T);
  k_cast<<<(HDIM * HDIM + 255) / 256, blk, 0, stream>>>(W2, W2bf, HDIM * HDIM);
  k_w2t<<<dim3(HDIM / 32, HDIM / 32), blk, 0, stream>>>(W2, W2T);

  auto G = [&](const ushort_t* Ap, const ushort_t* BTp, int K, int mode,
               const float* biasp, ushort_t* oA, ushort_t* oB, float* ep){
    gemm_p<<<dim3(HDIM / 128, Mc / 256), dim3(512), 0, stream>>>(
        Ap, BTp, HDIM, K, mode, biasp, W3, dgz1, oA, oB, ep, Mc);
  };
  auto Gdy = [&](int upd, const float* yh, const float* yt, const float* sg){
    gemm_dy2<<<dim3(2, Mc / 128), blk, 0, stream>>>(
        dz1, W1bf, upd, yneg, feat, yh, yt, sg, accs);
  };

  int nCh = B_TOT / Mc;
  for (int c = 0; c < nCh; ++c){
    int b0 = c * Mc;
    k_feat_static<<<(Mc * 196 + 255) / 256, blk, 0, stream>>>(
        cond + (size_t)b0 * CELLS, k_emb, k_idx + b0, feat, Mc);

    // ---- positive branch
    k_noise<<<(Mc * CELLS + 255) / 256, blk, 0, stream>>>(
        y_true + (size_t)b0 * YDIM, eps_pos + (size_t)b0 * YDIM, sigma_b + b0, yhat, feat, Mc);
    G(feat, W1T, FEATP, 0, b1, dgz1, h1, nullptr);
    G(h1, W2T, HDIM, 1, b2, nullptr, dz2, e_part);
    k_esum<<<(Mc + 255) / 256, blk, 0, stream>>>(e_part, b3, e_pos + b0, Mc);
    G(dz2, W2bf, HDIM, 2, nullptr, dz1, nullptr, nullptr);
    Gdy(0, yhat, y_true + (size_t)b0 * YDIM, sigma_b + b0);

    // ---- negative branch
    k_makeneg<<<(Mc * 64 + 255) / 256, blk, 0, stream>>>(y_true, sel, rv, yneg, feat, b0, Mc);
    for (int r = 0; r < 5; ++r){
      G(feat, W1T, FEATP, 0, b1, dgz1, h1, nullptr);
      G(h1, W2T, HDIM, 1, b2, nullptr, dz2, nullptr);
      G(dz2, W2bf, HDIM, 2, nullptr, dz1, nullptr, nullptr);
      Gdy(1, nullptr, nullptr, nullptr);
    }
    k_noise<<<(Mc * CELLS + 255) / 256, blk, 0, stream>>>(
        yneg, eps_neg + (size_t)b0 * YDIM, sigma_b + b0, yhat, feat, Mc);
    G(feat, W1T, FEATP, 0, b1, dgz1, h1, nullptr);
    G(h1, W2T, HDIM, 1, b2, nullptr, nullptr, e_part);
    k_esum<<<(Mc + 255) / 256, blk, 0, stream>>>(e_part, b3, e_neg + b0, Mc);
  }

  k_contrast<<<64, blk, 0, stream>>>(e_pos, e_neg, accs);
  k_finalize<<<1, 1, 0, stream>>>(accs, (float*)d_out);
}

// Round 7
// 3977.245 us; speedup vs baseline: 1.4991x; 1.0213x over previous
//
#include <hip/hip_runtime.h>
#include <math.h>

#define B_TOT 16384
#define CELLS 36
#define YDIM 252       // 7*6*6
#define FEATP 448      // 416 padded to 448
#define FEAT_REAL 416
#define HDIM 2048
#define EMB_DIM 128
#define KSTEPS 50
#define NPART 8        // e_part slabs = HDIM/256

typedef unsigned short ushort_t;
typedef __attribute__((ext_vector_type(8))) short short8v;
typedef __attribute__((ext_vector_type(4))) float float4v;

__device__ __forceinline__ float clip01(float x){ return fminf(fmaxf(x, 0.f), 1.f); }
__device__ __forceinline__ float tanh_fast(float u){
  float e = __expf(2.f * u);
  return 1.f - 2.f / (e + 1.f);
}
__device__ __forceinline__ float gelu_f(float x){
  float u = 0.7978845608028654f * (x + 0.044715f * x * x * x);
  return 0.5f * x * (1.f + tanh_fast(u));
}
__device__ __forceinline__ float dgelu_f(float x){
  float x2 = x * x;
  float u = 0.7978845608028654f * (x + 0.044715f * x2 * x);
  float t = tanh_fast(u);
  return 0.5f * (1.f + t) + 0.5f * x * (1.f - t * t) * 0.7978845608028654f * (1.f + 0.134145f * x2);
}
__device__ __forceinline__ float clipmask(float y){ return (y == 0.f || y == 1.f) ? 0.5f : 1.f; }
__device__ __forceinline__ ushort_t f2bf(float x){
  union { float f; unsigned u; } v; v.f = x;
  unsigned r = v.u + 0x7fffu + ((v.u >> 16) & 1u);
  return (ushort_t)(r >> 16);
}
__device__ __forceinline__ float bf2f(ushort_t h){
  union { unsigned u; float f; } v; v.u = ((unsigned)h) << 16; return v.f;
}
__device__ __forceinline__ void load_lds16(const void* g, void* l){
  __builtin_amdgcn_global_load_lds((const __attribute__((address_space(1))) unsigned int*)g,
                                   (__attribute__((address_space(3))) unsigned int*)l, 16, 0, 0);
}
__device__ __forceinline__ void store16(ushort_t* dst, const float* x){
  short8v r0, r1;
#pragma unroll
  for (int i = 0; i < 8; ++i){ r0[i] = (short)f2bf(x[i]); r1[i] = (short)f2bf(x[8 + i]); }
  *(short8v*)dst = r0;
  *(short8v*)&dst[8] = r1;
}
// m204 bijective XCD swizzle
__device__ __forceinline__ void xcd_swizzle(int GX, int GY, int& bx, int& by){
  int nwg = GX * GY;
  int orig = by * GX + bx;
  int q = nwg >> 3, r = nwg & 7;
  int xcd = orig & 7, loc = orig >> 3;
  int lin = (xcd < r ? xcd * (q + 1) : r * (q + 1) + (xcd - r) * q) + loc;
  bx = lin % GX; by = lin / GX;
}

// ---------------- small kernels ----------------
__global__ void k_zero_acc(double* acc){ acc[0] = 0.0; acc[1] = 0.0; acc[2] = 0.0; }

__global__ void k_sigma(const int* __restrict__ k_idx, float* __restrict__ sigma_b){
  int b = blockIdx.x * blockDim.x + threadIdx.x;
  if (b >= B_TOT) return;
  int i = (KSTEPS - 1) - k_idx[b];
  float t = (float)i / (float)(KSTEPS - 1);
  float ang = (1.f - t) * 1.57079632679489662f;
  float c = cosf(ang);
  sigma_b[b] = 0.01f + 0.94f * c * c;
}

__global__ void k_cast(const float* __restrict__ in, ushort_t* __restrict__ out, int n){
  int gid = blockIdx.x * blockDim.x + threadIdx.x;
  if (gid < n) out[gid] = f2bf(in[gid]);
}
// W1T[h][f] (f padded to 448)
__global__ void k_w1t(const float* __restrict__ W1, ushort_t* __restrict__ W1T){
  int gid = blockIdx.x * blockDim.x + threadIdx.x;
  if (gid >= HDIM * FEATP) return;
  int h = gid / FEATP, f = gid - h * FEATP;
  W1T[gid] = (f < FEAT_REAL) ? f2bf(W1[(size_t)f * HDIM + h]) : (ushort_t)0;
}
// tiled transpose: W2T[n][k] = W2[k][n]
__global__ __launch_bounds__(256) void k_w2t(const float* __restrict__ W2, ushort_t* __restrict__ W2T){
  __shared__ float tile[32][33];
  int x0 = blockIdx.x << 5, y0 = blockIdx.y << 5;
  int tx = threadIdx.x & 31, ty = threadIdx.x >> 5;
#pragma unroll
  for (int i = 0; i < 4; ++i)
    tile[ty + i * 8][tx] = W2[(size_t)(y0 + ty + i * 8) * HDIM + (x0 + tx)];
  __syncthreads();
#pragma unroll
  for (int i = 0; i < 4; ++i)
    W2T[(size_t)(x0 + ty + i * 8) * HDIM + (y0 + tx)] = f2bf(tile[tx][ty + i * 8]);
}

// static cols of feat: 252..447 (cond, emb, zero pad)
__global__ void k_feat_static(const float* __restrict__ cond, const float* __restrict__ k_emb,
                              const int* __restrict__ k_idx, ushort_t* __restrict__ feat, int Mc){
  int gid = blockIdx.x * blockDim.x + threadIdx.x;
  if (gid >= Mc * 196) return;
  int i = gid / 196, c = gid - i * 196;
  float v;
  if (c < CELLS)            v = cond[(size_t)i * CELLS + c];
  else if (c < CELLS + EMB_DIM) v = k_emb[(size_t)k_idx[i] * EMB_DIM + (c - CELLS)];
  else                      v = 0.f;
  feat[(size_t)i * FEATP + YDIM + c] = f2bf(v);
}

// noise + direct feat write
__global__ void k_noise(const float* __restrict__ y, const float* __restrict__ eps,
                        const float* __restrict__ sigma_b, float* __restrict__ out,
                        ushort_t* __restrict__ feat, int Mc){
  int gid = blockIdx.x * blockDim.x + threadIdx.x;
  if (gid >= Mc * CELLS) return;
  int i = gid / CELLS, cell = gid - i * CELLS;
  float sigma = sigma_b[i];
  float sq = sqrtf(fmaxf(1.f - sigma * sigma, 1e-8f));
  const float* yp = y + (size_t)i * YDIM + cell;
  const float* ep = eps + (size_t)i * YDIM + cell;
  float yh[7];
#pragma unroll
  for (int ch = 0; ch < 7; ++ch){
    float e = ep[ch * CELLS] * 0.1f;
    yh[ch] = clip01(sq * yp[ch * CELLS] + sigma * e);
  }
  bool filled = yh[0] > 0.5f;
  float s = 0.f;
#pragma unroll
  for (int ch = 1; ch < 7; ++ch) s += yh[ch];
  float* op = out + (size_t)i * YDIM + cell;
  ushort_t* fp = feat + (size_t)i * FEATP + cell;
  op[0] = yh[0];
  fp[0] = f2bf(yh[0]);
#pragma unroll
  for (int ch = 1; ch < 7; ++ch){
    float v = yh[ch];
    if (filled) v = v / (s + 1e-8f);
    v = clip01(v);
    op[ch * CELLS] = v;
    fp[ch * CELLS] = f2bf(v);
  }
}

// y_neg init + feat write
__global__ void k_makeneg(const float* __restrict__ y_true, const float* __restrict__ sel,
                          const float* __restrict__ rv, float* __restrict__ y_neg,
                          ushort_t* __restrict__ feat, int b0, int Mc){
  int w = (blockIdx.x * blockDim.x + threadIdx.x) >> 6;
  int lane = threadIdx.x & 63;
  if (w >= Mc) return;
  int b = b0 + w;
  int c = lane;
  bool active = c < CELLS;
  float yt0 = active ? y_true[(size_t)b * YDIM + c] : 0.f;
  bool filled = active && (yt0 > 0.5f);
  unsigned long long bal = __ballot(filled);
  int n_filled = __popcll(bal);
  int num_c = (int)floorf((float)n_filled * 0.3f);
  int idx = num_c - 1; if (idx < 0) idx = 0;
  float score = filled ? sel[(size_t)b * CELLS + c] : 2.0f;
  int cnt_lt = 0, cnt_le = 0;
  for (int l = 0; l < CELLS; ++l){
    float sv = __shfl(score, l);
    cnt_lt += (sv < score);
    cnt_le += (sv <= score);
  }
  float cand = (active && cnt_lt <= idx && idx < cnt_le) ? score : 3.4e38f;
  for (int off = 32; off; off >>= 1) cand = fminf(cand, __shfl_xor(cand, off));
  float thr = (num_c > 0) ? cand : -1.0f;
  bool corrupt = filled && (score <= thr);
  if (active){
    float rvv[6]; float rsum = 0.f;
#pragma unroll
    for (int ch = 0; ch < 6; ++ch){ rvv[ch] = rv[(size_t)b * (6 * CELLS) + ch * CELLS + c]; rsum += rvv[ch]; }
    float v0 = corrupt ? 0.f : yt0;
    y_neg[(size_t)w * YDIM + c] = v0;
    feat[(size_t)w * FEATP + c] = f2bf(clip01(v0));
#pragma unroll
    for (int ch = 0; ch < 6; ++ch){
      float val = corrupt ? rvv[ch] / rsum : y_true[(size_t)b * YDIM + (ch + 1) * CELLS + c];
      y_neg[(size_t)w * YDIM + (ch + 1) * CELLS + c] = val;
      feat[(size_t)w * FEATP + (ch + 1) * CELLS + c] = f2bf(clip01(val));
    }
  }
}

// e[i] = b3 + sum_x e_part[x][i]
__global__ void k_esum(const float* __restrict__ e_part, const float* __restrict__ b3,
                       float* __restrict__ e_out, int Mc){
  int i = blockIdx.x * blockDim.x + threadIdx.x;
  if (i >= Mc) return;
  float s = b3[0];
#pragma unroll
  for (int x = 0; x < NPART; ++x) s += e_part[(size_t)x * Mc + i];
  e_out[i] = s;
}

__global__ __launch_bounds__(256) void k_contrast(const float* __restrict__ e_pos, const float* __restrict__ e_neg,
                           double* __restrict__ acc){
  double con = 0.0, reg = 0.0;
  for (int b = blockIdx.x * blockDim.x + threadIdx.x; b < B_TOT; b += gridDim.x * blockDim.x){
    float ep = e_pos[b], en = e_neg[b];
    float a = -ep, bb = -en;
    float m = fmaxf(a, bb);
    float lse = m + logf(expf(a - m) + expf(bb - m));
    con += (double)(ep + lse);
    reg += (double)ep + (double)en;
  }
  for (int off = 32; off; off >>= 1){ con += __shfl_down(con, off); reg += __shfl_down(reg, off); }
  __shared__ double wc[4], wr[4];
  int lane = threadIdx.x & 63, wid = threadIdx.x >> 6;
  if (lane == 0){ wc[wid] = con; wr[wid] = reg; }
  __syncthreads();
  if (threadIdx.x == 0){
    atomicAdd(&acc[1], (wc[0] + wc[1]) + (wc[2] + wc[3]));
    atomicAdd(&acc[2], (wr[0] + wr[1]) + (wr[2] + wr[3]));
  }
}

__global__ void k_finalize(const double* __restrict__ acc, float* __restrict__ out){
  double mse = acc[0] / (double)((long long)B_TOT * YDIM);
  double con = acc[1] / (double)B_TOT;
  double reg = acc[2] / (double)B_TOT;
  out[0] = (float)(mse + con + 0.01 * reg);
}

// ============ pipelined GEMM: BM=256, BN=256, BK=32, 4 LDS buffers, 3-deep prefetch ============
// C[M,N] = A[M,K]bf16 @ BT[N,K]bf16. 512 thr = 8 waves (2M x 4N), wave tile 128x64
// (375 B LDS-read per MFMA vs 500 at 64x64 — LDS-BW was the R6 cap).
// LDS tile [256 rows][32 k] ushort (64B rows). Slot swizzle: 16B slot s holds global
// k-chunk (s - (row>>1))&3; read slot = (kg + (fr>>1))&3 -> exactly 2 lanes/bank (free).
// Counted vmcnt: 4 loads/tile, 3 tiles in flight -> steady vmcnt(12) (T4).
// modes: 0 z1: z=v+b1 -> outA=dgz1=bf(dgelu z), outB=h1=bf(gelu z)
//        1 z2: z=v+b2 -> outB?=dz2=bf(W3*dgelu z); e_part?=row sums gelu(z)*W3
//        2 dz1: v *= bf2f(dgz[o]); outA
#define STG_T(srcPtr, p0, buf, k0) \
  _Pragma("unroll") \
  for (int ro_ = 0; ro_ < 2; ++ro_){ \
    int r_ = (ro_ << 7) + (t >> 2); \
    int ck_ = ((t & 3) - (r_ >> 1)) & 3; \
    load_lds16((const char*)(srcPtr) + (((size_t)((p0) + r_)) * K + (k0) + (ck_ << 3)) * 2, \
               (char*)(buf) + (ro_ << 13) + (t << 4)); \
  }

__global__ __launch_bounds__(512, 1) void gemm_p(
    const ushort_t* __restrict__ A, const ushort_t* __restrict__ BT,
    int N, int K, int mode,
    const float* __restrict__ bias, const float* __restrict__ W3,
    const ushort_t* __restrict__ dgz,
    ushort_t* __restrict__ outA, ushort_t* __restrict__ outB,
    float* __restrict__ e_part, int Mrows){
  __shared__ __align__(16) ushort_t As[4][256 * 32];
  __shared__ __align__(16) ushort_t Bs[4][256 * 32];
  const int t = threadIdx.x, lane = t & 63, w = t >> 6;
  int bx = blockIdx.x, by = blockIdx.y;
  xcd_swizzle(gridDim.x, gridDim.y, bx, by);
  const int m0 = by << 8, n0 = bx << 8;
  const int fr = lane & 15, kg = lane >> 4;
  const int wr = (w >> 2) << 7, wc = (w & 3) << 6;   // 2M x 4N waves, tile 128x64
  const int slot = ((kg + (fr >> 1)) & 3) << 4;      // swizzled 16B slot (byte offset)
  const int NT = K >> 5;

  float4v acc[8][4];
#pragma unroll
  for (int m = 0; m < 8; ++m)
#pragma unroll
    for (int n = 0; n < 4; ++n) acc[m][n] = (float4v)0.f;

  // prologue: stage tiles 0,1,2
  STG_T(A, m0, &As[0][0], 0); STG_T(BT, n0, &Bs[0][0], 0);
  if (NT > 1){ STG_T(A, m0, &As[1][0], 32); STG_T(BT, n0, &Bs[1][0], 32); }
  if (NT > 2){ STG_T(A, m0, &As[2][0], 64); STG_T(BT, n0, &Bs[2][0], 64); }

  for (int kt = 0; kt < NT; ++kt){
    if (kt + 3 < NT){
      const int kn = (kt + 3) << 5;
      const int bi = (kt + 3) & 3;
      STG_T(A, m0, &As[bi][0], kn); STG_T(BT, n0, &Bs[bi][0], kn);
    }
    const int rem = NT - 1 - kt;
    if (rem >= 3)      asm volatile("s_waitcnt vmcnt(12)" ::: "memory");
    else if (rem == 2) asm volatile("s_waitcnt vmcnt(8)" ::: "memory");
    else if (rem == 1) asm volatile("s_waitcnt vmcnt(4)" ::: "memory");
    else               asm volatile("s_waitcnt vmcnt(0)" ::: "memory");
    __builtin_amdgcn_s_barrier();
    __builtin_amdgcn_sched_barrier(0);

    const char* Ac = (const char*)&As[kt & 3][0];
    const char* Bc = (const char*)&Bs[kt & 3][0];
    short8v a[8], b[4];
#pragma unroll
    for (int m = 0; m < 8; ++m)
      a[m] = *(const short8v*)(Ac + ((wr + (m << 4) + fr) << 6) + slot);
#pragma unroll
    for (int n = 0; n < 4; ++n)
      b[n] = *(const short8v*)(Bc + ((wc + (n << 4) + fr) << 6) + slot);
    asm volatile("s_waitcnt lgkmcnt(0)" ::: "memory");
    __builtin_amdgcn_sched_barrier(0);
    __builtin_amdgcn_s_setprio(1);
#pragma unroll
    for (int m = 0; m < 8; ++m)
#pragma unroll
      for (int n = 0; n < 4; ++n)
        acc[m][n] = __builtin_amdgcn_mfma_f32_16x16x32_bf16(a[m], b[n], acc[m][n], 0, 0, 0);
    __builtin_amdgcn_s_setprio(0);
    __builtin_amdgcn_sched_barrier(0);
    __builtin_amdgcn_s_barrier();
    __builtin_amdgcn_sched_barrier(0);
  }

  // ---- epilogue: per-wave f32 LDS slice -> coalesced 16B bf16 stores ----
  float* slice = (float*)&As[0][0] + w * (16 * 68);
  float* e_lds = (float*)&Bs[0][0];
  const bool do_e = (mode == 1) && (e_part != nullptr);
  if (do_e){
    if (t < 256) e_lds[t] = 0.f;
    __syncthreads();
  }
  const int rrow = lane >> 2;      // 0..15
  const int rq = lane & 3;         // 16-col group
#pragma unroll
  for (int m = 0; m < 8; ++m){
    if (m) asm volatile("s_waitcnt lgkmcnt(0)" ::: "memory");  // prior reads done before overwrite
#pragma unroll
    for (int j = 0; j < 4; ++j)
#pragma unroll
      for (int n = 0; n < 4; ++n)
        slice[((kg << 2) + j) * 68 + (n << 4) + fr] = acc[m][n][j];
    asm volatile("s_waitcnt lgkmcnt(0)" ::: "memory");
    const int grow = m0 + wr + (m << 4) + rrow;
    const int gcol = n0 + wc + (rq << 4);
    float val[16];
#pragma unroll
    for (int p2 = 0; p2 < 4; ++p2){
      float4 vv = *(const float4*)&slice[rrow * 68 + (rq << 4) + (p2 << 2)];
      val[p2 * 4 + 0] = vv.x; val[p2 * 4 + 1] = vv.y;
      val[p2 * 4 + 2] = vv.z; val[p2 * 4 + 3] = vv.w;
    }
    const size_t ob = (size_t)grow * N + gcol;
    if (mode == 0){
      float o0[16], o1[16];
#pragma unroll
      for (int e = 0; e < 16; ++e){
        float z = val[e] + bias[gcol + e];
        o0[e] = dgelu_f(z);
        o1[e] = gelu_f(z);
      }
      store16(outA + ob, o0);
      store16(outB + ob, o1);
    } else if (mode == 1){
      float pe = 0.f;
      float o0[16];
#pragma unroll
      for (int e = 0; e < 16; ++e){
        float z = val[e] + bias[gcol + e];
        float w3 = W3[gcol + e];
        o0[e] = w3 * dgelu_f(z);
        if (do_e) pe += gelu_f(z) * w3;
      }
      if (outB) store16(outB + ob, o0);
      if (do_e){
        pe += __shfl_xor(pe, 1);
        pe += __shfl_xor(pe, 2);
        if (rq == 0) atomicAdd(&e_lds[wr + (m << 4) + rrow], pe);
      }
    } else {
      float o0[16];
      short8v g0 = *(const short8v*)&dgz[ob];
      short8v g1 = *(const short8v*)&dgz[ob + 8];
#pragma unroll
      for (int e = 0; e < 8; ++e){
        o0[e]     = val[e]     * bf2f((ushort_t)g0[e]);
        o0[8 + e] = val[8 + e] * bf2f((ushort_t)g1[e]);
      }
      store16(outA + ob, o0);
    }
  }
  if (do_e){
    __syncthreads();
    if (t < 256) e_part[(size_t)bx * Mrows + m0 + t] = e_lds[t];
  }
}

// ============ dy GEMM (128x128, full K) with fused mse / refine-update epilogue ============
#define DY_STAGE(Asl_, Bsl_, k0_) do { \
  _Pragma("unroll") \
  for (int i_ = 0; i_ < 4; ++i_){ \
    int c_ = i_ * 4 + w; \
    int r_ = c_ * 8 + rsub; \
    load_lds16((const char*)A + ((size_t)(m0 + r_) * K + (k0_)) * 2 + cb, (char*)(Asl_) + c_ * 1024 + lane * 16); \
    load_lds16((const char*)BT + ((size_t)(n0 + r_) * K + (k0_)) * 2 + cb, (char*)(Bsl_) + c_ * 1024 + lane * 16); \
  } } while (0)

#define DY_MFMA(Asl_, Bsl_) do { \
  _Pragma("unroll") \
  for (int kk = 0; kk < 2; ++kk){ \
    int kb = kk * 32 + kg * 8; \
    short8v a[4], b[4]; \
    _Pragma("unroll") \
    for (int m = 0; m < 4; ++m) a[m] = *(const short8v*)&(Asl_)[(wr + m * 16 + fr) * 64 + kb]; \
    _Pragma("unroll") \
    for (int n = 0; n < 4; ++n) b[n] = *(const short8v*)&(Bsl_)[(wc + n * 16 + fr) * 64 + kb]; \
    _Pragma("unroll") \
    for (int m = 0; m < 4; ++m) \
      _Pragma("unroll") \
      for (int n = 0; n < 4; ++n) \
        acc[m][n] = __builtin_amdgcn_mfma_f32_16x16x32_bf16(a[m], b[n], acc[m][n], 0, 0, 0); \
  } } while (0)

__global__ __launch_bounds__(256) void gemm_dy2(
    const ushort_t* __restrict__ A, const ushort_t* __restrict__ BT, int upd,
    float* __restrict__ yneg, ushort_t* __restrict__ feat,
    const float* __restrict__ yhat, const float* __restrict__ y_true,
    const float* __restrict__ sigma_b, double* __restrict__ acc_g){
  __shared__ __align__(16) ushort_t Asl[2][128 * 64];
  __shared__ __align__(16) ushort_t Bsl[2][128 * 64];
  const int K = HDIM;
  const int t = threadIdx.x, lane = t & 63, w = t >> 6;
  int bx = blockIdx.x, by = blockIdx.y;
  xcd_swizzle(gridDim.x, gridDim.y, bx, by);
  const int m0 = by << 7, n0 = bx << 7;
  const int fr = lane & 15, kg = lane >> 4;
  const int rsub = lane >> 3;
  const int cb = (lane & 7) * 16;
  const int wr = (w >> 1) * 64, wc = (w & 1) * 64;

  float4v acc[4][4];
#pragma unroll
  for (int m = 0; m < 4; ++m)
#pragma unroll
    for (int n = 0; n < 4; ++n) acc[m][n] = (float4v)0.f;

  DY_STAGE(Asl[0], Bsl[0], 0);
  __syncthreads();
  int cur = 0;
  for (int k0 = 0; k0 < K; k0 += 64){
    if (k0 + 64 < K) DY_STAGE(Asl[cur ^ 1], Bsl[cur ^ 1], k0 + 64);
    DY_MFMA(Asl[cur], Bsl[cur]);
    __syncthreads();
    cur ^= 1;
  }

  double ms = 0.0;
#pragma unroll
  for (int m = 0; m < 4; ++m){
#pragma unroll
    for (int j = 0; j < 4; ++j){
      int row = m0 + wr + m * 16 + kg * 4 + j;
#pragma unroll
      for (int n = 0; n < 4; ++n){
        int col = n0 + wc + n * 16 + fr;
        if (col < YDIM){
          size_t o = (size_t)row * YDIM + col;
          float g = acc[m][n][j];
          if (upd){
            float y = yneg[o];
            y = clip01(y + 0.15f * g * clipmask(y));
            yneg[o] = y;
            feat[(size_t)row * FEATP + col] = f2bf(y);
          } else {
            float y = yhat[o];
            float score = g * clipmask(y);
            float tgt = (y - y_true[o]) / (sigma_b[row] + 1e-8f);
            float d = score - tgt;
            ms += (double)d * (double)d;
          }
        }
      }
    }
  }
  if (!upd){
    for (int off = 32; off; off >>= 1) ms += __shfl_down(ms, off);
    __shared__ double wsum[4];
    int wid = t >> 6;
    if ((t & 63) == 0) wsum[wid] = ms;
    __syncthreads();
    if (t == 0) atomicAdd(&acc_g[0], (wsum[0] + wsum[1]) + (wsum[2] + wsum[3]));
  }
}

// ---------------- host ----------------
static inline char* carve(char*& p, size_t bytes){
  char* r = p; p += (bytes + 255) & ~(size_t)255; return r;
}

extern "C" void kernel_launch(void* const* d_in, const int* in_sizes, int n_in,
                              void* d_out, int out_size, void* d_ws, size_t ws_size,
                              hipStream_t stream){
  (void)in_sizes; (void)n_in; (void)out_size;
  const float* y_true  = (const float*)d_in[0];
  const float* cond    = (const float*)d_in[1];
  const int*   k_idx   = (const int*)d_in[2];
  const float* eps_pos = (const float*)d_in[3];
  const float* eps_neg = (const float*)d_in[4];
  const float* sel     = (const float*)d_in[5];
  const float* rv      = (const float*)d_in[6];
  const float* W1      = (const float*)d_in[7];
  const float* b1      = (const float*)d_in[8];
  const float* W2      = (const float*)d_in[9];
  const float* b2      = (const float*)d_in[10];
  const float* W3      = (const float*)d_in[11];
  const float* b3      = (const float*)d_in[12];
  const float* k_emb   = (const float*)d_in[13];

  char* p = (char*)d_ws;
  double* accs   = (double*)carve(p, 3 * sizeof(double));
  float* sigma_b = (float*)carve(p, (size_t)B_TOT * 4);
  float* e_pos   = (float*)carve(p, (size_t)B_TOT * 4);
  float* e_neg   = (float*)carve(p, (size_t)B_TOT * 4);
  ushort_t* W1bf = (ushort_t*)carve(p, (size_t)256 * HDIM * 2);   // rows 0..255 of W1 (dy B^T)
  ushort_t* W1T  = (ushort_t*)carve(p, (size_t)HDIM * FEATP * 2);
  ushort_t* W2bf = (ushort_t*)carve(p, (size_t)HDIM * HDIM * 2);
  ushort_t* W2T  = (ushort_t*)carve(p, (size_t)HDIM * HDIM * 2);
  size_t fixed = (size_t)(p - (char*)d_ws);

  // per sample: feat 896 + 3 H-planes (dgz1,h1,dz2) 12288 + e_part 32 + yhat/yneg 2016
  const size_t per_sample = FEATP * 2 + 3 * HDIM * 2 + NPART * 4 + 2 * YDIM * 4;
  int Mc = B_TOT;
  while (Mc > 256 && fixed + (size_t)Mc * per_sample + 65536 > ws_size) Mc >>= 1;

  ushort_t* feat = (ushort_t*)carve(p, (size_t)Mc * FEATP * 2);
  ushort_t* dgz1 = (ushort_t*)carve(p, (size_t)Mc * HDIM * 2);
  ushort_t* h1   = (ushort_t*)carve(p, (size_t)Mc * HDIM * 2);
  ushort_t* dz2  = (ushort_t*)carve(p, (size_t)Mc * HDIM * 2);
  float* e_part  = (float*)carve(p, (size_t)Mc * NPART * 4);
  float* yhat    = (float*)carve(p, (size_t)Mc * YDIM * 4);
  float* yneg    = (float*)carve(p, (size_t)Mc * YDIM * 4);
  ushort_t* dz1  = h1;   // alias: h1 dead once the z2-GEMM consumed it

  dim3 blk(256);
  k_zero_acc<<<1, 1, 0, stream>>>(accs);
  k_sigma<<<(B_TOT + 255) / 256, blk, 0, stream>>>(k_idx, sigma_b);
  k_cast<<<(256 * HDIM + 255) / 256, blk, 0, stream>>>(W1, W1bf, 256 * HDIM);
  k_w1t<<<(HDIM * FEATP + 255) / 256, blk, 0, stream>>>(W1, W1T);
  k_cast<<<(HDIM * HDIM + 255) / 256, blk, 0, stream>>>(W2, W2bf, HDIM * HDIM);
  k_w2t<<<dim3(HDIM / 32, HDIM / 32), blk, 0, stream>>>(W2, W2T);

  auto G = [&](const ushort_t* Ap, const ushort_t* BTp, int K, int mode,
               const float* biasp, ushort_t* oA, ushort_t* oB, float* ep){
    gemm_p<<<dim3(HDIM / 256, Mc / 256), dim3(512), 0, stream>>>(
        Ap, BTp, HDIM, K, mode, biasp, W3, dgz1, oA, oB, ep, Mc);
  };
  auto Gdy = [&](int upd, const float* yh, const float* yt, const float* sg){
    gemm_dy2<<<dim3(2, Mc / 128), blk, 0, stream>>>(
        dz1, W1bf, upd, yneg, feat, yh, yt, sg, accs);
  };

  int nCh = B_TOT / Mc;
  for (int c = 0; c < nCh; ++c){
    int b0 = c * Mc;
    k_feat_static<<<(Mc * 196 + 255) / 256, blk, 0, stream>>>(
        cond + (size_t)b0 * CELLS, k_emb, k_idx + b0, feat, Mc);

    // ---- positive branch
    k_noise<<<(Mc * CELLS + 255) / 256, blk, 0, stream>>>(
        y_true + (size_t)b0 * YDIM, eps_pos + (size_t)b0 * YDIM, sigma_b + b0, yhat, feat, Mc);
    G(feat, W1T, FEATP, 0, b1, dgz1, h1, nullptr);
    G(h1, W2T, HDIM, 1, b2, nullptr, dz2, e_part);
    k_esum<<<(Mc + 255) / 256, blk, 0, stream>>>(e_part, b3, e_pos + b0, Mc);
    G(dz2, W2bf, HDIM, 2, nullptr, dz1, nullptr, nullptr);
    Gdy(0, yhat, y_true + (size_t)b0 * YDIM, sigma_b + b0);

    // ---- negative branch
    k_makeneg<<<(Mc * 64 + 255) / 256, blk, 0, stream>>>(y_true, sel, rv, yneg, feat, b0, Mc);
    for (int r = 0; r < 5; ++r){
      G(feat, W1T, FEATP, 0, b1, dgz1, h1, nullptr);
      G(h1, W2T, HDIM, 1, b2, nullptr, dz2, nullptr);
      G(dz2, W2bf, HDIM, 2, nullptr, dz1, nullptr, nullptr);
      Gdy(1, nullptr, nullptr, nullptr);
    }
    k_noise<<<(Mc * CELLS + 255) / 256, blk, 0, stream>>>(
        yneg, eps_neg + (size_t)b0 * YDIM, sigma_b + b0, yhat, feat, Mc);
    G(feat, W1T, FEATP, 0, b1, dgz1, h1, nullptr);
    G(h1, W2T, HDIM, 1, b2, nullptr, nullptr, e_part);
    k_esum<<<(Mc + 255) / 256, blk, 0, stream>>>(e_part, b3, e_neg + b0, Mc);
  }

  k_contrast<<<64, blk, 0, stream>>>(e_pos, e_neg, accs);
  k_finalize<<<1, 1, 0, stream>>>(accs, (float*)d_out);
}

// Round 8
// 3779.823 us; speedup vs baseline: 1.5774x; 1.0522x over previous
//
#include <hip/hip_runtime.h>
#include <math.h>

#define B_TOT 16384
#define CELLS 36
#define YDIM 252       // 7*6*6
#define FEATP 448      // 416 padded to 448
#define FEAT_REAL 416
#define HDIM 2048
#define EMB_DIM 128
#define KSTEPS 50
#define NPART 8        // e_part slabs = HDIM/256

typedef unsigned short ushort_t;
typedef __attribute__((ext_vector_type(8))) short short8v;
typedef __attribute__((ext_vector_type(4))) float float4v;

__device__ __forceinline__ float clip01(float x){ return fminf(fmaxf(x, 0.f), 1.f); }
__device__ __forceinline__ float tanh_fast(float u){
  float e = __expf(2.f * u);
  return 1.f - 2.f / (e + 1.f);
}
__device__ __forceinline__ float gelu_f(float x){
  float u = 0.7978845608028654f * (x + 0.044715f * x * x * x);
  return 0.5f * x * (1.f + tanh_fast(u));
}
__device__ __forceinline__ float dgelu_f(float x){
  float x2 = x * x;
  float u = 0.7978845608028654f * (x + 0.044715f * x2 * x);
  float t = tanh_fast(u);
  return 0.5f * (1.f + t) + 0.5f * x * (1.f - t * t) * 0.7978845608028654f * (1.f + 0.134145f * x2);
}
__device__ __forceinline__ float clipmask(float y){ return (y == 0.f || y == 1.f) ? 0.5f : 1.f; }
__device__ __forceinline__ ushort_t f2bf(float x){
  union { float f; unsigned u; } v; v.f = x;
  unsigned r = v.u + 0x7fffu + ((v.u >> 16) & 1u);
  return (ushort_t)(r >> 16);
}
__device__ __forceinline__ float bf2f(ushort_t h){
  union { unsigned u; float f; } v; v.u = ((unsigned)h) << 16; return v.f;
}
__device__ __forceinline__ void load_lds16(const void* g, void* l){
  __builtin_amdgcn_global_load_lds((const __attribute__((address_space(1))) unsigned int*)g,
                                   (__attribute__((address_space(3))) unsigned int*)l, 16, 0, 0);
}
__device__ __forceinline__ void store16(ushort_t* dst, const float* x){
  short8v r0, r1;
#pragma unroll
  for (int i = 0; i < 8; ++i){ r0[i] = (short)f2bf(x[i]); r1[i] = (short)f2bf(x[8 + i]); }
  *(short8v*)dst = r0;
  *(short8v*)&dst[8] = r1;
}
// m204 bijective XCD swizzle
__device__ __forceinline__ void xcd_swizzle(int GX, int GY, int& bx, int& by){
  int nwg = GX * GY;
  int orig = by * GX + bx;
  int q = nwg >> 3, r = nwg & 7;
  int xcd = orig & 7, loc = orig >> 3;
  int lin = (xcd < r ? xcd * (q + 1) : r * (q + 1) + (xcd - r) * q) + loc;
  bx = lin % GX; by = lin / GX;
}

// ---------------- small kernels ----------------
__global__ void k_zero_acc(double* acc){ acc[0] = 0.0; acc[1] = 0.0; acc[2] = 0.0; }

__global__ void k_sigma(const int* __restrict__ k_idx, float* __restrict__ sigma_b){
  int b = blockIdx.x * blockDim.x + threadIdx.x;
  if (b >= B_TOT) return;
  int i = (KSTEPS - 1) - k_idx[b];
  float t = (float)i / (float)(KSTEPS - 1);
  float ang = (1.f - t) * 1.57079632679489662f;
  float c = cosf(ang);
  sigma_b[b] = 0.01f + 0.94f * c * c;
}

__global__ void k_cast(const float* __restrict__ in, ushort_t* __restrict__ out, int n){
  int gid = blockIdx.x * blockDim.x + threadIdx.x;
  if (gid < n) out[gid] = f2bf(in[gid]);
}
// W1T[h][f] (f padded to 448)
__global__ void k_w1t(const float* __restrict__ W1, ushort_t* __restrict__ W1T){
  int gid = blockIdx.x * blockDim.x + threadIdx.x;
  if (gid >= HDIM * FEATP) return;
  int h = gid / FEATP, f = gid - h * FEATP;
  W1T[gid] = (f < FEAT_REAL) ? f2bf(W1[(size_t)f * HDIM + h]) : (ushort_t)0;
}
// tiled transpose: W2T[n][k] = W2[k][n]
__global__ __launch_bounds__(256) void k_w2t(const float* __restrict__ W2, ushort_t* __restrict__ W2T){
  __shared__ float tile[32][33];
  int x0 = blockIdx.x << 5, y0 = blockIdx.y << 5;
  int tx = threadIdx.x & 31, ty = threadIdx.x >> 5;
#pragma unroll
  for (int i = 0; i < 4; ++i)
    tile[ty + i * 8][tx] = W2[(size_t)(y0 + ty + i * 8) * HDIM + (x0 + tx)];
  __syncthreads();
#pragma unroll
  for (int i = 0; i < 4; ++i)
    W2T[(size_t)(x0 + ty + i * 8) * HDIM + (y0 + tx)] = f2bf(tile[tx][ty + i * 8]);
}

// static cols of feat: 252..447 (cond, emb, zero pad)
__global__ void k_feat_static(const float* __restrict__ cond, const float* __restrict__ k_emb,
                              const int* __restrict__ k_idx, ushort_t* __restrict__ feat, int Mc){
  int gid = blockIdx.x * blockDim.x + threadIdx.x;
  if (gid >= Mc * 196) return;
  int i = gid / 196, c = gid - i * 196;
  float v;
  if (c < CELLS)            v = cond[(size_t)i * CELLS + c];
  else if (c < CELLS + EMB_DIM) v = k_emb[(size_t)k_idx[i] * EMB_DIM + (c - CELLS)];
  else                      v = 0.f;
  feat[(size_t)i * FEATP + YDIM + c] = f2bf(v);
}

// noise + direct feat write
__global__ void k_noise(const float* __restrict__ y, const float* __restrict__ eps,
                        const float* __restrict__ sigma_b, float* __restrict__ out,
                        ushort_t* __restrict__ feat, int Mc){
  int gid = blockIdx.x * blockDim.x + threadIdx.x;
  if (gid >= Mc * CELLS) return;
  int i = gid / CELLS, cell = gid - i * CELLS;
  float sigma = sigma_b[i];
  float sq = sqrtf(fmaxf(1.f - sigma * sigma, 1e-8f));
  const float* yp = y + (size_t)i * YDIM + cell;
  const float* ep = eps + (size_t)i * YDIM + cell;
  float yh[7];
#pragma unroll
  for (int ch = 0; ch < 7; ++ch){
    float e = ep[ch * CELLS] * 0.1f;
    yh[ch] = clip01(sq * yp[ch * CELLS] + sigma * e);
  }
  bool filled = yh[0] > 0.5f;
  float s = 0.f;
#pragma unroll
  for (int ch = 1; ch < 7; ++ch) s += yh[ch];
  float* op = out + (size_t)i * YDIM + cell;
  ushort_t* fp = feat + (size_t)i * FEATP + cell;
  op[0] = yh[0];
  fp[0] = f2bf(yh[0]);
#pragma unroll
  for (int ch = 1; ch < 7; ++ch){
    float v = yh[ch];
    if (filled) v = v / (s + 1e-8f);
    v = clip01(v);
    op[ch * CELLS] = v;
    fp[ch * CELLS] = f2bf(v);
  }
}

// y_neg init + feat write
__global__ void k_makeneg(const float* __restrict__ y_true, const float* __restrict__ sel,
                          const float* __restrict__ rv, float* __restrict__ y_neg,
                          ushort_t* __restrict__ feat, int b0, int Mc){
  int w = (blockIdx.x * blockDim.x + threadIdx.x) >> 6;
  int lane = threadIdx.x & 63;
  if (w >= Mc) return;
  int b = b0 + w;
  int c = lane;
  bool active = c < CELLS;
  float yt0 = active ? y_true[(size_t)b * YDIM + c] : 0.f;
  bool filled = active && (yt0 > 0.5f);
  unsigned long long bal = __ballot(filled);
  int n_filled = __popcll(bal);
  int num_c = (int)floorf((float)n_filled * 0.3f);
  int idx = num_c - 1; if (idx < 0) idx = 0;
  float score = filled ? sel[(size_t)b * CELLS + c] : 2.0f;
  int cnt_lt = 0, cnt_le = 0;
  for (int l = 0; l < CELLS; ++l){
    float sv = __shfl(score, l);
    cnt_lt += (sv < score);
    cnt_le += (sv <= score);
  }
  float cand = (active && cnt_lt <= idx && idx < cnt_le) ? score : 3.4e38f;
  for (int off = 32; off; off >>= 1) cand = fminf(cand, __shfl_xor(cand, off));
  float thr = (num_c > 0) ? cand : -1.0f;
  bool corrupt = filled && (score <= thr);
  if (active){
    float rvv[6]; float rsum = 0.f;
#pragma unroll
    for (int ch = 0; ch < 6; ++ch){ rvv[ch] = rv[(size_t)b * (6 * CELLS) + ch * CELLS + c]; rsum += rvv[ch]; }
    float v0 = corrupt ? 0.f : yt0;
    y_neg[(size_t)w * YDIM + c] = v0;
    feat[(size_t)w * FEATP + c] = f2bf(clip01(v0));
#pragma unroll
    for (int ch = 0; ch < 6; ++ch){
      float val = corrupt ? rvv[ch] / rsum : y_true[(size_t)b * YDIM + (ch + 1) * CELLS + c];
      y_neg[(size_t)w * YDIM + (ch + 1) * CELLS + c] = val;
      feat[(size_t)w * FEATP + (ch + 1) * CELLS + c] = f2bf(clip01(val));
    }
  }
}

// e[i] = b3 + sum_x e_part[x][i]
__global__ void k_esum(const float* __restrict__ e_part, const float* __restrict__ b3,
                       float* __restrict__ e_out, int Mc){
  int i = blockIdx.x * blockDim.x + threadIdx.x;
  if (i >= Mc) return;
  float s = b3[0];
#pragma unroll
  for (int x = 0; x < NPART; ++x) s += e_part[(size_t)x * Mc + i];
  e_out[i] = s;
}

__global__ __launch_bounds__(256) void k_contrast(const float* __restrict__ e_pos, const float* __restrict__ e_neg,
                           double* __restrict__ acc){
  double con = 0.0, reg = 0.0;
  for (int b = blockIdx.x * blockDim.x + threadIdx.x; b < B_TOT; b += gridDim.x * blockDim.x){
    float ep = e_pos[b], en = e_neg[b];
    float a = -ep, bb = -en;
    float m = fmaxf(a, bb);
    float lse = m + logf(expf(a - m) + expf(bb - m));
    con += (double)(ep + lse);
    reg += (double)ep + (double)en;
  }
  for (int off = 32; off; off >>= 1){ con += __shfl_down(con, off); reg += __shfl_down(reg, off); }
  __shared__ double wc[4], wr[4];
  int lane = threadIdx.x & 63, wid = threadIdx.x >> 6;
  if (lane == 0){ wc[wid] = con; wr[wid] = reg; }
  __syncthreads();
  if (threadIdx.x == 0){
    atomicAdd(&acc[1], (wc[0] + wc[1]) + (wc[2] + wc[3]));
    atomicAdd(&acc[2], (wr[0] + wr[1]) + (wr[2] + wr[3]));
  }
}

__global__ void k_finalize(const double* __restrict__ acc, float* __restrict__ out){
  double mse = acc[0] / (double)((long long)B_TOT * YDIM);
  double con = acc[1] / (double)B_TOT;
  double reg = acc[2] / (double)B_TOT;
  out[0] = (float)(mse + con + 0.01 * reg);
}

// ============ pipelined GEMM: BM=256, BN=256, BK=32, 4 LDS bufs, 3-deep global prefetch,
// ============ register double-buffered fragments (ds_read of tile k+1 overlaps MFMA of k) ====
// C[M,N] = A[M,K]bf16 @ BT[N,K]bf16. 512 thr = 8 waves (2M x 4N), wave tile 128x64.
// Derived waits: vmcnt(8) -> tile kt+1 staged (2 tiles stay in flight);
//                lgkmcnt(12) -> tile kt's 12 frag reads done (kt+1's 12 stay in flight).
// modes: 0 z1: z=v+b1 -> outA=dgz1=bf(dgelu z), outB=h1=bf(gelu z)
//        1 z2: z=v+b2 -> outB?=dz2=bf(W3*dgelu z); e_part?=row sums gelu(z)*W3
//        2 dz1: v *= bf2f(dgz[o]); outA
#define STG_T(srcPtr, p0, buf, k0) \
  _Pragma("unroll") \
  for (int ro_ = 0; ro_ < 2; ++ro_){ \
    int r_ = (ro_ << 7) + (t >> 2); \
    int ck_ = ((t & 3) - (r_ >> 1)) & 3; \
    load_lds16((const char*)(srcPtr) + (((size_t)((p0) + r_)) * K + (k0) + (ck_ << 3)) * 2, \
               (char*)(buf) + (ro_ << 13) + (t << 4)); \
  }

#define FRAG_RD(bi, RA, RB) do { \
  const char* An_ = (const char*)&As[bi][0]; \
  const char* Bn_ = (const char*)&Bs[bi][0]; \
  _Pragma("unroll") \
  for (int m_ = 0; m_ < 8; ++m_) \
    RA[m_] = *(const short8v*)(An_ + ((wr + (m_ << 4) + fr) << 6) + slot); \
  _Pragma("unroll") \
  for (int n_ = 0; n_ < 4; ++n_) \
    RB[n_] = *(const short8v*)(Bn_ + ((wc + (n_ << 4) + fr) << 6) + slot); \
} while (0)

// One K-tile: stage kt+3, ensure kt+1 staged, read kt+1 frags into (NA,NB),
// wait prior frag reads (CA,CB ready), MFMA on (CA,CB).
#define GP_TILE(ktv, CA, CB, NA, NB) do { \
  const int kt_ = (ktv); \
  if (kt_ + 3 < NT){ \
    const int kn_ = (kt_ + 3) << 5; \
    const int bi_ = (kt_ + 3) & 3; \
    STG_T(A, m0, &As[bi_][0], kn_); STG_T(BT, n0, &Bs[bi_][0], kn_); \
  } \
  { const int rem_ = NT - 2 - kt_; \
    if (rem_ >= 2)      asm volatile("s_waitcnt vmcnt(8)" ::: "memory"); \
    else if (rem_ == 1) asm volatile("s_waitcnt vmcnt(4)" ::: "memory"); \
    else                asm volatile("s_waitcnt vmcnt(0)" ::: "memory"); } \
  __builtin_amdgcn_s_barrier(); \
  __builtin_amdgcn_sched_barrier(0); \
  if (kt_ + 1 < NT){ \
    FRAG_RD((kt_ + 1) & 3, NA, NB); \
    asm volatile("s_waitcnt lgkmcnt(12)" ::: "memory"); \
  } else { \
    asm volatile("s_waitcnt lgkmcnt(0)" ::: "memory"); \
  } \
  __builtin_amdgcn_sched_barrier(0); \
  __builtin_amdgcn_s_setprio(1); \
  _Pragma("unroll") \
  for (int m_ = 0; m_ < 8; ++m_) \
    _Pragma("unroll") \
    for (int n_ = 0; n_ < 4; ++n_) \
      acc[m_][n_] = __builtin_amdgcn_mfma_f32_16x16x32_bf16(CA[m_], CB[n_], acc[m_][n_], 0, 0, 0); \
  __builtin_amdgcn_s_setprio(0); \
  __builtin_amdgcn_sched_barrier(0); \
  __builtin_amdgcn_s_barrier(); \
} while (0)

__global__ __launch_bounds__(512, 1) void gemm_p(
    const ushort_t* __restrict__ A, const ushort_t* __restrict__ BT,
    int N, int K, int mode,
    const float* __restrict__ bias, const float* __restrict__ W3,
    const ushort_t* __restrict__ dgz,
    ushort_t* __restrict__ outA, ushort_t* __restrict__ outB,
    float* __restrict__ e_part, int Mrows){
  __shared__ __align__(16) ushort_t As[4][256 * 32];
  __shared__ __align__(16) ushort_t Bs[4][256 * 32];
  const int t = threadIdx.x, lane = t & 63, w = t >> 6;
  int bx = blockIdx.x, by = blockIdx.y;
  xcd_swizzle(gridDim.x, gridDim.y, bx, by);
  const int m0 = by << 8, n0 = bx << 8;
  const int fr = lane & 15, kg = lane >> 4;
  const int wr = (w >> 2) << 7, wc = (w & 3) << 6;   // 2M x 4N waves, tile 128x64
  const int slot = ((kg + (fr >> 1)) & 3) << 4;      // swizzled 16B slot (byte offset)
  const int NT = K >> 5;                             // NT even for all K used (14, 64)

  float4v acc[8][4];
#pragma unroll
  for (int m = 0; m < 8; ++m)
#pragma unroll
    for (int n = 0; n < 4; ++n) acc[m][n] = (float4v)0.f;

  short8v raa[8], rab[4], rba[8], rbb[4];

  // prologue: stage tiles 0,1,2; read tile-0 fragments
  STG_T(A, m0, &As[0][0], 0); STG_T(BT, n0, &Bs[0][0], 0);
  if (NT > 1){ STG_T(A, m0, &As[1][0], 32); STG_T(BT, n0, &Bs[1][0], 32); }
  if (NT > 2){ STG_T(A, m0, &As[2][0], 64); STG_T(BT, n0, &Bs[2][0], 64); }
  if (NT > 2)      asm volatile("s_waitcnt vmcnt(8)" ::: "memory");
  else if (NT > 1) asm volatile("s_waitcnt vmcnt(4)" ::: "memory");
  else             asm volatile("s_waitcnt vmcnt(0)" ::: "memory");
  __builtin_amdgcn_s_barrier();
  __builtin_amdgcn_sched_barrier(0);
  FRAG_RD(0, raa, rab);

  for (int kt = 0; kt < NT; kt += 2){
    GP_TILE(kt,     raa, rab, rba, rbb);
    GP_TILE(kt + 1, rba, rbb, raa, rab);
  }

  // ---- epilogue: per-wave f32 LDS slice -> coalesced 16B bf16 stores ----
  float* slice = (float*)&As[0][0] + w * (16 * 68);
  float* e_lds = (float*)&Bs[0][0];
  const bool do_e = (mode == 1) && (e_part != nullptr);
  if (do_e){
    if (t < 256) e_lds[t] = 0.f;
    __syncthreads();
  }
  const int rrow = lane >> 2;      // 0..15
  const int rq = lane & 3;         // 16-col group
#pragma unroll
  for (int m = 0; m < 8; ++m){
    if (m) asm volatile("s_waitcnt lgkmcnt(0)" ::: "memory");  // prior reads done before overwrite
#pragma unroll
    for (int j = 0; j < 4; ++j)
#pragma unroll
      for (int n = 0; n < 4; ++n)
        slice[((kg << 2) + j) * 68 + (n << 4) + fr] = acc[m][n][j];
    asm volatile("s_waitcnt lgkmcnt(0)" ::: "memory");
    const int grow = m0 + wr + (m << 4) + rrow;
    const int gcol = n0 + wc + (rq << 4);
    float val[16];
#pragma unroll
    for (int p2 = 0; p2 < 4; ++p2){
      float4 vv = *(const float4*)&slice[rrow * 68 + (rq << 4) + (p2 << 2)];
      val[p2 * 4 + 0] = vv.x; val[p2 * 4 + 1] = vv.y;
      val[p2 * 4 + 2] = vv.z; val[p2 * 4 + 3] = vv.w;
    }
    const size_t ob = (size_t)grow * N + gcol;
    if (mode == 0){
      float o0[16], o1[16];
#pragma unroll
      for (int e = 0; e < 16; ++e){
        float z = val[e] + bias[gcol + e];
        o0[e] = dgelu_f(z);
        o1[e] = gelu_f(z);
      }
      store16(outA + ob, o0);
      store16(outB + ob, o1);
    } else if (mode == 1){
      float pe = 0.f;
      float o0[16];
#pragma unroll
      for (int e = 0; e < 16; ++e){
        float z = val[e] + bias[gcol + e];
        float w3 = W3[gcol + e];
        o0[e] = w3 * dgelu_f(z);
        if (do_e) pe += gelu_f(z) * w3;
      }
      if (outB) store16(outB + ob, o0);
      if (do_e){
        pe += __shfl_xor(pe, 1);
        pe += __shfl_xor(pe, 2);
        if (rq == 0) atomicAdd(&e_lds[wr + (m << 4) + rrow], pe);
      }
    } else {
      float o0[16];
      short8v g0 = *(const short8v*)&dgz[ob];
      short8v g1 = *(const short8v*)&dgz[ob + 8];
#pragma unroll
      for (int e = 0; e < 8; ++e){
        o0[e]     = val[e]     * bf2f((ushort_t)g0[e]);
        o0[8 + e] = val[8 + e] * bf2f((ushort_t)g1[e]);
      }
      store16(outA + ob, o0);
    }
  }
  if (do_e){
    __syncthreads();
    if (t < 256) e_part[(size_t)bx * Mrows + m0 + t] = e_lds[t];
  }
}

// ============ dy GEMM (128x128, full K) with fused mse / refine-update epilogue ============
#define DY_STAGE(Asl_, Bsl_, k0_) do { \
  _Pragma("unroll") \
  for (int i_ = 0; i_ < 4; ++i_){ \
    int c_ = i_ * 4 + w; \
    int r_ = c_ * 8 + rsub; \
    load_lds16((const char*)A + ((size_t)(m0 + r_) * K + (k0_)) * 2 + cb, (char*)(Asl_) + c_ * 1024 + lane * 16); \
    load_lds16((const char*)BT + ((size_t)(n0 + r_) * K + (k0_)) * 2 + cb, (char*)(Bsl_) + c_ * 1024 + lane * 16); \
  } } while (0)

#define DY_MFMA(Asl_, Bsl_) do { \
  _Pragma("unroll") \
  for (int kk = 0; kk < 2; ++kk){ \
    int kb = kk * 32 + kg * 8; \
    short8v a[4], b[4]; \
    _Pragma("unroll") \
    for (int m = 0; m < 4; ++m) a[m] = *(const short8v*)&(Asl_)[(wr + m * 16 + fr) * 64 + kb]; \
    _Pragma("unroll") \
    for (int n = 0; n < 4; ++n) b[n] = *(const short8v*)&(Bsl_)[(wc + n * 16 + fr) * 64 + kb]; \
    _Pragma("unroll") \
    for (int m = 0; m < 4; ++m) \
      _Pragma("unroll") \
      for (int n = 0; n < 4; ++n) \
        acc[m][n] = __builtin_amdgcn_mfma_f32_16x16x32_bf16(a[m], b[n], acc[m][n], 0, 0, 0); \
  } } while (0)

__global__ __launch_bounds__(256) void gemm_dy2(
    const ushort_t* __restrict__ A, const ushort_t* __restrict__ BT, int upd,
    float* __restrict__ yneg, ushort_t* __restrict__ feat,
    const float* __restrict__ yhat, const float* __restrict__ y_true,
    const float* __restrict__ sigma_b, double* __restrict__ acc_g){
  __shared__ __align__(16) ushort_t Asl[2][128 * 64];
  __shared__ __align__(16) ushort_t Bsl[2][128 * 64];
  const int K = HDIM;
  const int t = threadIdx.x, lane = t & 63, w = t >> 6;
  int bx = blockIdx.x, by = blockIdx.y;
  xcd_swizzle(gridDim.x, gridDim.y, bx, by);
  const int m0 = by << 7, n0 = bx << 7;
  const int fr = lane & 15, kg = lane >> 4;
  const int rsub = lane >> 3;
  const int cb = (lane & 7) * 16;
  const int wr = (w >> 1) * 64, wc = (w & 1) * 64;

  float4v acc[4][4];
#pragma unroll
  for (int m = 0; m < 4; ++m)
#pragma unroll
    for (int n = 0; n < 4; ++n) acc[m][n] = (float4v)0.f;

  DY_STAGE(Asl[0], Bsl[0], 0);
  __syncthreads();
  int cur = 0;
  for (int k0 = 0; k0 < K; k0 += 64){
    if (k0 + 64 < K) DY_STAGE(Asl[cur ^ 1], Bsl[cur ^ 1], k0 + 64);
    DY_MFMA(Asl[cur], Bsl[cur]);
    __syncthreads();
    cur ^= 1;
  }

  double ms = 0.0;
#pragma unroll
  for (int m = 0; m < 4; ++m){
#pragma unroll
    for (int j = 0; j < 4; ++j){
      int row = m0 + wr + m * 16 + kg * 4 + j;
#pragma unroll
      for (int n = 0; n < 4; ++n){
        int col = n0 + wc + n * 16 + fr;
        if (col < YDIM){
          size_t o = (size_t)row * YDIM + col;
          float g = acc[m][n][j];
          if (upd){
            float y = yneg[o];
            y = clip01(y + 0.15f * g * clipmask(y));
            yneg[o] = y;
            feat[(size_t)row * FEATP + col] = f2bf(y);
          } else {
            float y = yhat[o];
            float score = g * clipmask(y);
            float tgt = (y - y_true[o]) / (sigma_b[row] + 1e-8f);
            float d = score - tgt;
            ms += (double)d * (double)d;
          }
        }
      }
    }
  }
  if (!upd){
    for (int off = 32; off; off >>= 1) ms += __shfl_down(ms, off);
    __shared__ double wsum[4];
    int wid = t >> 6;
    if ((t & 63) == 0) wsum[wid] = ms;
    __syncthreads();
    if (t == 0) atomicAdd(&acc_g[0], (wsum[0] + wsum[1]) + (wsum[2] + wsum[3]));
  }
}

// ---------------- host ----------------
static inline char* carve(char*& p, size_t bytes){
  char* r = p; p += (bytes + 255) & ~(size_t)255; return r;
}

extern "C" void kernel_launch(void* const* d_in, const int* in_sizes, int n_in,
                              void* d_out, int out_size, void* d_ws, size_t ws_size,
                              hipStream_t stream){
  (void)in_sizes; (void)n_in; (void)out_size;
  const float* y_true  = (const float*)d_in[0];
  const float* cond    = (const float*)d_in[1];
  const int*   k_idx   = (const int*)d_in[2];
  const float* eps_pos = (const float*)d_in[3];
  const float* eps_neg = (const float*)d_in[4];
  const float* sel     = (const float*)d_in[5];
  const float* rv      = (const float*)d_in[6];
  const float* W1      = (const float*)d_in[7];
  const float* b1      = (const float*)d_in[8];
  const float* W2      = (const float*)d_in[9];
  const float* b2      = (const float*)d_in[10];
  const float* W3      = (const float*)d_in[11];
  const float* b3      = (const float*)d_in[12];
  const float* k_emb   = (const float*)d_in[13];

  char* p = (char*)d_ws;
  double* accs   = (double*)carve(p, 3 * sizeof(double));
  float* sigma_b = (float*)carve(p, (size_t)B_TOT * 4);
  float* e_pos   = (float*)carve(p, (size_t)B_TOT * 4);
  float* e_neg   = (float*)carve(p, (size_t)B_TOT * 4);
  ushort_t* W1bf = (ushort_t*)carve(p, (size_t)256 * HDIM * 2);   // rows 0..255 of W1 (dy B^T)
  ushort_t* W1T  = (ushort_t*)carve(p, (size_t)HDIM * FEATP * 2);
  ushort_t* W2bf = (ushort_t*)carve(p, (size_t)HDIM * HDIM * 2);
  ushort_t* W2T  = (ushort_t*)carve(p, (size_t)HDIM * HDIM * 2);
  size_t fixed = (size_t)(p - (char*)d_ws);

  // per sample: feat 896 + 3 H-planes (dgz1,h1,dz2) 12288 + e_part 32 + yhat/yneg 2016
  const size_t per_sample = FEATP * 2 + 3 * HDIM * 2 + NPART * 4 + 2 * YDIM * 4;
  int Mc = B_TOT;
  while (Mc > 256 && fixed + (size_t)Mc * per_sample + 65536 > ws_size) Mc >>= 1;

  ushort_t* feat = (ushort_t*)carve(p, (size_t)Mc * FEATP * 2);
  ushort_t* dgz1 = (ushort_t*)carve(p, (size_t)Mc * HDIM * 2);
  ushort_t* h1   = (ushort_t*)carve(p, (size_t)Mc * HDIM * 2);
  ushort_t* dz2  = (ushort_t*)carve(p, (size_t)Mc * HDIM * 2);
  float* e_part  = (float*)carve(p, (size_t)Mc * NPART * 4);
  float* yhat    = (float*)carve(p, (size_t)Mc * YDIM * 4);
  float* yneg    = (float*)carve(p, (size_t)Mc * YDIM * 4);
  ushort_t* dz1  = h1;   // alias: h1 dead once the z2-GEMM consumed it

  dim3 blk(256);
  k_zero_acc<<<1, 1, 0, stream>>>(accs);
  k_sigma<<<(B_TOT + 255) / 256, blk, 0, stream>>>(k_idx, sigma_b);
  k_cast<<<(256 * HDIM + 255) / 256, blk, 0, stream>>>(W1, W1bf, 256 * HDIM);
  k_w1t<<<(HDIM * FEATP + 255) / 256, blk, 0, stream>>>(W1, W1T);
  k_cast<<<(HDIM * HDIM + 255) / 256, blk, 0, stream>>>(W2, W2bf, HDIM * HDIM);
  k_w2t<<<dim3(HDIM / 32, HDIM / 32), blk, 0, stream>>>(W2, W2T);

  auto G = [&](const ushort_t* Ap, const ushort_t* BTp, int K, int mode,
               const float* biasp, ushort_t* oA, ushort_t* oB, float* ep){
    gemm_p<<<dim3(HDIM / 256, Mc / 256), dim3(512), 0, stream>>>(
        Ap, BTp, HDIM, K, mode, biasp, W3, dgz1, oA, oB, ep, Mc);
  };
  auto Gdy = [&](int upd, const float* yh, const float* yt, const float* sg){
    gemm_dy2<<<dim3(2, Mc / 128), blk, 0, stream>>>(
        dz1, W1bf, upd, yneg, feat, yh, yt, sg, accs);
  };

  int nCh = B_TOT / Mc;
  for (int c = 0; c < nCh; ++c){
    int b0 = c * Mc;
    k_feat_static<<<(Mc * 196 + 255) / 256, blk, 0, stream>>>(
        cond + (size_t)b0 * CELLS, k_emb, k_idx + b0, feat, Mc);

    // ---- positive branch
    k_noise<<<(Mc * CELLS + 255) / 256, blk, 0, stream>>>(
        y_true + (size_t)b0 * YDIM, eps_pos + (size_t)b0 * YDIM, sigma_b + b0, yhat, feat, Mc);
    G(feat, W1T, FEATP, 0, b1, dgz1, h1, nullptr);
    G(h1, W2T, HDIM, 1, b2, nullptr, dz2, e_part);
    k_esum<<<(Mc + 255) / 256, blk, 0, stream>>>(e_part, b3, e_pos + b0, Mc);
    G(dz2, W2bf, HDIM, 2, nullptr, dz1, nullptr, nullptr);
    Gdy(0, yhat, y_true + (size_t)b0 * YDIM, sigma_b + b0);

    // ---- negative branch
    k_makeneg<<<(Mc * 64 + 255) / 256, blk, 0, stream>>>(y_true, sel, rv, yneg, feat, b0, Mc);
    for (int r = 0; r < 5; ++r){
      G(feat, W1T, FEATP, 0, b1, dgz1, h1, nullptr);
      G(h1, W2T, HDIM, 1, b2, nullptr, dz2, nullptr);
      G(dz2, W2bf, HDIM, 2, nullptr, dz1, nullptr, nullptr);
      Gdy(1, nullptr, nullptr, nullptr);
    }
    k_noise<<<(Mc * CELLS + 255) / 256, blk, 0, stream>>>(
        yneg, eps_neg + (size_t)b0 * YDIM, sigma_b + b0, yhat, feat, Mc);
    G(feat, W1T, FEATP, 0, b1, dgz1, h1, nullptr);
    G(h1, W2T, HDIM, 1, b2, nullptr, nullptr, e_part);
    k_esum<<<(Mc + 255) / 256, blk, 0, stream>>>(e_part, b3, e_neg + b0, Mc);
  }

  k_contrast<<<64, blk, 0, stream>>>(e_pos, e_neg, accs);
  k_finalize<<<1, 1, 0, stream>>>(accs, (float*)d_out);
}

// Round 9
// 3621.064 us; speedup vs baseline: 1.6466x; 1.0438x over previous
//
#include <hip/hip_runtime.h>
#include <math.h>

#define B_TOT 16384
#define CELLS 36
#define YDIM 252       // 7*6*6
#define FEATP 448      // 416 padded to 448
#define FEAT_REAL 416
#define HDIM 2048
#define EMB_DIM 128
#define KSTEPS 50
#define NPART 8        // e_part slabs = HDIM/256

typedef unsigned short ushort_t;
typedef __attribute__((ext_vector_type(8))) short short8v;
typedef __attribute__((ext_vector_type(4))) float float4v;

__device__ __forceinline__ float clip01(float x){ return fminf(fmaxf(x, 0.f), 1.f); }
__device__ __forceinline__ float tanh_fast(float u){
  float e = __expf(2.f * u);
  return 1.f - 2.f / (e + 1.f);
}
__device__ __forceinline__ float gelu_f(float x){
  float u = 0.7978845608028654f * (x + 0.044715f * x * x * x);
  return 0.5f * x * (1.f + tanh_fast(u));
}
__device__ __forceinline__ float dgelu_f(float x){
  float x2 = x * x;
  float u = 0.7978845608028654f * (x + 0.044715f * x2 * x);
  float t = tanh_fast(u);
  return 0.5f * (1.f + t) + 0.5f * x * (1.f - t * t) * 0.7978845608028654f * (1.f + 0.134145f * x2);
}
__device__ __forceinline__ float clipmask(float y){ return (y == 0.f || y == 1.f) ? 0.5f : 1.f; }
__device__ __forceinline__ ushort_t f2bf(float x){
  union { float f; unsigned u; } v; v.f = x;
  unsigned r = v.u + 0x7fffu + ((v.u >> 16) & 1u);
  return (ushort_t)(r >> 16);
}
__device__ __forceinline__ float bf2f(ushort_t h){
  union { unsigned u; float f; } v; v.u = ((unsigned)h) << 16; return v.f;
}
__device__ __forceinline__ void load_lds16(const void* g, void* l){
  __builtin_amdgcn_global_load_lds((const __attribute__((address_space(1))) unsigned int*)g,
                                   (__attribute__((address_space(3))) unsigned int*)l, 16, 0, 0);
}
__device__ __forceinline__ void store16(ushort_t* dst, const float* x){
  short8v r0, r1;
#pragma unroll
  for (int i = 0; i < 8; ++i){ r0[i] = (short)f2bf(x[i]); r1[i] = (short)f2bf(x[8 + i]); }
  *(short8v*)dst = r0;
  *(short8v*)&dst[8] = r1;
}
// m204 bijective XCD swizzle
__device__ __forceinline__ void xcd_swizzle(int GX, int GY, int& bx, int& by){
  int nwg = GX * GY;
  int orig = by * GX + bx;
  int q = nwg >> 3, r = nwg & 7;
  int xcd = orig & 7, loc = orig >> 3;
  int lin = (xcd < r ? xcd * (q + 1) : r * (q + 1) + (xcd - r) * q) + loc;
  bx = lin % GX; by = lin / GX;
}

// ---------------- small kernels ----------------
__global__ void k_zero_acc(double* acc){ acc[0] = 0.0; acc[1] = 0.0; acc[2] = 0.0; }

__global__ void k_sigma(const int* __restrict__ k_idx, float* __restrict__ sigma_b){
  int b = blockIdx.x * blockDim.x + threadIdx.x;
  if (b >= B_TOT) return;
  int i = (KSTEPS - 1) - k_idx[b];
  float t = (float)i / (float)(KSTEPS - 1);
  float ang = (1.f - t) * 1.57079632679489662f;
  float c = cosf(ang);
  sigma_b[b] = 0.01f + 0.94f * c * c;
}

__global__ void k_cast(const float* __restrict__ in, ushort_t* __restrict__ out, int n){
  int gid = blockIdx.x * blockDim.x + threadIdx.x;
  if (gid < n) out[gid] = f2bf(in[gid]);
}
// W1T[h][f] (f padded to 448)
__global__ void k_w1t(const float* __restrict__ W1, ushort_t* __restrict__ W1T){
  int gid = blockIdx.x * blockDim.x + threadIdx.x;
  if (gid >= HDIM * FEATP) return;
  int h = gid / FEATP, f = gid - h * FEATP;
  W1T[gid] = (f < FEAT_REAL) ? f2bf(W1[(size_t)f * HDIM + h]) : (ushort_t)0;
}
// tiled transpose: W2T[n][k] = W2[k][n]
__global__ __launch_bounds__(256) void k_w2t(const float* __restrict__ W2, ushort_t* __restrict__ W2T){
  __shared__ float tile[32][33];
  int x0 = blockIdx.x << 5, y0 = blockIdx.y << 5;
  int tx = threadIdx.x & 31, ty = threadIdx.x >> 5;
#pragma unroll
  for (int i = 0; i < 4; ++i)
    tile[ty + i * 8][tx] = W2[(size_t)(y0 + ty + i * 8) * HDIM + (x0 + tx)];
  __syncthreads();
#pragma unroll
  for (int i = 0; i < 4; ++i)
    W2T[(size_t)(x0 + ty + i * 8) * HDIM + (y0 + tx)] = f2bf(tile[tx][ty + i * 8]);
}

// static cols of feat: 252..447 (cond, emb, zero pad)
__global__ void k_feat_static(const float* __restrict__ cond, const float* __restrict__ k_emb,
                              const int* __restrict__ k_idx, ushort_t* __restrict__ feat, int Mc){
  int gid = blockIdx.x * blockDim.x + threadIdx.x;
  if (gid >= Mc * 196) return;
  int i = gid / 196, c = gid - i * 196;
  float v;
  if (c < CELLS)            v = cond[(size_t)i * CELLS + c];
  else if (c < CELLS + EMB_DIM) v = k_emb[(size_t)k_idx[i] * EMB_DIM + (c - CELLS)];
  else                      v = 0.f;
  feat[(size_t)i * FEATP + YDIM + c] = f2bf(v);
}

// noise + direct feat write
__global__ void k_noise(const float* __restrict__ y, const float* __restrict__ eps,
                        const float* __restrict__ sigma_b, float* __restrict__ out,
                        ushort_t* __restrict__ feat, int Mc){
  int gid = blockIdx.x * blockDim.x + threadIdx.x;
  if (gid >= Mc * CELLS) return;
  int i = gid / CELLS, cell = gid - i * CELLS;
  float sigma = sigma_b[i];
  float sq = sqrtf(fmaxf(1.f - sigma * sigma, 1e-8f));
  const float* yp = y + (size_t)i * YDIM + cell;
  const float* ep = eps + (size_t)i * YDIM + cell;
  float yh[7];
#pragma unroll
  for (int ch = 0; ch < 7; ++ch){
    float e = ep[ch * CELLS] * 0.1f;
    yh[ch] = clip01(sq * yp[ch * CELLS] + sigma * e);
  }
  bool filled = yh[0] > 0.5f;
  float s = 0.f;
#pragma unroll
  for (int ch = 1; ch < 7; ++ch) s += yh[ch];
  float* op = out + (size_t)i * YDIM + cell;
  ushort_t* fp = feat + (size_t)i * FEATP + cell;
  op[0] = yh[0];
  fp[0] = f2bf(yh[0]);
#pragma unroll
  for (int ch = 1; ch < 7; ++ch){
    float v = yh[ch];
    if (filled) v = v / (s + 1e-8f);
    v = clip01(v);
    op[ch * CELLS] = v;
    fp[ch * CELLS] = f2bf(v);
  }
}

// y_neg init + feat write
__global__ void k_makeneg(const float* __restrict__ y_true, const float* __restrict__ sel,
                          const float* __restrict__ rv, float* __restrict__ y_neg,
                          ushort_t* __restrict__ feat, int b0, int Mc){
  int w = (blockIdx.x * blockDim.x + threadIdx.x) >> 6;
  int lane = threadIdx.x & 63;
  if (w >= Mc) return;
  int b = b0 + w;
  int c = lane;
  bool active = c < CELLS;
  float yt0 = active ? y_true[(size_t)b * YDIM + c] : 0.f;
  bool filled = active && (yt0 > 0.5f);
  unsigned long long bal = __ballot(filled);
  int n_filled = __popcll(bal);
  int num_c = (int)floorf((float)n_filled * 0.3f);
  int idx = num_c - 1; if (idx < 0) idx = 0;
  float score = filled ? sel[(size_t)b * CELLS + c] : 2.0f;
  int cnt_lt = 0, cnt_le = 0;
  for (int l = 0; l < CELLS; ++l){
    float sv = __shfl(score, l);
    cnt_lt += (sv < score);
    cnt_le += (sv <= score);
  }
  float cand = (active && cnt_lt <= idx && idx < cnt_le) ? score : 3.4e38f;
  for (int off = 32; off; off >>= 1) cand = fminf(cand, __shfl_xor(cand, off));
  float thr = (num_c > 0) ? cand : -1.0f;
  bool corrupt = filled && (score <= thr);
  if (active){
    float rvv[6]; float rsum = 0.f;
#pragma unroll
    for (int ch = 0; ch < 6; ++ch){ rvv[ch] = rv[(size_t)b * (6 * CELLS) + ch * CELLS + c]; rsum += rvv[ch]; }
    float v0 = corrupt ? 0.f : yt0;
    y_neg[(size_t)w * YDIM + c] = v0;
    feat[(size_t)w * FEATP + c] = f2bf(clip01(v0));
#pragma unroll
    for (int ch = 0; ch < 6; ++ch){
      float val = corrupt ? rvv[ch] / rsum : y_true[(size_t)b * YDIM + (ch + 1) * CELLS + c];
      y_neg[(size_t)w * YDIM + (ch + 1) * CELLS + c] = val;
      feat[(size_t)w * FEATP + (ch + 1) * CELLS + c] = f2bf(clip01(val));
    }
  }
}

// e[i] = b3 + sum_x e_part[x][i]
__global__ void k_esum(const float* __restrict__ e_part, const float* __restrict__ b3,
                       float* __restrict__ e_out, int Mc){
  int i = blockIdx.x * blockDim.x + threadIdx.x;
  if (i >= Mc) return;
  float s = b3[0];
#pragma unroll
  for (int x = 0; x < NPART; ++x) s += e_part[(size_t)x * Mc + i];
  e_out[i] = s;
}

__global__ __launch_bounds__(256) void k_contrast(const float* __restrict__ e_pos, const float* __restrict__ e_neg,
                           double* __restrict__ acc){
  double con = 0.0, reg = 0.0;
  for (int b = blockIdx.x * blockDim.x + threadIdx.x; b < B_TOT; b += gridDim.x * blockDim.x){
    float ep = e_pos[b], en = e_neg[b];
    float a = -ep, bb = -en;
    float m = fmaxf(a, bb);
    float lse = m + logf(expf(a - m) + expf(bb - m));
    con += (double)(ep + lse);
    reg += (double)ep + (double)en;
  }
  for (int off = 32; off; off >>= 1){ con += __shfl_down(con, off); reg += __shfl_down(reg, off); }
  __shared__ double wc[4], wr[4];
  int lane = threadIdx.x & 63, wid = threadIdx.x >> 6;
  if (lane == 0){ wc[wid] = con; wr[wid] = reg; }
  __syncthreads();
  if (threadIdx.x == 0){
    atomicAdd(&acc[1], (wc[0] + wc[1]) + (wc[2] + wc[3]));
    atomicAdd(&acc[2], (wr[0] + wr[1]) + (wr[2] + wr[3]));
  }
}

__global__ void k_finalize(const double* __restrict__ acc, float* __restrict__ out){
  double mse = acc[0] / (double)((long long)B_TOT * YDIM);
  double con = acc[1] / (double)B_TOT;
  double reg = acc[2] / (double)B_TOT;
  out[0] = (float)(mse + con + 0.01 * reg);
}

// ============ 8-phase GEMM (m201-style): BM=BN=256, K-step 64, 4 phases/K-step ============
// C[M,N] = A[M,K]bf16 @ BT[N,K]bf16. 512 thr = 8 waves (2M x 4N), wave tile 128x64.
// LDS: 2 x (A[256][64] + B[256][64]) = 128 KiB, buffer parity per K-step.
// Rows are 128 B = 8 x 16B slots; slot s of row r holds k-chunk (s - r)&7 (rotate swizzle:
// frag read slot = (chunk + fr)&7 -> 2 lanes/bank = free; inverse rotation on global source).
// Phases: ph0 {stage A(s+1), vmcnt(4), barrier, read b[kk0]+a[mh0,kk0], MFMA16},
//         ph1 {stage B(s+1), read a[mh1,kk0], MFMA16}, ph2/ph3 idem kk1.
// WAR safety: K-step s-1's frag reads drain (lgkmcnt(0) per phase) before its end barrier,
// so s's stages may overwrite buf[s^1]. vmcnt(4) leaves only the 4 just-issued in flight.
// modes: 0 z1: z=v+b1 -> outA=dgz1=bf(dgelu z), outB=h1=bf(gelu z)
//        1 z2: z=v+b2 -> outB?=dz2=bf(W3*dgelu z); e_part?=row sums gelu(z)*W3
//        2 dz1: v *= bf2f(dgz[o]); outA
#define STG_OP(srcPtr, p0, bufB, k0) \
  _Pragma("unroll") \
  for (int ro_ = 0; ro_ < 4; ++ro_){ \
    int r_ = (ro_ << 6) + (t >> 3); \
    int c_ = ((t & 7) - r_) & 7; \
    load_lds16((const char*)(srcPtr) + (((size_t)((p0) + r_)) * K + (k0) + (c_ << 3)) * 2, \
               (char*)(bufB) + (r_ << 7) + ((t & 7) << 4)); \
  }

__global__ __launch_bounds__(512, 1) void gemm_p(
    const ushort_t* __restrict__ A, const ushort_t* __restrict__ BT,
    int N, int K, int mode,
    const float* __restrict__ bias, const float* __restrict__ W3,
    const ushort_t* __restrict__ dgz,
    ushort_t* __restrict__ outA, ushort_t* __restrict__ outB,
    float* __restrict__ e_part, int Mrows){
  __shared__ __align__(16) ushort_t Al[2][256 * 64];
  __shared__ __align__(16) ushort_t Bl[2][256 * 64];
  const int t = threadIdx.x, lane = t & 63, w = t >> 6;
  int bx = blockIdx.x, by = blockIdx.y;
  xcd_swizzle(gridDim.x, gridDim.y, bx, by);
  const int m0 = by << 8, n0 = bx << 8;
  const int fr = lane & 15, kg = lane >> 4;
  const int wm = w >> 2, wn = w & 3;
  const int NT = K >> 6;
  const int wr = wm << 7, wc = wn << 6;
  // frag read bases (byte offsets into a 256x64-ushort buffer)
  const int aslot0 = ((kg + fr) & 7) << 4;        // kk=0: chunk=kg
  const int aslot1 = ((4 + kg + fr) & 7) << 4;    // kk=1: chunk=4+kg
  const int arow = ((wm << 7) + fr) << 7;         // row (wm*128+fr) * 128 B
  const int brow = ((wn << 6) + fr) << 7;

  float4v acc[8][4];
#pragma unroll
  for (int m = 0; m < 8; ++m)
#pragma unroll
    for (int n = 0; n < 4; ++n) acc[m][n] = (float4v)0.f;

  // prologue: stage K-step 0 (A then B)
  STG_OP(A, m0, &Al[0][0], 0);
  STG_OP(BT, n0, &Bl[0][0], 0);

  for (int s = 0; s < NT; ++s){
    const char* cA = (const char*)&Al[s & 1][0];
    const char* cB = (const char*)&Bl[s & 1][0];
    char* nA = (char*)&Al[(s + 1) & 1][0];
    char* nB = (char*)&Bl[(s + 1) & 1][0];
    const int kn = (s + 1) << 6;
    short8v af[4], bf[4];

    // ---- phase 0: stage A(s+1); compute (mh=0, kk=0)
    if (s + 1 < NT){
      STG_OP(A, m0, nA, kn);
      asm volatile("s_waitcnt vmcnt(4)" ::: "memory");
    } else {
      asm volatile("s_waitcnt vmcnt(0)" ::: "memory");
    }
    __builtin_amdgcn_s_barrier();
    __builtin_amdgcn_sched_barrier(0);
#pragma unroll
    for (int n = 0; n < 4; ++n) bf[n] = *(const short8v*)(cB + brow + (n << 11) + aslot0);
#pragma unroll
    for (int m = 0; m < 4; ++m) af[m] = *(const short8v*)(cA + arow + (m << 11) + aslot0);
    asm volatile("s_waitcnt lgkmcnt(0)" ::: "memory");
    __builtin_amdgcn_sched_barrier(0);
    __builtin_amdgcn_s_setprio(1);
#pragma unroll
    for (int m = 0; m < 4; ++m)
#pragma unroll
      for (int n = 0; n < 4; ++n)
        acc[m][n] = __builtin_amdgcn_mfma_f32_16x16x32_bf16(af[m], bf[n], acc[m][n], 0, 0, 0);
    __builtin_amdgcn_s_setprio(0);
    __builtin_amdgcn_sched_barrier(0);
    __builtin_amdgcn_s_barrier();

    // ---- phase 1: stage B(s+1); compute (mh=1, kk=0)  [bf reused]
    if (s + 1 < NT){ STG_OP(BT, n0, nB, kn); }
#pragma unroll
    for (int m = 0; m < 4; ++m) af[m] = *(const short8v*)(cA + arow + ((m + 4) << 11) + aslot0);
    asm volatile("s_waitcnt lgkmcnt(0)" ::: "memory");
    __builtin_amdgcn_sched_barrier(0);
    __builtin_amdgcn_s_setprio(1);
#pragma unroll
    for (int m = 0; m < 4; ++m)
#pragma unroll
      for (int n = 0; n < 4; ++n)
        acc[m + 4][n] = __builtin_amdgcn_mfma_f32_16x16x32_bf16(af[m], bf[n], acc[m + 4][n], 0, 0, 0);
    __builtin_amdgcn_s_setprio(0);
    __builtin_amdgcn_sched_barrier(0);
    __builtin_amdgcn_s_barrier();

    // ---- phase 2: compute (mh=0, kk=1)
#pragma unroll
    for (int n = 0; n < 4; ++n) bf[n] = *(const short8v*)(cB + brow + (n << 11) + aslot1);
#pragma unroll
    for (int m = 0; m < 4; ++m) af[m] = *(const short8v*)(cA + arow + (m << 11) + aslot1);
    asm volatile("s_waitcnt lgkmcnt(0)" ::: "memory");
    __builtin_amdgcn_sched_barrier(0);
    __builtin_amdgcn_s_setprio(1);
#pragma unroll
    for (int m = 0; m < 4; ++m)
#pragma unroll
      for (int n = 0; n < 4; ++n)
        acc[m][n] = __builtin_amdgcn_mfma_f32_16x16x32_bf16(af[m], bf[n], acc[m][n], 0, 0, 0);
    __builtin_amdgcn_s_setprio(0);
    __builtin_amdgcn_sched_barrier(0);
    __builtin_amdgcn_s_barrier();

    // ---- phase 3: compute (mh=1, kk=1)
#pragma unroll
    for (int m = 0; m < 4; ++m) af[m] = *(const short8v*)(cA + arow + ((m + 4) << 11) + aslot1);
    asm volatile("s_waitcnt lgkmcnt(0)" ::: "memory");
    __builtin_amdgcn_sched_barrier(0);
    __builtin_amdgcn_s_setprio(1);
#pragma unroll
    for (int m = 0; m < 4; ++m)
#pragma unroll
      for (int n = 0; n < 4; ++n)
        acc[m + 4][n] = __builtin_amdgcn_mfma_f32_16x16x32_bf16(af[m], bf[n], acc[m + 4][n], 0, 0, 0);
    __builtin_amdgcn_s_setprio(0);
    __builtin_amdgcn_sched_barrier(0);
    __builtin_amdgcn_s_barrier();
  }

  // ---- epilogue: per-wave f32 LDS slice -> coalesced 16B bf16 stores ----
  float* slice = (float*)&Al[0][0] + w * (16 * 68);
  float* e_lds = (float*)&Bl[0][0];
  const bool do_e = (mode == 1) && (e_part != nullptr);
  if (do_e){
    if (t < 256) e_lds[t] = 0.f;
    __syncthreads();
  }
  const int rrow = lane >> 2;      // 0..15
  const int rq = lane & 3;         // 16-col group
#pragma unroll
  for (int m = 0; m < 8; ++m){
    if (m) asm volatile("s_waitcnt lgkmcnt(0)" ::: "memory");  // prior reads done before overwrite
#pragma unroll
    for (int j = 0; j < 4; ++j)
#pragma unroll
      for (int n = 0; n < 4; ++n)
        slice[((kg << 2) + j) * 68 + (n << 4) + fr] = acc[m][n][j];
    asm volatile("s_waitcnt lgkmcnt(0)" ::: "memory");
    const int grow = m0 + wr + (m << 4) + rrow;
    const int gcol = n0 + wc + (rq << 4);
    float val[16];
#pragma unroll
    for (int p2 = 0; p2 < 4; ++p2){
      float4 vv = *(const float4*)&slice[rrow * 68 + (rq << 4) + (p2 << 2)];
      val[p2 * 4 + 0] = vv.x; val[p2 * 4 + 1] = vv.y;
      val[p2 * 4 + 2] = vv.z; val[p2 * 4 + 3] = vv.w;
    }
    const size_t ob = (size_t)grow * N + gcol;
    if (mode == 0){
      float o0[16], o1[16];
#pragma unroll
      for (int e = 0; e < 16; ++e){
        float z = val[e] + bias[gcol + e];
        o0[e] = dgelu_f(z);
        o1[e] = gelu_f(z);
      }
      store16(outA + ob, o0);
      store16(outB + ob, o1);
    } else if (mode == 1){
      float pe = 0.f;
      float o0[16];
#pragma unroll
      for (int e = 0; e < 16; ++e){
        float z = val[e] + bias[gcol + e];
        float w3 = W3[gcol + e];
        o0[e] = w3 * dgelu_f(z);
        if (do_e) pe += gelu_f(z) * w3;
      }
      if (outB) store16(outB + ob, o0);
      if (do_e){
        pe += __shfl_xor(pe, 1);
        pe += __shfl_xor(pe, 2);
        if (rq == 0) atomicAdd(&e_lds[wr + (m << 4) + rrow], pe);
      }
    } else {
      float o0[16];
      short8v g0 = *(const short8v*)&dgz[ob];
      short8v g1 = *(const short8v*)&dgz[ob + 8];
#pragma unroll
      for (int e = 0; e < 8; ++e){
        o0[e]     = val[e]     * bf2f((ushort_t)g0[e]);
        o0[8 + e] = val[8 + e] * bf2f((ushort_t)g1[e]);
      }
      store16(outA + ob, o0);
    }
  }
  if (do_e){
    __syncthreads();
    if (t < 256) e_part[(size_t)bx * Mrows + m0 + t] = e_lds[t];
  }
}

// ============ dy GEMM (128x128, full K) with fused mse / refine-update epilogue ============
#define DY_STAGE(Asl_, Bsl_, k0_) do { \
  _Pragma("unroll") \
  for (int i_ = 0; i_ < 4; ++i_){ \
    int c_ = i_ * 4 + w; \
    int r_ = c_ * 8 + rsub; \
    load_lds16((const char*)A + ((size_t)(m0 + r_) * K + (k0_)) * 2 + cb, (char*)(Asl_) + c_ * 1024 + lane * 16); \
    load_lds16((const char*)BT + ((size_t)(n0 + r_) * K + (k0_)) * 2 + cb, (char*)(Bsl_) + c_ * 1024 + lane * 16); \
  } } while (0)

#define DY_MFMA(Asl_, Bsl_) do { \
  _Pragma("unroll") \
  for (int kk = 0; kk < 2; ++kk){ \
    int kb = kk * 32 + kg * 8; \
    short8v a[4], b[4]; \
    _Pragma("unroll") \
    for (int m = 0; m < 4; ++m) a[m] = *(const short8v*)&(Asl_)[(wr + m * 16 + fr) * 64 + kb]; \
    _Pragma("unroll") \
    for (int n = 0; n < 4; ++n) b[n] = *(const short8v*)&(Bsl_)[(wc + n * 16 + fr) * 64 + kb]; \
    _Pragma("unroll") \
    for (int m = 0; m < 4; ++m) \
      _Pragma("unroll") \
      for (int n = 0; n < 4; ++n) \
        acc[m][n] = __builtin_amdgcn_mfma_f32_16x16x32_bf16(a[m], b[n], acc[m][n], 0, 0, 0); \
  } } while (0)

__global__ __launch_bounds__(256) void gemm_dy2(
    const ushort_t* __restrict__ A, const ushort_t* __restrict__ BT, int upd,
    float* __restrict__ yneg, ushort_t* __restrict__ feat,
    const float* __restrict__ yhat, const float* __restrict__ y_true,
    const float* __restrict__ sigma_b, double* __restrict__ acc_g){
  __shared__ __align__(16) ushort_t Asl[2][128 * 64];
  __shared__ __align__(16) ushort_t Bsl[2][128 * 64];
  const int K = HDIM;
  const int t = threadIdx.x, lane = t & 63, w = t >> 6;
  int bx = blockIdx.x, by = blockIdx.y;
  xcd_swizzle(gridDim.x, gridDim.y, bx, by);
  const int m0 = by << 7, n0 = bx << 7;
  const int fr = lane & 15, kg = lane >> 4;
  const int rsub = lane >> 3;
  const int cb = (lane & 7) * 16;
  const int wr = (w >> 1) * 64, wc = (w & 1) * 64;

  float4v acc[4][4];
#pragma unroll
  for (int m = 0; m < 4; ++m)
#pragma unroll
    for (int n = 0; n < 4; ++n) acc[m][n] = (float4v)0.f;

  DY_STAGE(Asl[0], Bsl[0], 0);
  __syncthreads();
  int cur = 0;
  for (int k0 = 0; k0 < K; k0 += 64){
    if (k0 + 64 < K) DY_STAGE(Asl[cur ^ 1], Bsl[cur ^ 1], k0 + 64);
    DY_MFMA(Asl[cur], Bsl[cur]);
    __syncthreads();
    cur ^= 1;
  }

  double ms = 0.0;
#pragma unroll
  for (int m = 0; m < 4; ++m){
#pragma unroll
    for (int j = 0; j < 4; ++j){
      int row = m0 + wr + m * 16 + kg * 4 + j;
#pragma unroll
      for (int n = 0; n < 4; ++n){
        int col = n0 + wc + n * 16 + fr;
        if (col < YDIM){
          size_t o = (size_t)row * YDIM + col;
          float g = acc[m][n][j];
          if (upd){
            float y = yneg[o];
            y = clip01(y + 0.15f * g * clipmask(y));
            yneg[o] = y;
            feat[(size_t)row * FEATP + col] = f2bf(y);
          } else {
            float y = yhat[o];
            float score = g * clipmask(y);
            float tgt = (y - y_true[o]) / (sigma_b[row] + 1e-8f);
            float d = score - tgt;
            ms += (double)d * (double)d;
          }
        }
      }
    }
  }
  if (!upd){
    for (int off = 32; off; off >>= 1) ms += __shfl_down(ms, off);
    __shared__ double wsum[4];
    int wid = t >> 6;
    if ((t & 63) == 0) wsum[wid] = ms;
    __syncthreads();
    if (t == 0) atomicAdd(&acc_g[0], (wsum[0] + wsum[1]) + (wsum[2] + wsum[3]));
  }
}

// ---------------- host ----------------
static inline char* carve(char*& p, size_t bytes){
  char* r = p; p += (bytes + 255) & ~(size_t)255; return r;
}

extern "C" void kernel_launch(void* const* d_in, const int* in_sizes, int n_in,
                              void* d_out, int out_size, void* d_ws, size_t ws_size,
                              hipStream_t stream){
  (void)in_sizes; (void)n_in; (void)out_size;
  const float* y_true  = (const float*)d_in[0];
  const float* cond    = (const float*)d_in[1];
  const int*   k_idx   = (const int*)d_in[2];
  const float* eps_pos = (const float*)d_in[3];
  const float* eps_neg = (const float*)d_in[4];
  const float* sel     = (const float*)d_in[5];
  const float* rv      = (const float*)d_in[6];
  const float* W1      = (const float*)d_in[7];
  const float* b1      = (const float*)d_in[8];
  const float* W2      = (const float*)d_in[9];
  const float* b2      = (const float*)d_in[10];
  const float* W3      = (const float*)d_in[11];
  const float* b3      = (const float*)d_in[12];
  const float* k_emb   = (const float*)d_in[13];

  char* p = (char*)d_ws;
  double* accs   = (double*)carve(p, 3 * sizeof(double));
  float* sigma_b = (float*)carve(p, (size_t)B_TOT * 4);
  float* e_pos   = (float*)carve(p, (size_t)B_TOT * 4);
  float* e_neg   = (float*)carve(p, (size_t)B_TOT * 4);
  ushort_t* W1bf = (ushort_t*)carve(p, (size_t)256 * HDIM * 2);   // rows 0..255 of W1 (dy B^T)
  ushort_t* W1T  = (ushort_t*)carve(p, (size_t)HDIM * FEATP * 2);
  ushort_t* W2bf = (ushort_t*)carve(p, (size_t)HDIM * HDIM * 2);
  ushort_t* W2T  = (ushort_t*)carve(p, (size_t)HDIM * HDIM * 2);
  size_t fixed = (size_t)(p - (char*)d_ws);

  // per sample: feat 896 + 3 H-planes (dgz1,h1,dz2) 12288 + e_part 32 + yhat/yneg 2016
  const size_t per_sample = FEATP * 2 + 3 * HDIM * 2 + NPART * 4 + 2 * YDIM * 4;
  int Mc = B_TOT;
  while (Mc > 256 && fixed + (size_t)Mc * per_sample + 65536 > ws_size) Mc >>= 1;

  ushort_t* feat = (ushort_t*)carve(p, (size_t)Mc * FEATP * 2);
  ushort_t* dgz1 = (ushort_t*)carve(p, (size_t)Mc * HDIM * 2);
  ushort_t* h1   = (ushort_t*)carve(p, (size_t)Mc * HDIM * 2);
  ushort_t* dz2  = (ushort_t*)carve(p, (size_t)Mc * HDIM * 2);
  float* e_part  = (float*)carve(p, (size_t)Mc * NPART * 4);
  float* yhat    = (float*)carve(p, (size_t)Mc * YDIM * 4);
  float* yneg    = (float*)carve(p, (size_t)Mc * YDIM * 4);
  ushort_t* dz1  = h1;   // alias: h1 dead once the z2-GEMM consumed it

  dim3 blk(256);
  k_zero_acc<<<1, 1, 0, stream>>>(accs);
  k_sigma<<<(B_TOT + 255) / 256, blk, 0, stream>>>(k_idx, sigma_b);
  k_cast<<<(256 * HDIM + 255) / 256, blk, 0, stream>>>(W1, W1bf, 256 * HDIM);
  k_w1t<<<(HDIM * FEATP + 255) / 256, blk, 0, stream>>>(W1, W1T);
  k_cast<<<(HDIM * HDIM + 255) / 256, blk, 0, stream>>>(W2, W2bf, HDIM * HDIM);
  k_w2t<<<dim3(HDIM / 32, HDIM / 32), blk, 0, stream>>>(W2, W2T);

  auto G = [&](const ushort_t* Ap, const ushort_t* BTp, int K, int mode,
               const float* biasp, ushort_t* oA, ushort_t* oB, float* ep){
    gemm_p<<<dim3(HDIM / 256, Mc / 256), dim3(512), 0, stream>>>(
        Ap, BTp, HDIM, K, mode, biasp, W3, dgz1, oA, oB, ep, Mc);
  };
  auto Gdy = [&](int upd, const float* yh, const float* yt, const float* sg){
    gemm_dy2<<<dim3(2, Mc / 128), blk, 0, stream>>>(
        dz1, W1bf, upd, yneg, feat, yh, yt, sg, accs);
  };

  int nCh = B_TOT / Mc;
  for (int c = 0; c < nCh; ++c){
    int b0 = c * Mc;
    k_feat_static<<<(Mc * 196 + 255) / 256, blk, 0, stream>>>(
        cond + (size_t)b0 * CELLS, k_emb, k_idx + b0, feat, Mc);

    // ---- positive branch
    k_noise<<<(Mc * CELLS + 255) / 256, blk, 0, stream>>>(
        y_true + (size_t)b0 * YDIM, eps_pos + (size_t)b0 * YDIM, sigma_b + b0, yhat, feat, Mc);
    G(feat, W1T, FEATP, 0, b1, dgz1, h1, nullptr);
    G(h1, W2T, HDIM, 1, b2, nullptr, dz2, e_part);
    k_esum<<<(Mc + 255) / 256, blk, 0, stream>>>(e_part, b3, e_pos + b0, Mc);
    G(dz2, W2bf, HDIM, 2, nullptr, dz1, nullptr, nullptr);
    Gdy(0, yhat, y_true + (size_t)b0 * YDIM, sigma_b + b0);

    // ---- negative branch
    k_makeneg<<<(Mc * 64 + 255) / 256, blk, 0, stream>>>(y_true, sel, rv, yneg, feat, b0, Mc);
    for (int r = 0; r < 5; ++r){
      G(feat, W1T, FEATP, 0, b1, dgz1, h1, nullptr);
      G(h1, W2T, HDIM, 1, b2, nullptr, dz2, nullptr);
      G(dz2, W2bf, HDIM, 2, nullptr, dz1, nullptr, nullptr);
      Gdy(1, nullptr, nullptr, nullptr);
    }
    k_noise<<<(Mc * CELLS + 255) / 256, blk, 0, stream>>>(
        yneg, eps_neg + (size_t)b0 * YDIM, sigma_b + b0, yhat, feat, Mc);
    G(feat, W1T, FEATP, 0, b1, dgz1, h1, nullptr);
    G(h1, W2T, HDIM, 1, b2, nullptr, nullptr, e_part);
    k_esum<<<(Mc + 255) / 256, blk, 0, stream>>>(e_part, b3, e_neg + b0, Mc);
  }

  k_contrast<<<64, blk, 0, stream>>>(e_pos, e_neg, accs);
  k_finalize<<<1, 1, 0, stream>>>(accs, (float*)d_out);
}

// Round 10
// 3390.862 us; speedup vs baseline: 1.7584x; 1.0679x over previous
//
#include <hip/hip_runtime.h>
#include <math.h>

#define B_TOT 16384
#define CELLS 36
#define YDIM 252       // 7*6*6
#define FEATP 448      // 416 padded to 448
#define FEAT_REAL 416
#define HDIM 2048
#define EMB_DIM 128
#define KSTEPS 50
#define NPART 8        // e_part slabs = HDIM/256

typedef unsigned short ushort_t;
typedef __attribute__((ext_vector_type(8))) short short8v;
typedef __attribute__((ext_vector_type(4))) float float4v;

__device__ __forceinline__ float clip01(float x){ return fminf(fmaxf(x, 0.f), 1.f); }
__device__ __forceinline__ float tanh_fast(float u){
  float e = __expf(2.f * u);
  return 1.f - 2.f / (e + 1.f);
}
__device__ __forceinline__ float gelu_f(float x){
  float u = 0.7978845608028654f * (x + 0.044715f * x * x * x);
  return 0.5f * x * (1.f + tanh_fast(u));
}
__device__ __forceinline__ float dgelu_f(float x){
  float x2 = x * x;
  float u = 0.7978845608028654f * (x + 0.044715f * x2 * x);
  float t = tanh_fast(u);
  return 0.5f * (1.f + t) + 0.5f * x * (1.f - t * t) * 0.7978845608028654f * (1.f + 0.134145f * x2);
}
__device__ __forceinline__ float clipmask(float y){ return (y == 0.f || y == 1.f) ? 0.5f : 1.f; }
__device__ __forceinline__ ushort_t f2bf(float x){
  union { float f; unsigned u; } v; v.f = x;
  unsigned r = v.u + 0x7fffu + ((v.u >> 16) & 1u);
  return (ushort_t)(r >> 16);
}
__device__ __forceinline__ float bf2f(ushort_t h){
  union { unsigned u; float f; } v; v.u = ((unsigned)h) << 16; return v.f;
}
__device__ __forceinline__ void load_lds16(const void* g, void* l){
  __builtin_amdgcn_global_load_lds((const __attribute__((address_space(1))) unsigned int*)g,
                                   (__attribute__((address_space(3))) unsigned int*)l, 16, 0, 0);
}
__device__ __forceinline__ void store16(ushort_t* dst, const float* x){
  short8v r0, r1;
#pragma unroll
  for (int i = 0; i < 8; ++i){ r0[i] = (short)f2bf(x[i]); r1[i] = (short)f2bf(x[8 + i]); }
  *(short8v*)dst = r0;
  *(short8v*)&dst[8] = r1;
}
// m204 bijective XCD swizzle
__device__ __forceinline__ void xcd_swizzle(int GX, int GY, int& bx, int& by){
  int nwg = GX * GY;
  int orig = by * GX + bx;
  int q = nwg >> 3, r = nwg & 7;
  int xcd = orig & 7, loc = orig >> 3;
  int lin = (xcd < r ? xcd * (q + 1) : r * (q + 1) + (xcd - r) * q) + loc;
  bx = lin % GX; by = lin / GX;
}

// ---------------- small kernels ----------------
__global__ void k_zero_acc(double* acc){ acc[0] = 0.0; acc[1] = 0.0; acc[2] = 0.0; }

__global__ void k_sigma(const int* __restrict__ k_idx, float* __restrict__ sigma_b){
  int b = blockIdx.x * blockDim.x + threadIdx.x;
  if (b >= B_TOT) return;
  int i = (KSTEPS - 1) - k_idx[b];
  float t = (float)i / (float)(KSTEPS - 1);
  float ang = (1.f - t) * 1.57079632679489662f;
  float c = cosf(ang);
  sigma_b[b] = 0.01f + 0.94f * c * c;
}

__global__ void k_cast(const float* __restrict__ in, ushort_t* __restrict__ out, int n){
  int gid = blockIdx.x * blockDim.x + threadIdx.x;
  if (gid < n) out[gid] = f2bf(in[gid]);
}
// W1T[h][f] (f padded to 448)
__global__ void k_w1t(const float* __restrict__ W1, ushort_t* __restrict__ W1T){
  int gid = blockIdx.x * blockDim.x + threadIdx.x;
  if (gid >= HDIM * FEATP) return;
  int h = gid / FEATP, f = gid - h * FEATP;
  W1T[gid] = (f < FEAT_REAL) ? f2bf(W1[(size_t)f * HDIM + h]) : (ushort_t)0;
}
// tiled transpose: W2T[n][k] = W2[k][n]
__global__ __launch_bounds__(256) void k_w2t(const float* __restrict__ W2, ushort_t* __restrict__ W2T){
  __shared__ float tile[32][33];
  int x0 = blockIdx.x << 5, y0 = blockIdx.y << 5;
  int tx = threadIdx.x & 31, ty = threadIdx.x >> 5;
#pragma unroll
  for (int i = 0; i < 4; ++i)
    tile[ty + i * 8][tx] = W2[(size_t)(y0 + ty + i * 8) * HDIM + (x0 + tx)];
  __syncthreads();
#pragma unroll
  for (int i = 0; i < 4; ++i)
    W2T[(size_t)(x0 + ty + i * 8) * HDIM + (y0 + tx)] = f2bf(tile[tx][ty + i * 8]);
}

// static cols of feat: 252..447 (cond, emb, zero pad)
__global__ void k_feat_static(const float* __restrict__ cond, const float* __restrict__ k_emb,
                              const int* __restrict__ k_idx, ushort_t* __restrict__ feat, int Mc){
  int gid = blockIdx.x * blockDim.x + threadIdx.x;
  if (gid >= Mc * 196) return;
  int i = gid / 196, c = gid - i * 196;
  float v;
  if (c < CELLS)            v = cond[(size_t)i * CELLS + c];
  else if (c < CELLS + EMB_DIM) v = k_emb[(size_t)k_idx[i] * EMB_DIM + (c - CELLS)];
  else                      v = 0.f;
  feat[(size_t)i * FEATP + YDIM + c] = f2bf(v);
}

// noise + direct feat write
__global__ void k_noise(const float* __restrict__ y, const float* __restrict__ eps,
                        const float* __restrict__ sigma_b, float* __restrict__ out,
                        ushort_t* __restrict__ feat, int Mc){
  int gid = blockIdx.x * blockDim.x + threadIdx.x;
  if (gid >= Mc * CELLS) return;
  int i = gid / CELLS, cell = gid - i * CELLS;
  float sigma = sigma_b[i];
  float sq = sqrtf(fmaxf(1.f - sigma * sigma, 1e-8f));
  const float* yp = y + (size_t)i * YDIM + cell;
  const float* ep = eps + (size_t)i * YDIM + cell;
  float yh[7];
#pragma unroll
  for (int ch = 0; ch < 7; ++ch){
    float e = ep[ch * CELLS] * 0.1f;
    yh[ch] = clip01(sq * yp[ch * CELLS] + sigma * e);
  }
  bool filled = yh[0] > 0.5f;
  float s = 0.f;
#pragma unroll
  for (int ch = 1; ch < 7; ++ch) s += yh[ch];
  float* op = out + (size_t)i * YDIM + cell;
  ushort_t* fp = feat + (size_t)i * FEATP + cell;
  op[0] = yh[0];
  fp[0] = f2bf(yh[0]);
#pragma unroll
  for (int ch = 1; ch < 7; ++ch){
    float v = yh[ch];
    if (filled) v = v / (s + 1e-8f);
    v = clip01(v);
    op[ch * CELLS] = v;
    fp[ch * CELLS] = f2bf(v);
  }
}

// y_neg init + feat write
__global__ void k_makeneg(const float* __restrict__ y_true, const float* __restrict__ sel,
                          const float* __restrict__ rv, float* __restrict__ y_neg,
                          ushort_t* __restrict__ feat, int b0, int Mc){
  int w = (blockIdx.x * blockDim.x + threadIdx.x) >> 6;
  int lane = threadIdx.x & 63;
  if (w >= Mc) return;
  int b = b0 + w;
  int c = lane;
  bool active = c < CELLS;
  float yt0 = active ? y_true[(size_t)b * YDIM + c] : 0.f;
  bool filled = active && (yt0 > 0.5f);
  unsigned long long bal = __ballot(filled);
  int n_filled = __popcll(bal);
  int num_c = (int)floorf((float)n_filled * 0.3f);
  int idx = num_c - 1; if (idx < 0) idx = 0;
  float score = filled ? sel[(size_t)b * CELLS + c] : 2.0f;
  int cnt_lt = 0, cnt_le = 0;
  for (int l = 0; l < CELLS; ++l){
    float sv = __shfl(score, l);
    cnt_lt += (sv < score);
    cnt_le += (sv <= score);
  }
  float cand = (active && cnt_lt <= idx && idx < cnt_le) ? score : 3.4e38f;
  for (int off = 32; off; off >>= 1) cand = fminf(cand, __shfl_xor(cand, off));
  float thr = (num_c > 0) ? cand : -1.0f;
  bool corrupt = filled && (score <= thr);
  if (active){
    float rvv[6]; float rsum = 0.f;
#pragma unroll
    for (int ch = 0; ch < 6; ++ch){ rvv[ch] = rv[(size_t)b * (6 * CELLS) + ch * CELLS + c]; rsum += rvv[ch]; }
    float v0 = corrupt ? 0.f : yt0;
    y_neg[(size_t)w * YDIM + c] = v0;
    feat[(size_t)w * FEATP + c] = f2bf(clip01(v0));
#pragma unroll
    for (int ch = 0; ch < 6; ++ch){
      float val = corrupt ? rvv[ch] / rsum : y_true[(size_t)b * YDIM + (ch + 1) * CELLS + c];
      y_neg[(size_t)w * YDIM + (ch + 1) * CELLS + c] = val;
      feat[(size_t)w * FEATP + (ch + 1) * CELLS + c] = f2bf(clip01(val));
    }
  }
}

// e[i] = b3 + sum_x e_part[x][i]
__global__ void k_esum(const float* __restrict__ e_part, const float* __restrict__ b3,
                       float* __restrict__ e_out, int Mc){
  int i = blockIdx.x * blockDim.x + threadIdx.x;
  if (i >= Mc) return;
  float s = b3[0];
#pragma unroll
  for (int x = 0; x < NPART; ++x) s += e_part[(size_t)x * Mc + i];
  e_out[i] = s;
}

__global__ __launch_bounds__(256) void k_contrast(const float* __restrict__ e_pos, const float* __restrict__ e_neg,
                           double* __restrict__ acc){
  double con = 0.0, reg = 0.0;
  for (int b = blockIdx.x * blockDim.x + threadIdx.x; b < B_TOT; b += gridDim.x * blockDim.x){
    float ep = e_pos[b], en = e_neg[b];
    float a = -ep, bb = -en;
    float m = fmaxf(a, bb);
    float lse = m + logf(expf(a - m) + expf(bb - m));
    con += (double)(ep + lse);
    reg += (double)ep + (double)en;
  }
  for (int off = 32; off; off >>= 1){ con += __shfl_down(con, off); reg += __shfl_down(reg, off); }
  __shared__ double wc[4], wr[4];
  int lane = threadIdx.x & 63, wid = threadIdx.x >> 6;
  if (lane == 0){ wc[wid] = con; wr[wid] = reg; }
  __syncthreads();
  if (threadIdx.x == 0){
    atomicAdd(&acc[1], (wc[0] + wc[1]) + (wc[2] + wc[3]));
    atomicAdd(&acc[2], (wr[0] + wr[1]) + (wr[2] + wr[3]));
  }
}

__global__ void k_finalize(const double* __restrict__ acc, float* __restrict__ out){
  double mse = acc[0] / (double)((long long)B_TOT * YDIM);
  double con = acc[1] / (double)B_TOT;
  double reg = acc[2] / (double)B_TOT;
  out[0] = (float)(mse + con + 0.01 * reg);
}

// ============ 8-phase GEMM (m201 template): BM=BN=256, K-step 64, 4 phases/K-step ============
// C[M,N] = A[M,K]bf16 @ BT[N,K]bf16. 512 thr = 8 waves (2M x 4N), wave tile 128x64.
// LDS: 2 x (A[256][64] + B[256][64]) = 128 KiB, parity per K-step.
// Rows 128 B = 8 x 16B slots; slot s of row r holds k-chunk (s - r)&7; frag read slot
// (chunk + fr)&7 -> even 8-lanes-per-4-bank spread (conflict-free b128).
// Half-tiles by CONSUMPTION: A-half h = rows used at mh=h = {h*64..h*64+63, 128+h*64..};
// B-half h = rows [h*128, h*128+128) (waves wn=0,1 vs 2,3).
// Stage plan per K-step t (2 gl_lds per half): ph0 -> B1(t+1), ph1 -> A1(t+1),
// ph3 -> A0(t+2)+B0(t+2) into cur parity (safe: cur's A0/B0 reads all complete by
// ph2's end barrier). Boundary vmcnt(4) at ph3 end (before end-barrier): confirms all
// of t+1 landed, leaves the two t+2 halves (4 loads) in flight. No sched_barrier(0):
// ds_reads are compiler-visible, explicit order-pinning regresses (m141).
// modes: 0 z1: z=v+b1 -> outA=dgz1=bf(dgelu z), outB=h1=bf(gelu z)
//        1 z2: z=v+b2 -> outB?=dz2=bf(W3*dgelu z); e_part?=row sums gelu(z)*W3
//        2 dz1: v *= bf2f(dgz[o]); outA
#define STG_H(srcPtr, p0, buf, k0, h) \
  _Pragma("unroll") \
  for (int ro_ = 0; ro_ < 2; ++ro_){ \
    int r_ = (ro_ << 7) + ((h) << 6) + (t >> 3); \
    int c_ = ((t & 7) - r_) & 7; \
    load_lds16((const char*)(srcPtr) + (((size_t)((p0) + r_)) * K + (k0) + (c_ << 3)) * 2, \
               (char*)(buf) + (r_ << 7) + ((t & 7) << 4)); \
  }

__global__ __launch_bounds__(512, 1) void gemm_p(
    const ushort_t* __restrict__ A, const ushort_t* __restrict__ BT,
    int N, int K, int mode,
    const float* __restrict__ bias, const float* __restrict__ W3,
    const ushort_t* __restrict__ dgz,
    ushort_t* __restrict__ outA, ushort_t* __restrict__ outB,
    float* __restrict__ e_part, int Mrows){
  __shared__ __align__(16) ushort_t Al[2][256 * 64];
  __shared__ __align__(16) ushort_t Bl[2][256 * 64];
  const int t = threadIdx.x, lane = t & 63, w = t >> 6;
  int bx = blockIdx.x, by = blockIdx.y;
  xcd_swizzle(gridDim.x, gridDim.y, bx, by);
  const int m0 = by << 8, n0 = bx << 8;
  const int fr = lane & 15, kg = lane >> 4;
  const int wm = w >> 2, wn = w & 3;
  const int NT = K >> 6;
  const int wr = wm << 7, wc = wn << 6;
  const int aslot0 = ((kg + fr) & 7) << 4;        // kk=0: chunk=kg
  const int aslot1 = ((4 + kg + fr) & 7) << 4;    // kk=1: chunk=4+kg
  const int arow = ((wm << 7) + fr) << 7;
  const int brow = ((wn << 6) + fr) << 7;

  float4v acc[8][4];
#pragma unroll
  for (int m = 0; m < 8; ++m)
#pragma unroll
    for (int n = 0; n < 4; ++n) acc[m][n] = (float4v)0.f;

  // prologue: K-step 0 fully, then A0(1),B0(1)
  STG_H(A, m0, &Al[0][0], 0, 0); STG_H(A, m0, &Al[0][0], 0, 1);
  STG_H(BT, n0, &Bl[0][0], 0, 0); STG_H(BT, n0, &Bl[0][0], 0, 1);
  if (NT > 1){ STG_H(A, m0, &Al[1][0], 64, 0); STG_H(BT, n0, &Bl[1][0], 64, 0); }
  if (NT > 1) asm volatile("s_waitcnt vmcnt(4)" ::: "memory");
  else        asm volatile("s_waitcnt vmcnt(0)" ::: "memory");
  __builtin_amdgcn_s_barrier();

  for (int s = 0; s < NT; ++s){
    const char* cA = (const char*)&Al[s & 1][0];
    const char* cB = (const char*)&Bl[s & 1][0];
    char* nA = (char*)&Al[(s + 1) & 1][0];
    char* nB = (char*)&Bl[(s + 1) & 1][0];
    char* cA2 = (char*)&Al[s & 1][0];
    char* cB2 = (char*)&Bl[s & 1][0];
    const int kn1 = (s + 1) << 6, kn2 = (s + 2) << 6;
    short8v af[4], bf[4];

    // ---- phase 0: (mh0, kk0); stage B1(s+1)
#pragma unroll
    for (int n = 0; n < 4; ++n) bf[n] = *(const short8v*)(cB + brow + (n << 11) + aslot0);
#pragma unroll
    for (int m = 0; m < 4; ++m) af[m] = *(const short8v*)(cA + arow + (m << 11) + aslot0);
    if (s + 1 < NT){ STG_H(BT, n0, nB, kn1, 1); }
    __builtin_amdgcn_s_barrier();
    asm volatile("s_waitcnt lgkmcnt(0)" ::: "memory");
    __builtin_amdgcn_s_setprio(1);
#pragma unroll
    for (int m = 0; m < 4; ++m)
#pragma unroll
      for (int n = 0; n < 4; ++n)
        acc[m][n] = __builtin_amdgcn_mfma_f32_16x16x32_bf16(af[m], bf[n], acc[m][n], 0, 0, 0);
    __builtin_amdgcn_s_setprio(0);
    __builtin_amdgcn_s_barrier();

    // ---- phase 1: (mh1, kk0); stage A1(s+1)  [bf reused]
#pragma unroll
    for (int m = 0; m < 4; ++m) af[m] = *(const short8v*)(cA + arow + ((m + 4) << 11) + aslot0);
    if (s + 1 < NT){ STG_H(A, m0, nA, kn1, 1); }
    __builtin_amdgcn_s_barrier();
    asm volatile("s_waitcnt lgkmcnt(0)" ::: "memory");
    __builtin_amdgcn_s_setprio(1);
#pragma unroll
    for (int m = 0; m < 4; ++m)
#pragma unroll
      for (int n = 0; n < 4; ++n)
        acc[m + 4][n] = __builtin_amdgcn_mfma_f32_16x16x32_bf16(af[m], bf[n], acc[m + 4][n], 0, 0, 0);
    __builtin_amdgcn_s_setprio(0);
    __builtin_amdgcn_s_barrier();

    // ---- phase 2: (mh0, kk1); no stage
#pragma unroll
    for (int n = 0; n < 4; ++n) bf[n] = *(const short8v*)(cB + brow + (n << 11) + aslot1);
#pragma unroll
    for (int m = 0; m < 4; ++m) af[m] = *(const short8v*)(cA + arow + (m << 11) + aslot1);
    __builtin_amdgcn_s_barrier();
    asm volatile("s_waitcnt lgkmcnt(0)" ::: "memory");
    __builtin_amdgcn_s_setprio(1);
#pragma unroll
    for (int m = 0; m < 4; ++m)
#pragma unroll
      for (int n = 0; n < 4; ++n)
        acc[m][n] = __builtin_amdgcn_mfma_f32_16x16x32_bf16(af[m], bf[n], acc[m][n], 0, 0, 0);
    __builtin_amdgcn_s_setprio(0);
    __builtin_amdgcn_s_barrier();

    // ---- phase 3: (mh1, kk1); stage A0(s+2)+B0(s+2) into cur (WAR-safe after ph2 barrier)
#pragma unroll
    for (int m = 0; m < 4; ++m) af[m] = *(const short8v*)(cA + arow + ((m + 4) << 11) + aslot1);
    if (s + 2 < NT){ STG_H(A, m0, cA2, kn2, 0); STG_H(BT, n0, cB2, kn2, 0); }
    __builtin_amdgcn_s_barrier();
    asm volatile("s_waitcnt lgkmcnt(0)" ::: "memory");
    __builtin_amdgcn_s_setprio(1);
#pragma unroll
    for (int m = 0; m < 4; ++m)
#pragma unroll
      for (int n = 0; n < 4; ++n)
        acc[m + 4][n] = __builtin_amdgcn_mfma_f32_16x16x32_bf16(af[m], bf[n], acc[m + 4][n], 0, 0, 0);
    __builtin_amdgcn_s_setprio(0);
    if (s + 1 < NT){
      if (s + 2 < NT) asm volatile("s_waitcnt vmcnt(4)" ::: "memory");
      else            asm volatile("s_waitcnt vmcnt(0)" ::: "memory");
    }
    __builtin_amdgcn_s_barrier();
  }

  // ---- epilogue: per-wave f32 LDS slice -> coalesced 16B bf16 stores ----
  float* slice = (float*)&Al[0][0] + w * (16 * 68);
  float* e_lds = (float*)&Bl[0][0];
  const bool do_e = (mode == 1) && (e_part != nullptr);
  if (do_e){
    if (t < 256) e_lds[t] = 0.f;
    __syncthreads();
  }
  const int rrow = lane >> 2;      // 0..15
  const int rq = lane & 3;         // 16-col group
#pragma unroll
  for (int m = 0; m < 8; ++m){
    if (m) asm volatile("s_waitcnt lgkmcnt(0)" ::: "memory");  // prior reads done before overwrite
#pragma unroll
    for (int j = 0; j < 4; ++j)
#pragma unroll
      for (int n = 0; n < 4; ++n)
        slice[((kg << 2) + j) * 68 + (n << 4) + fr] = acc[m][n][j];
    asm volatile("s_waitcnt lgkmcnt(0)" ::: "memory");
    const int grow = m0 + wr + (m << 4) + rrow;
    const int gcol = n0 + wc + (rq << 4);
    float val[16];
#pragma unroll
    for (int p2 = 0; p2 < 4; ++p2){
      float4 vv = *(const float4*)&slice[rrow * 68 + (rq << 4) + (p2 << 2)];
      val[p2 * 4 + 0] = vv.x; val[p2 * 4 + 1] = vv.y;
      val[p2 * 4 + 2] = vv.z; val[p2 * 4 + 3] = vv.w;
    }
    const size_t ob = (size_t)grow * N + gcol;
    if (mode == 0){
      float o0[16], o1[16];
#pragma unroll
      for (int e = 0; e < 16; ++e){
        float z = val[e] + bias[gcol + e];
        o0[e] = dgelu_f(z);
        o1[e] = gelu_f(z);
      }
      store16(outA + ob, o0);
      store16(outB + ob, o1);
    } else if (mode == 1){
      float pe = 0.f;
      float o0[16];
#pragma unroll
      for (int e = 0; e < 16; ++e){
        float z = val[e] + bias[gcol + e];
        float w3 = W3[gcol + e];
        o0[e] = w3 * dgelu_f(z);
        if (do_e) pe += gelu_f(z) * w3;
      }
      if (outB) store16(outB + ob, o0);
      if (do_e){
        pe += __shfl_xor(pe, 1);
        pe += __shfl_xor(pe, 2);
        if (rq == 0) atomicAdd(&e_lds[wr + (m << 4) + rrow], pe);
      }
    } else {
      float o0[16];
      short8v g0 = *(const short8v*)&dgz[ob];
      short8v g1 = *(const short8v*)&dgz[ob + 8];
#pragma unroll
      for (int e = 0; e < 8; ++e){
        o0[e]     = val[e]     * bf2f((ushort_t)g0[e]);
        o0[8 + e] = val[8 + e] * bf2f((ushort_t)g1[e]);
      }
      store16(outA + ob, o0);
    }
  }
  if (do_e){
    __syncthreads();
    if (t < 256) e_part[(size_t)bx * Mrows + m0 + t] = e_lds[t];
  }
}

// ============ dy GEMM (128x128, full K) with fused mse / refine-update epilogue ============
#define DY_STAGE(Asl_, Bsl_, k0_) do { \
  _Pragma("unroll") \
  for (int i_ = 0; i_ < 4; ++i_){ \
    int c_ = i_ * 4 + w; \
    int r_ = c_ * 8 + rsub; \
    load_lds16((const char*)A + ((size_t)(m0 + r_) * K + (k0_)) * 2 + cb, (char*)(Asl_) + c_ * 1024 + lane * 16); \
    load_lds16((const char*)BT + ((size_t)(n0 + r_) * K + (k0_)) * 2 + cb, (char*)(Bsl_) + c_ * 1024 + lane * 16); \
  } } while (0)

#define DY_MFMA(Asl_, Bsl_) do { \
  _Pragma("unroll") \
  for (int kk = 0; kk < 2; ++kk){ \
    int kb = kk * 32 + kg * 8; \
    short8v a[4], b[4]; \
    _Pragma("unroll") \
    for (int m = 0; m < 4; ++m) a[m] = *(const short8v*)&(Asl_)[(wr + m * 16 + fr) * 64 + kb]; \
    _Pragma("unroll") \
    for (int n = 0; n < 4; ++n) b[n] = *(const short8v*)&(Bsl_)[(wc + n * 16 + fr) * 64 + kb]; \
    _Pragma("unroll") \
    for (int m = 0; m < 4; ++m) \
      _Pragma("unroll") \
      for (int n = 0; n < 4; ++n) \
        acc[m][n] = __builtin_amdgcn_mfma_f32_16x16x32_bf16(a[m], b[n], acc[m][n], 0, 0, 0); \
  } } while (0)

__global__ __launch_bounds__(256) void gemm_dy2(
    const ushort_t* __restrict__ A, const ushort_t* __restrict__ BT, int upd,
    float* __restrict__ yneg, ushort_t* __restrict__ feat,
    const float* __restrict__ yhat, const float* __restrict__ y_true,
    const float* __restrict__ sigma_b, double* __restrict__ acc_g){
  __shared__ __align__(16) ushort_t Asl[2][128 * 64];
  __shared__ __align__(16) ushort_t Bsl[2][128 * 64];
  const int K = HDIM;
  const int t = threadIdx.x, lane = t & 63, w = t >> 6;
  int bx = blockIdx.x, by = blockIdx.y;
  xcd_swizzle(gridDim.x, gridDim.y, bx, by);
  const int m0 = by << 7, n0 = bx << 7;
  const int fr = lane & 15, kg = lane >> 4;
  const int rsub = lane >> 3;
  const int cb = (lane & 7) * 16;
  const int wr = (w >> 1) * 64, wc = (w & 1) * 64;

  float4v acc[4][4];
#pragma unroll
  for (int m = 0; m < 4; ++m)
#pragma unroll
    for (int n = 0; n < 4; ++n) acc[m][n] = (float4v)0.f;

  DY_STAGE(Asl[0], Bsl[0], 0);
  __syncthreads();
  int cur = 0;
  for (int k0 = 0; k0 < K; k0 += 64){
    if (k0 + 64 < K) DY_STAGE(Asl[cur ^ 1], Bsl[cur ^ 1], k0 + 64);
    DY_MFMA(Asl[cur], Bsl[cur]);
    __syncthreads();
    cur ^= 1;
  }

  double ms = 0.0;
#pragma unroll
  for (int m = 0; m < 4; ++m){
#pragma unroll
    for (int j = 0; j < 4; ++j){
      int row = m0 + wr + m * 16 + kg * 4 + j;
#pragma unroll
      for (int n = 0; n < 4; ++n){
        int col = n0 + wc + n * 16 + fr;
        if (col < YDIM){
          size_t o = (size_t)row * YDIM + col;
          float g = acc[m][n][j];
          if (upd){
            float y = yneg[o];
            y = clip01(y + 0.15f * g * clipmask(y));
            yneg[o] = y;
            feat[(size_t)row * FEATP + col] = f2bf(y);
          } else {
            float y = yhat[o];
            float score = g * clipmask(y);
            float tgt = (y - y_true[o]) / (sigma_b[row] + 1e-8f);
            float d = score - tgt;
            ms += (double)d * (double)d;
          }
        }
      }
    }
  }
  if (!upd){
    for (int off = 32; off; off >>= 1) ms += __shfl_down(ms, off);
    __shared__ double wsum[4];
    int wid = t >> 6;
    if ((t & 63) == 0) wsum[wid] = ms;
    __syncthreads();
    if (t == 0) atomicAdd(&acc_g[0], (wsum[0] + wsum[1]) + (wsum[2] + wsum[3]));
  }
}

// ---------------- host ----------------
static inline char* carve(char*& p, size_t bytes){
  char* r = p; p += (bytes + 255) & ~(size_t)255; return r;
}

extern "C" void kernel_launch(void* const* d_in, const int* in_sizes, int n_in,
                              void* d_out, int out_size, void* d_ws, size_t ws_size,
                              hipStream_t stream){
  (void)in_sizes; (void)n_in; (void)out_size;
  const float* y_true  = (const float*)d_in[0];
  const float* cond    = (const float*)d_in[1];
  const int*   k_idx   = (const int*)d_in[2];
  const float* eps_pos = (const float*)d_in[3];
  const float* eps_neg = (const float*)d_in[4];
  const float* sel     = (const float*)d_in[5];
  const float* rv      = (const float*)d_in[6];
  const float* W1      = (const float*)d_in[7];
  const float* b1      = (const float*)d_in[8];
  const float* W2      = (const float*)d_in[9];
  const float* b2      = (const float*)d_in[10];
  const float* W3      = (const float*)d_in[11];
  const float* b3      = (const float*)d_in[12];
  const float* k_emb   = (const float*)d_in[13];

  char* p = (char*)d_ws;
  double* accs   = (double*)carve(p, 3 * sizeof(double));
  float* sigma_b = (float*)carve(p, (size_t)B_TOT * 4);
  float* e_pos   = (float*)carve(p, (size_t)B_TOT * 4);
  float* e_neg   = (float*)carve(p, (size_t)B_TOT * 4);
  ushort_t* W1bf = (ushort_t*)carve(p, (size_t)256 * HDIM * 2);   // rows 0..255 of W1 (dy B^T)
  ushort_t* W1T  = (ushort_t*)carve(p, (size_t)HDIM * FEATP * 2);
  ushort_t* W2bf = (ushort_t*)carve(p, (size_t)HDIM * HDIM * 2);
  ushort_t* W2T  = (ushort_t*)carve(p, (size_t)HDIM * HDIM * 2);
  size_t fixed = (size_t)(p - (char*)d_ws);

  // per sample: feat 896 + 3 H-planes (dgz1,h1,dz2) 12288 + e_part 32 + yhat/yneg 2016
  const size_t per_sample = FEATP * 2 + 3 * HDIM * 2 + NPART * 4 + 2 * YDIM * 4;
  int Mc = B_TOT;
  while (Mc > 256 && fixed + (size_t)Mc * per_sample + 65536 > ws_size) Mc >>= 1;

  ushort_t* feat = (ushort_t*)carve(p, (size_t)Mc * FEATP * 2);
  ushort_t* dgz1 = (ushort_t*)carve(p, (size_t)Mc * HDIM * 2);
  ushort_t* h1   = (ushort_t*)carve(p, (size_t)Mc * HDIM * 2);
  ushort_t* dz2  = (ushort_t*)carve(p, (size_t)Mc * HDIM * 2);
  float* e_part  = (float*)carve(p, (size_t)Mc * NPART * 4);
  float* yhat    = (float*)carve(p, (size_t)Mc * YDIM * 4);
  float* yneg    = (float*)carve(p, (size_t)Mc * YDIM * 4);
  ushort_t* dz1  = h1;   // alias: h1 dead once the z2-GEMM consumed it

  dim3 blk(256);
  k_zero_acc<<<1, 1, 0, stream>>>(accs);
  k_sigma<<<(B_TOT + 255) / 256, blk, 0, stream>>>(k_idx, sigma_b);
  k_cast<<<(256 * HDIM + 255) / 256, blk, 0, stream>>>(W1, W1bf, 256 * HDIM);
  k_w1t<<<(HDIM * FEATP + 255) / 256, blk, 0, stream>>>(W1, W1T);
  k_cast<<<(HDIM * HDIM + 255) / 256, blk, 0, stream>>>(W2, W2bf, HDIM * HDIM);
  k_w2t<<<dim3(HDIM / 32, HDIM / 32), blk, 0, stream>>>(W2, W2T);

  auto G = [&](const ushort_t* Ap, const ushort_t* BTp, int K, int mode,
               const float* biasp, ushort_t* oA, ushort_t* oB, float* ep){
    gemm_p<<<dim3(HDIM / 256, Mc / 256), dim3(512), 0, stream>>>(
        Ap, BTp, HDIM, K, mode, biasp, W3, dgz1, oA, oB, ep, Mc);
  };
  auto Gdy = [&](int upd, const float* yh, const float* yt, const float* sg){
    gemm_dy2<<<dim3(2, Mc / 128), blk, 0, stream>>>(
        dz1, W1bf, upd, yneg, feat, yh, yt, sg, accs);
  };

  int nCh = B_TOT / Mc;
  for (int c = 0; c < nCh; ++c){
    int b0 = c * Mc;
    k_feat_static<<<(Mc * 196 + 255) / 256, blk, 0, stream>>>(
        cond + (size_t)b0 * CELLS, k_emb, k_idx + b0, feat, Mc);

    // ---- positive branch
    k_noise<<<(Mc * CELLS + 255) / 256, blk, 0, stream>>>(
        y_true + (size_t)b0 * YDIM, eps_pos + (size_t)b0 * YDIM, sigma_b + b0, yhat, feat, Mc);
    G(feat, W1T, FEATP, 0, b1, dgz1, h1, nullptr);
    G(h1, W2T, HDIM, 1, b2, nullptr, dz2, e_part);
    k_esum<<<(Mc + 255) / 256, blk, 0, stream>>>(e_part, b3, e_pos + b0, Mc);
    G(dz2, W2bf, HDIM, 2, nullptr, dz1, nullptr, nullptr);
    Gdy(0, yhat, y_true + (size_t)b0 * YDIM, sigma_b + b0);

    // ---- negative branch
    k_makeneg<<<(Mc * 64 + 255) / 256, blk, 0, stream>>>(y_true, sel, rv, yneg, feat, b0, Mc);
    for (int r = 0; r < 5; ++r){
      G(feat, W1T, FEATP, 0, b1, dgz1, h1, nullptr);
      G(h1, W2T, HDIM, 1, b2, nullptr, dz2, nullptr);
      G(dz2, W2bf, HDIM, 2, nullptr, dz1, nullptr, nullptr);
      Gdy(1, nullptr, nullptr, nullptr);
    }
    k_noise<<<(Mc * CELLS + 255) / 256, blk, 0, stream>>>(
        yneg, eps_neg + (size_t)b0 * YDIM, sigma_b + b0, yhat, feat, Mc);
    G(feat, W1T, FEATP, 0, b1, dgz1, h1, nullptr);
    G(h1, W2T, HDIM, 1, b2, nullptr, nullptr, e_part);
    k_esum<<<(Mc + 255) / 256, blk, 0, stream>>>(e_part, b3, e_neg + b0, Mc);
  }

  k_contrast<<<64, blk, 0, stream>>>(e_pos, e_neg, accs);
  k_finalize<<<1, 1, 0, stream>>>(accs, (float*)d_out);
}

// Round 11
// 3059.206 us; speedup vs baseline: 1.9490x; 1.1084x over previous
//
#include <hip/hip_runtime.h>
#include <math.h>

#define B_TOT 16384
#define CELLS 36
#define YDIM 252       // 7*6*6
#define FEATP 448      // 416 padded to 448
#define FEAT_REAL 416
#define HDIM 2048
#define EMB_DIM 128
#define KSTEPS 50
#define NPART 8        // e_part slabs = HDIM/256

typedef unsigned short ushort_t;
typedef __attribute__((ext_vector_type(8))) short short8v;
typedef __attribute__((ext_vector_type(4))) float float4v;

__device__ __forceinline__ float clip01(float x){ return fminf(fmaxf(x, 0.f), 1.f); }
__device__ __forceinline__ float tanh_fast(float u){
  float e = __expf(2.f * u);
  return 1.f - 2.f / (e + 1.f);
}
__device__ __forceinline__ float gelu_f(float x){
  float u = 0.7978845608028654f * (x + 0.044715f * x * x * x);
  return 0.5f * x * (1.f + tanh_fast(u));
}
__device__ __forceinline__ float dgelu_f(float x){
  float x2 = x * x;
  float u = 0.7978845608028654f * (x + 0.044715f * x2 * x);
  float t = tanh_fast(u);
  return 0.5f * (1.f + t) + 0.5f * x * (1.f - t * t) * 0.7978845608028654f * (1.f + 0.134145f * x2);
}
__device__ __forceinline__ float clipmask(float y){ return (y == 0.f || y == 1.f) ? 0.5f : 1.f; }
__device__ __forceinline__ ushort_t f2bf(float x){
  union { float f; unsigned u; } v; v.f = x;
  unsigned r = v.u + 0x7fffu + ((v.u >> 16) & 1u);
  return (ushort_t)(r >> 16);
}
__device__ __forceinline__ float bf2f(ushort_t h){
  union { unsigned u; float f; } v; v.u = ((unsigned)h) << 16; return v.f;
}
__device__ __forceinline__ void load_lds16(const void* g, void* l){
  __builtin_amdgcn_global_load_lds((const __attribute__((address_space(1))) unsigned int*)g,
                                   (__attribute__((address_space(3))) unsigned int*)l, 16, 0, 0);
}
__device__ __forceinline__ void store16(ushort_t* dst, const float* x){
  short8v r0, r1;
#pragma unroll
  for (int i = 0; i < 8; ++i){ r0[i] = (short)f2bf(x[i]); r1[i] = (short)f2bf(x[8 + i]); }
  *(short8v*)dst = r0;
  *(short8v*)&dst[8] = r1;
}
// m204 bijective XCD swizzle
__device__ __forceinline__ void xcd_swizzle(int GX, int GY, int& bx, int& by){
  int nwg = GX * GY;
  int orig = by * GX + bx;
  int q = nwg >> 3, r = nwg & 7;
  int xcd = orig & 7, loc = orig >> 3;
  int lin = (xcd < r ? xcd * (q + 1) : r * (q + 1) + (xcd - r) * q) + loc;
  bx = lin % GX; by = lin / GX;
}

// ---------------- small kernels ----------------
__global__ void k_zero_acc(double* acc){ acc[0] = 0.0; acc[1] = 0.0; acc[2] = 0.0; }

__global__ void k_sigma(const int* __restrict__ k_idx, float* __restrict__ sigma_b){
  int b = blockIdx.x * blockDim.x + threadIdx.x;
  if (b >= B_TOT) return;
  int i = (KSTEPS - 1) - k_idx[b];
  float t = (float)i / (float)(KSTEPS - 1);
  float ang = (1.f - t) * 1.57079632679489662f;
  float c = cosf(ang);
  sigma_b[b] = 0.01f + 0.94f * c * c;
}

__global__ void k_cast(const float* __restrict__ in, ushort_t* __restrict__ out, int n){
  int gid = blockIdx.x * blockDim.x + threadIdx.x;
  if (gid < n) out[gid] = f2bf(in[gid]);
}
// W1T[h][f] (f padded to 448)
__global__ void k_w1t(const float* __restrict__ W1, ushort_t* __restrict__ W1T){
  int gid = blockIdx.x * blockDim.x + threadIdx.x;
  if (gid >= HDIM * FEATP) return;
  int h = gid / FEATP, f = gid - h * FEATP;
  W1T[gid] = (f < FEAT_REAL) ? f2bf(W1[(size_t)f * HDIM + h]) : (ushort_t)0;
}
// tiled transpose: W2T[n][k] = W2[k][n]
__global__ __launch_bounds__(256) void k_w2t(const float* __restrict__ W2, ushort_t* __restrict__ W2T){
  __shared__ float tile[32][33];
  int x0 = blockIdx.x << 5, y0 = blockIdx.y << 5;
  int tx = threadIdx.x & 31, ty = threadIdx.x >> 5;
#pragma unroll
  for (int i = 0; i < 4; ++i)
    tile[ty + i * 8][tx] = W2[(size_t)(y0 + ty + i * 8) * HDIM + (x0 + tx)];
  __syncthreads();
#pragma unroll
  for (int i = 0; i < 4; ++i)
    W2T[(size_t)(x0 + ty + i * 8) * HDIM + (y0 + tx)] = f2bf(tile[tx][ty + i * 8]);
}

// static cols of feat: 252..447 (cond, emb, zero pad)
__global__ void k_feat_static(const float* __restrict__ cond, const float* __restrict__ k_emb,
                              const int* __restrict__ k_idx, ushort_t* __restrict__ feat, int Mc){
  int gid = blockIdx.x * blockDim.x + threadIdx.x;
  if (gid >= Mc * 196) return;
  int i = gid / 196, c = gid - i * 196;
  float v;
  if (c < CELLS)            v = cond[(size_t)i * CELLS + c];
  else if (c < CELLS + EMB_DIM) v = k_emb[(size_t)k_idx[i] * EMB_DIM + (c - CELLS)];
  else                      v = 0.f;
  feat[(size_t)i * FEATP + YDIM + c] = f2bf(v);
}

// noise + direct feat write
__global__ void k_noise(const float* __restrict__ y, const float* __restrict__ eps,
                        const float* __restrict__ sigma_b, float* __restrict__ out,
                        ushort_t* __restrict__ feat, int Mc){
  int gid = blockIdx.x * blockDim.x + threadIdx.x;
  if (gid >= Mc * CELLS) return;
  int i = gid / CELLS, cell = gid - i * CELLS;
  float sigma = sigma_b[i];
  float sq = sqrtf(fmaxf(1.f - sigma * sigma, 1e-8f));
  const float* yp = y + (size_t)i * YDIM + cell;
  const float* ep = eps + (size_t)i * YDIM + cell;
  float yh[7];
#pragma unroll
  for (int ch = 0; ch < 7; ++ch){
    float e = ep[ch * CELLS] * 0.1f;
    yh[ch] = clip01(sq * yp[ch * CELLS] + sigma * e);
  }
  bool filled = yh[0] > 0.5f;
  float s = 0.f;
#pragma unroll
  for (int ch = 1; ch < 7; ++ch) s += yh[ch];
  float* op = out + (size_t)i * YDIM + cell;
  ushort_t* fp = feat + (size_t)i * FEATP + cell;
  op[0] = yh[0];
  fp[0] = f2bf(yh[0]);
#pragma unroll
  for (int ch = 1; ch < 7; ++ch){
    float v = yh[ch];
    if (filled) v = v / (s + 1e-8f);
    v = clip01(v);
    op[ch * CELLS] = v;
    fp[ch * CELLS] = f2bf(v);
  }
}

// y_neg init + feat write
__global__ void k_makeneg(const float* __restrict__ y_true, const float* __restrict__ sel,
                          const float* __restrict__ rv, float* __restrict__ y_neg,
                          ushort_t* __restrict__ feat, int b0, int Mc){
  int w = (blockIdx.x * blockDim.x + threadIdx.x) >> 6;
  int lane = threadIdx.x & 63;
  if (w >= Mc) return;
  int b = b0 + w;
  int c = lane;
  bool active = c < CELLS;
  float yt0 = active ? y_true[(size_t)b * YDIM + c] : 0.f;
  bool filled = active && (yt0 > 0.5f);
  unsigned long long bal = __ballot(filled);
  int n_filled = __popcll(bal);
  int num_c = (int)floorf((float)n_filled * 0.3f);
  int idx = num_c - 1; if (idx < 0) idx = 0;
  float score = filled ? sel[(size_t)b * CELLS + c] : 2.0f;
  int cnt_lt = 0, cnt_le = 0;
  for (int l = 0; l < CELLS; ++l){
    float sv = __shfl(score, l);
    cnt_lt += (sv < score);
    cnt_le += (sv <= score);
  }
  float cand = (active && cnt_lt <= idx && idx < cnt_le) ? score : 3.4e38f;
  for (int off = 32; off; off >>= 1) cand = fminf(cand, __shfl_xor(cand, off));
  float thr = (num_c > 0) ? cand : -1.0f;
  bool corrupt = filled && (score <= thr);
  if (active){
    float rvv[6]; float rsum = 0.f;
#pragma unroll
    for (int ch = 0; ch < 6; ++ch){ rvv[ch] = rv[(size_t)b * (6 * CELLS) + ch * CELLS + c]; rsum += rvv[ch]; }
    float v0 = corrupt ? 0.f : yt0;
    y_neg[(size_t)w * YDIM + c] = v0;
    feat[(size_t)w * FEATP + c] = f2bf(clip01(v0));
#pragma unroll
    for (int ch = 0; ch < 6; ++ch){
      float val = corrupt ? rvv[ch] / rsum : y_true[(size_t)b * YDIM + (ch + 1) * CELLS + c];
      y_neg[(size_t)w * YDIM + (ch + 1) * CELLS + c] = val;
      feat[(size_t)w * FEATP + (ch + 1) * CELLS + c] = f2bf(clip01(val));
    }
  }
}

// e[i] = b3 + sum_x e_part[x][i]
__global__ void k_esum(const float* __restrict__ e_part, const float* __restrict__ b3,
                       float* __restrict__ e_out, int Mc){
  int i = blockIdx.x * blockDim.x + threadIdx.x;
  if (i >= Mc) return;
  float s = b3[0];
#pragma unroll
  for (int x = 0; x < NPART; ++x) s += e_part[(size_t)x * Mc + i];
  e_out[i] = s;
}

// refine update from 4 split-K partials; also refresh feat
__global__ void k_upd(const float* __restrict__ part, float* __restrict__ yneg,
                      ushort_t* __restrict__ feat, int Mc){
  int gid = blockIdx.x * blockDim.x + threadIdx.x;
  int total = Mc * YDIM;
  if (gid >= total) return;
  int i = gid / YDIM, c = gid - i * YDIM;
  float g = ((part[gid] + part[(size_t)total + gid]) +
             (part[2 * (size_t)total + gid] + part[3 * (size_t)total + gid]));
  float y = yneg[gid];
  y = clip01(y + 0.15f * g * clipmask(y));
  yneg[gid] = y;
  feat[(size_t)i * FEATP + c] = f2bf(y);
}

// mse: grid-stride, block-reduce, 1 atomic per block
__global__ __launch_bounds__(256) void k_mse(const float* __restrict__ part, const float* __restrict__ yhat,
                      const float* __restrict__ y_true, const float* __restrict__ sigma_b,
                      double* __restrict__ acc, int Mc){
  int total = Mc * YDIM;
  double v = 0.0;
  for (int gid = blockIdx.x * blockDim.x + threadIdx.x; gid < total; gid += gridDim.x * blockDim.x){
    int i = gid / YDIM;
    float y = yhat[gid];
    float dy = ((part[gid] + part[(size_t)total + gid]) +
                (part[2 * (size_t)total + gid] + part[3 * (size_t)total + gid]));
    float score = dy * clipmask(y);
    float sigma = sigma_b[i];
    float tgt = (y - y_true[gid]) / (sigma + 1e-8f);
    float d = score - tgt;
    v += (double)d * (double)d;
  }
  for (int off = 32; off; off >>= 1) v += __shfl_down(v, off);
  __shared__ double wsum[4];
  int lane = threadIdx.x & 63, wid = threadIdx.x >> 6;
  if (lane == 0) wsum[wid] = v;
  __syncthreads();
  if (threadIdx.x == 0) atomicAdd(&acc[0], (wsum[0] + wsum[1]) + (wsum[2] + wsum[3]));
}

__global__ __launch_bounds__(256) void k_contrast(const float* __restrict__ e_pos, const float* __restrict__ e_neg,
                           double* __restrict__ acc){
  double con = 0.0, reg = 0.0;
  for (int b = blockIdx.x * blockDim.x + threadIdx.x; b < B_TOT; b += gridDim.x * blockDim.x){
    float ep = e_pos[b], en = e_neg[b];
    float a = -ep, bb = -en;
    float m = fmaxf(a, bb);
    float lse = m + logf(expf(a - m) + expf(bb - m));
    con += (double)(ep + lse);
    reg += (double)ep + (double)en;
  }
  for (int off = 32; off; off >>= 1){ con += __shfl_down(con, off); reg += __shfl_down(reg, off); }
  __shared__ double wc[4], wr[4];
  int lane = threadIdx.x & 63, wid = threadIdx.x >> 6;
  if (lane == 0){ wc[wid] = con; wr[wid] = reg; }
  __syncthreads();
  if (threadIdx.x == 0){
    atomicAdd(&acc[1], (wc[0] + wc[1]) + (wc[2] + wc[3]));
    atomicAdd(&acc[2], (wr[0] + wr[1]) + (wr[2] + wr[3]));
  }
}

__global__ void k_finalize(const double* __restrict__ acc, float* __restrict__ out){
  double mse = acc[0] / (double)((long long)B_TOT * YDIM);
  double con = acc[1] / (double)B_TOT;
  double reg = acc[2] / (double)B_TOT;
  out[0] = (float)(mse + con + 0.01 * reg);
}

// ============ 8-phase GEMM (m201 template, x2-unrolled static parity) ============
// BM=BN=256, K-step 64, 4 phases/K-step, 512 thr = 8 waves (2M x 4N), wave 128x64.
// LDS 2x(A[256][64]+B[256][64]) = 128 KiB. Rows 128B = 8 slots; slot s of row r holds
// k-chunk (s-r)&7; read slot (chunk+fr)&7 (conflict-free, inverse on global source).
// K-loop unrolled x2 so LDS buffer parity is COMPILE-TIME: ds_read offsets fold to
// immediates (runtime Al[s&1] was materializing per-iteration address VALU — R10's
// VALUBusy 38%). Schedule identical to R10: ph0 stage B1(t+1), ph1 A1(t+1),
// ph3 A0+B0(t+2) into cur parity + boundary vmcnt(4).
#define STG_H(srcPtr, p0, buf, k0, h) \
  _Pragma("unroll") \
  for (int ro_ = 0; ro_ < 2; ++ro_){ \
    int r_ = (ro_ << 7) + ((h) << 6) + (t >> 3); \
    int c_ = ((t & 7) - r_) & 7; \
    load_lds16((const char*)(srcPtr) + (((size_t)((p0) + r_)) * K + (k0) + (c_ << 3)) * 2, \
               (char*)(buf) + (r_ << 7) + ((t & 7) << 4)); \
  }

// one K-step with compile-time cur/next buffers
#define K_STEP(SV, CA_, CB_, NA_, NB_) do { \
  const int s_ = (SV); \
  const int kn1_ = (s_ + 1) << 6, kn2_ = (s_ + 2) << 6; \
  short8v af[4], bf[4]; \
  /* ph0: (mh0,kk0); stage B1(s+1) */ \
  _Pragma("unroll") \
  for (int n = 0; n < 4; ++n) bf[n] = *(const short8v*)((const char*)(CB_) + brow + (n << 11) + aslot0); \
  _Pragma("unroll") \
  for (int m = 0; m < 4; ++m) af[m] = *(const short8v*)((const char*)(CA_) + arow + (m << 11) + aslot0); \
  if (s_ + 1 < NT){ STG_H(BT, n0, (NB_), kn1_, 1); } \
  __builtin_amdgcn_s_barrier(); \
  asm volatile("s_waitcnt lgkmcnt(0)" ::: "memory"); \
  __builtin_amdgcn_s_setprio(1); \
  _Pragma("unroll") \
  for (int m = 0; m < 4; ++m) \
    _Pragma("unroll") \
    for (int n = 0; n < 4; ++n) \
      acc[m][n] = __builtin_amdgcn_mfma_f32_16x16x32_bf16(af[m], bf[n], acc[m][n], 0, 0, 0); \
  __builtin_amdgcn_s_setprio(0); \
  __builtin_amdgcn_s_barrier(); \
  /* ph1: (mh1,kk0); stage A1(s+1) */ \
  _Pragma("unroll") \
  for (int m = 0; m < 4; ++m) af[m] = *(const short8v*)((const char*)(CA_) + arow + ((m + 4) << 11) + aslot0); \
  if (s_ + 1 < NT){ STG_H(A, m0, (NA_), kn1_, 1); } \
  __builtin_amdgcn_s_barrier(); \
  asm volatile("s_waitcnt lgkmcnt(0)" ::: "memory"); \
  __builtin_amdgcn_s_setprio(1); \
  _Pragma("unroll") \
  for (int m = 0; m < 4; ++m) \
    _Pragma("unroll") \
    for (int n = 0; n < 4; ++n) \
      acc[m + 4][n] = __builtin_amdgcn_mfma_f32_16x16x32_bf16(af[m], bf[n], acc[m + 4][n], 0, 0, 0); \
  __builtin_amdgcn_s_setprio(0); \
  __builtin_amdgcn_s_barrier(); \
  /* ph2: (mh0,kk1) */ \
  _Pragma("unroll") \
  for (int n = 0; n < 4; ++n) bf[n] = *(const short8v*)((const char*)(CB_) + brow + (n << 11) + aslot1); \
  _Pragma("unroll") \
  for (int m = 0; m < 4; ++m) af[m] = *(const short8v*)((const char*)(CA_) + arow + (m << 11) + aslot1); \
  __builtin_amdgcn_s_barrier(); \
  asm volatile("s_waitcnt lgkmcnt(0)" ::: "memory"); \
  __builtin_amdgcn_s_setprio(1); \
  _Pragma("unroll") \
  for (int m = 0; m < 4; ++m) \
    _Pragma("unroll") \
    for (int n = 0; n < 4; ++n) \
      acc[m][n] = __builtin_amdgcn_mfma_f32_16x16x32_bf16(af[m], bf[n], acc[m][n], 0, 0, 0); \
  __builtin_amdgcn_s_setprio(0); \
  __builtin_amdgcn_s_barrier(); \
  /* ph3: (mh1,kk1); stage A0+B0(s+2) into cur parity */ \
  _Pragma("unroll") \
  for (int m = 0; m < 4; ++m) af[m] = *(const short8v*)((const char*)(CA_) + arow + ((m + 4) << 11) + aslot1); \
  if (s_ + 2 < NT){ STG_H(A, m0, (CA_), kn2_, 0); STG_H(BT, n0, (CB_), kn2_, 0); } \
  __builtin_amdgcn_s_barrier(); \
  asm volatile("s_waitcnt lgkmcnt(0)" ::: "memory"); \
  __builtin_amdgcn_s_setprio(1); \
  _Pragma("unroll") \
  for (int m = 0; m < 4; ++m) \
    _Pragma("unroll") \
    for (int n = 0; n < 4; ++n) \
      acc[m + 4][n] = __builtin_amdgcn_mfma_f32_16x16x32_bf16(af[m], bf[n], acc[m + 4][n], 0, 0, 0); \
  __builtin_amdgcn_s_setprio(0); \
  if (s_ + 1 < NT){ \
    if (s_ + 2 < NT) asm volatile("s_waitcnt vmcnt(4)" ::: "memory"); \
    else             asm volatile("s_waitcnt vmcnt(0)" ::: "memory"); \
  } \
  __builtin_amdgcn_s_barrier(); \
} while (0)

__global__ __launch_bounds__(512, 1) void gemm_p(
    const ushort_t* __restrict__ A, const ushort_t* __restrict__ BT,
    int N, int K, int mode,
    const float* __restrict__ bias, const float* __restrict__ W3,
    const ushort_t* __restrict__ dgz,
    ushort_t* __restrict__ outA, ushort_t* __restrict__ outB,
    float* __restrict__ e_part, int Mrows){
  __shared__ __align__(16) ushort_t Al[2][256 * 64];
  __shared__ __align__(16) ushort_t Bl[2][256 * 64];
  const int t = threadIdx.x, lane = t & 63, w = t >> 6;
  int bx = blockIdx.x, by = blockIdx.y;
  xcd_swizzle(gridDim.x, gridDim.y, bx, by);
  const int m0 = by << 8, n0 = bx << 8;
  const int fr = lane & 15, kg = lane >> 4;
  const int wm = w >> 2, wn = w & 3;
  const int NT = K >> 6;
  const int wr = wm << 7, wc = wn << 6;
  const int aslot0 = ((kg + fr) & 7) << 4;        // kk=0: chunk=kg
  const int aslot1 = ((4 + kg + fr) & 7) << 4;    // kk=1: chunk=4+kg
  const int arow = ((wm << 7) + fr) << 7;
  const int brow = ((wn << 6) + fr) << 7;

  float4v acc[8][4];
#pragma unroll
  for (int m = 0; m < 8; ++m)
#pragma unroll
    for (int n = 0; n < 4; ++n) acc[m][n] = (float4v)0.f;

  // prologue: K-step 0 fully, then A0(1),B0(1)
  STG_H(A, m0, &Al[0][0], 0, 0); STG_H(A, m0, &Al[0][0], 0, 1);
  STG_H(BT, n0, &Bl[0][0], 0, 0); STG_H(BT, n0, &Bl[0][0], 0, 1);
  if (NT > 1){ STG_H(A, m0, &Al[1][0], 64, 0); STG_H(BT, n0, &Bl[1][0], 64, 0); }
  if (NT > 1) asm volatile("s_waitcnt vmcnt(4)" ::: "memory");
  else        asm volatile("s_waitcnt vmcnt(0)" ::: "memory");
  __builtin_amdgcn_s_barrier();

  for (int s2 = 0; s2 + 1 < NT; s2 += 2){
    K_STEP(s2,     &Al[0][0], &Bl[0][0], &Al[1][0], &Bl[1][0]);
    K_STEP(s2 + 1, &Al[1][0], &Bl[1][0], &Al[0][0], &Bl[0][0]);
  }
  if (NT & 1) K_STEP(NT - 1, &Al[0][0], &Bl[0][0], &Al[1][0], &Bl[1][0]);

  // ---- epilogue: per-wave f32 LDS slice -> coalesced 16B bf16 stores ----
  float* slice = (float*)&Al[0][0] + w * (16 * 68);
  float* e_lds = (float*)&Bl[0][0];
  const bool do_e = (mode == 1) && (e_part != nullptr);
  if (do_e){
    if (t < 256) e_lds[t] = 0.f;
    __syncthreads();
  }
  const int rrow = lane >> 2;      // 0..15
  const int rq = lane & 3;         // 16-col group
#pragma unroll
  for (int m = 0; m < 8; ++m){
    if (m) asm volatile("s_waitcnt lgkmcnt(0)" ::: "memory");  // prior reads done before overwrite
#pragma unroll
    for (int j = 0; j < 4; ++j)
#pragma unroll
      for (int n = 0; n < 4; ++n)
        slice[((kg << 2) + j) * 68 + (n << 4) + fr] = acc[m][n][j];
    asm volatile("s_waitcnt lgkmcnt(0)" ::: "memory");
    const int grow = m0 + wr + (m << 4) + rrow;
    const int gcol = n0 + wc + (rq << 4);
    float val[16];
#pragma unroll
    for (int p2 = 0; p2 < 4; ++p2){
      float4 vv = *(const float4*)&slice[rrow * 68 + (rq << 4) + (p2 << 2)];
      val[p2 * 4 + 0] = vv.x; val[p2 * 4 + 1] = vv.y;
      val[p2 * 4 + 2] = vv.z; val[p2 * 4 + 3] = vv.w;
    }
    const size_t ob = (size_t)grow * N + gcol;
    if (mode == 0){
      float o0[16], o1[16];
#pragma unroll
      for (int e = 0; e < 16; ++e){
        float z = val[e] + bias[gcol + e];
        o0[e] = dgelu_f(z);
        o1[e] = gelu_f(z);
      }
      store16(outA + ob, o0);
      store16(outB + ob, o1);
    } else if (mode == 1){
      float pe = 0.f;
      float o0[16];
#pragma unroll
      for (int e = 0; e < 16; ++e){
        float z = val[e] + bias[gcol + e];
        float w3 = W3[gcol + e];
        o0[e] = w3 * dgelu_f(z);
        if (do_e) pe += gelu_f(z) * w3;
      }
      if (outB) store16(outB + ob, o0);
      if (do_e){
        pe += __shfl_xor(pe, 1);
        pe += __shfl_xor(pe, 2);
        if (rq == 0) atomicAdd(&e_lds[wr + (m << 4) + rrow], pe);
      }
    } else {
      float o0[16];
      short8v g0 = *(const short8v*)&dgz[ob];
      short8v g1 = *(const short8v*)&dgz[ob + 8];
#pragma unroll
      for (int e = 0; e < 8; ++e){
        o0[e]     = val[e]     * bf2f((ushort_t)g0[e]);
        o0[8 + e] = val[8 + e] * bf2f((ushort_t)g1[e]);
      }
      store16(outA + ob, o0);
    }
  }
  if (do_e){
    __syncthreads();
    if (t < 256) e_part[(size_t)bx * Mrows + m0 + t] = e_lds[t];
  }
}

// ============ dy GEMM: 128x128 tile, split-K x4 (grid 2 x Mc/128 x 4 = 512 blocks,
// ============ ~2 blocks/CU vs old full-K 256-block kernel's 1 wave/SIMD) ============
#define DY_STAGE(Asl_, Bsl_, k0_) do { \
  _Pragma("unroll") \
  for (int i_ = 0; i_ < 4; ++i_){ \
    int c_ = i_ * 4 + w; \
    int r_ = c_ * 8 + rsub; \
    load_lds16((const char*)A + ((size_t)(m0 + r_) * K + (k0_)) * 2 + cb, (char*)(Asl_) + c_ * 1024 + lane * 16); \
    load_lds16((const char*)BT + ((size_t)(n0 + r_) * K + (k0_)) * 2 + cb, (char*)(Bsl_) + c_ * 1024 + lane * 16); \
  } } while (0)

#define DY_MFMA(Asl_, Bsl_) do { \
  _Pragma("unroll") \
  for (int kk = 0; kk < 2; ++kk){ \
    int kb = kk * 32 + kg * 8; \
    short8v a[4], b[4]; \
    _Pragma("unroll") \
    for (int m = 0; m < 4; ++m) a[m] = *(const short8v*)&(Asl_)[(wr + m * 16 + fr) * 64 + kb]; \
    _Pragma("unroll") \
    for (int n = 0; n < 4; ++n) b[n] = *(const short8v*)&(Bsl_)[(wc + n * 16 + fr) * 64 + kb]; \
    _Pragma("unroll") \
    for (int m = 0; m < 4; ++m) \
      _Pragma("unroll") \
      for (int n = 0; n < 4; ++n) \
        acc[m][n] = __builtin_amdgcn_mfma_f32_16x16x32_bf16(a[m], b[n], acc[m][n], 0, 0, 0); \
  } } while (0)

__global__ __launch_bounds__(256) void gemm_dy4(
    const ushort_t* __restrict__ A, const ushort_t* __restrict__ BT,
    float* __restrict__ part, int Mc){
  __shared__ __align__(16) ushort_t Asl[2][128 * 64];
  __shared__ __align__(16) ushort_t Bsl[2][128 * 64];
  const int K = HDIM;
  const int t = threadIdx.x, lane = t & 63, w = t >> 6;
  int bx = blockIdx.x, by = blockIdx.y;
  xcd_swizzle(gridDim.x, gridDim.y, bx, by);
  const int m0 = by << 7, n0 = bx << 7;
  const int ks = blockIdx.z;
  const int kbeg = ks << 9, kend = kbeg + 512;
  const int fr = lane & 15, kg = lane >> 4;
  const int rsub = lane >> 3;
  const int cb = (lane & 7) * 16;
  const int wr = (w >> 1) * 64, wc = (w & 1) * 64;

  float4v acc[4][4];
#pragma unroll
  for (int m = 0; m < 4; ++m)
#pragma unroll
    for (int n = 0; n < 4; ++n) acc[m][n] = (float4v)0.f;

  DY_STAGE(Asl[0], Bsl[0], kbeg);
  __syncthreads();
  int cur = 0;
  for (int k0 = kbeg; k0 < kend; k0 += 64){
    if (k0 + 64 < kend) DY_STAGE(Asl[cur ^ 1], Bsl[cur ^ 1], k0 + 64);
    DY_MFMA(Asl[cur], Bsl[cur]);
    __syncthreads();
    cur ^= 1;
  }

  float* pp = part + (size_t)ks * Mc * YDIM;
#pragma unroll
  for (int m = 0; m < 4; ++m){
#pragma unroll
    for (int j = 0; j < 4; ++j){
      int row = m0 + wr + m * 16 + kg * 4 + j;
#pragma unroll
      for (int n = 0; n < 4; ++n){
        int col = n0 + wc + n * 16 + fr;
        if (col < YDIM) pp[(size_t)row * YDIM + col] = acc[m][n][j];
      }
    }
  }
}

// ---------------- host ----------------
static inline char* carve(char*& p, size_t bytes){
  char* r = p; p += (bytes + 255) & ~(size_t)255; return r;
}

extern "C" void kernel_launch(void* const* d_in, const int* in_sizes, int n_in,
                              void* d_out, int out_size, void* d_ws, size_t ws_size,
                              hipStream_t stream){
  (void)in_sizes; (void)n_in; (void)out_size;
  const float* y_true  = (const float*)d_in[0];
  const float* cond    = (const float*)d_in[1];
  const int*   k_idx   = (const int*)d_in[2];
  const float* eps_pos = (const float*)d_in[3];
  const float* eps_neg = (const float*)d_in[4];
  const float* sel     = (const float*)d_in[5];
  const float* rv      = (const float*)d_in[6];
  const float* W1      = (const float*)d_in[7];
  const float* b1      = (const float*)d_in[8];
  const float* W2      = (const float*)d_in[9];
  const float* b2      = (const float*)d_in[10];
  const float* W3      = (const float*)d_in[11];
  const float* b3      = (const float*)d_in[12];
  const float* k_emb   = (const float*)d_in[13];

  char* p = (char*)d_ws;
  double* accs   = (double*)carve(p, 3 * sizeof(double));
  float* sigma_b = (float*)carve(p, (size_t)B_TOT * 4);
  float* e_pos   = (float*)carve(p, (size_t)B_TOT * 4);
  float* e_neg   = (float*)carve(p, (size_t)B_TOT * 4);
  ushort_t* W1bf = (ushort_t*)carve(p, (size_t)256 * HDIM * 2);   // rows 0..255 of W1 (dy B^T)
  ushort_t* W1T  = (ushort_t*)carve(p, (size_t)HDIM * FEATP * 2);
  ushort_t* W2bf = (ushort_t*)carve(p, (size_t)HDIM * HDIM * 2);
  ushort_t* W2T  = (ushort_t*)carve(p, (size_t)HDIM * HDIM * 2);
  size_t fixed = (size_t)(p - (char*)d_ws);

  // per sample: feat 896 + 3 H-planes (dgz1,h1,dz2) 12288 + e_part 32 + yhat/yneg 2016
  // dy partials (4 x 252 f32 = 4032 B) alias dgz1 (dead after the dz1-GEMM read it).
  const size_t per_sample = FEATP * 2 + 3 * HDIM * 2 + NPART * 4 + 2 * YDIM * 4;
  int Mc = B_TOT;
  while (Mc > 256 && fixed + (size_t)Mc * per_sample + 65536 > ws_size) Mc >>= 1;

  ushort_t* feat = (ushort_t*)carve(p, (size_t)Mc * FEATP * 2);
  ushort_t* dgz1 = (ushort_t*)carve(p, (size_t)Mc * HDIM * 2);
  ushort_t* h1   = (ushort_t*)carve(p, (size_t)Mc * HDIM * 2);
  ushort_t* dz2  = (ushort_t*)carve(p, (size_t)Mc * HDIM * 2);
  float* e_part  = (float*)carve(p, (size_t)Mc * NPART * 4);
  float* yhat    = (float*)carve(p, (size_t)Mc * YDIM * 4);
  float* yneg    = (float*)carve(p, (size_t)Mc * YDIM * 4);
  ushort_t* dz1  = h1;          // alias: h1 dead once the z2-GEMM consumed it
  float* part    = (float*)dgz1; // alias: dgz1 dead once the dz1-GEMM consumed it

  dim3 blk(256);
  k_zero_acc<<<1, 1, 0, stream>>>(accs);
  k_sigma<<<(B_TOT + 255) / 256, blk, 0, stream>>>(k_idx, sigma_b);
  k_cast<<<(256 * HDIM + 255) / 256, blk, 0, stream>>>(W1, W1bf, 256 * HDIM);
  k_w1t<<<(HDIM * FEATP + 255) / 256, blk, 0, stream>>>(W1, W1T);
  k_cast<<<(HDIM * HDIM + 255) / 256, blk, 0, stream>>>(W2, W2bf, HDIM * HDIM);
  k_w2t<<<dim3(HDIM / 32, HDIM / 32), blk, 0, stream>>>(W2, W2T);

  auto G = [&](const ushort_t* Ap, const ushort_t* BTp, int K, int mode,
               const float* biasp, ushort_t* oA, ushort_t* oB, float* ep){
    gemm_p<<<dim3(HDIM / 256, Mc / 256), dim3(512), 0, stream>>>(
        Ap, BTp, HDIM, K, mode, biasp, W3, dgz1, oA, oB, ep, Mc);
  };
  auto Gdy = [&](){
    gemm_dy4<<<dim3(2, Mc / 128, 4), blk, 0, stream>>>(dz1, W1bf, part, Mc);
  };

  int nCh = B_TOT / Mc;
  for (int c = 0; c < nCh; ++c){
    int b0 = c * Mc;
    k_feat_static<<<(Mc * 196 + 255) / 256, blk, 0, stream>>>(
        cond + (size_t)b0 * CELLS, k_emb, k_idx + b0, feat, Mc);

    // ---- positive branch
    k_noise<<<(Mc * CELLS + 255) / 256, blk, 0, stream>>>(
        y_true + (size_t)b0 * YDIM, eps_pos + (size_t)b0 * YDIM, sigma_b + b0, yhat, feat, Mc);
    G(feat, W1T, FEATP, 0, b1, dgz1, h1, nullptr);
    G(h1, W2T, HDIM, 1, b2, nullptr, dz2, e_part);
    k_esum<<<(Mc + 255) / 256, blk, 0, stream>>>(e_part, b3, e_pos + b0, Mc);
    G(dz2, W2bf, HDIM, 2, nullptr, dz1, nullptr, nullptr);
    Gdy();
    k_mse<<<512, blk, 0, stream>>>(part, yhat, y_true + (size_t)b0 * YDIM, sigma_b + b0, accs, Mc);

    // ---- negative branch
    k_makeneg<<<(Mc * 64 + 255) / 256, blk, 0, stream>>>(y_true, sel, rv, yneg, feat, b0, Mc);
    for (int r = 0; r < 5; ++r){
      G(feat, W1T, FEATP, 0, b1, dgz1, h1, nullptr);
      G(h1, W2T, HDIM, 1, b2, nullptr, dz2, nullptr);
      G(dz2, W2bf, HDIM, 2, nullptr, dz1, nullptr, nullptr);
      Gdy();
      k_upd<<<(Mc * YDIM + 255) / 256, blk, 0, stream>>>(part, yneg, feat, Mc);
    }
    k_noise<<<(Mc * CELLS + 255) / 256, blk, 0, stream>>>(
        yneg, eps_neg + (size_t)b0 * YDIM, sigma_b + b0, yhat, feat, Mc);
    G(feat, W1T, FEATP, 0, b1, dgz1, h1, nullptr);
    G(h1, W2T, HDIM, 1, b2, nullptr, nullptr, e_part);
    k_esum<<<(Mc + 255) / 256, blk, 0, stream>>>(e_part, b3, e_neg + b0, Mc);
  }

  k_contrast<<<64, blk, 0, stream>>>(e_pos, e_neg, accs);
  k_finalize<<<1, 1, 0, stream>>>(accs, (float*)d_out);
}

// Round 12
// 2886.422 us; speedup vs baseline: 2.0657x; 1.0599x over previous
//
#include <hip/hip_runtime.h>
#include <math.h>

#define B_TOT 16384
#define CELLS 36
#define YDIM 252       // 7*6*6
#define FEATP 448      // 416 padded to 448
#define FEAT_REAL 416
#define HDIM 2048
#define EMB_DIM 128
#define KSTEPS 50
#define NPART 8        // e_part slabs = HDIM/256

typedef unsigned short ushort_t;
typedef __attribute__((ext_vector_type(8))) short short8v;
typedef __attribute__((ext_vector_type(4))) float float4v;

__device__ __forceinline__ float clip01(float x){ return fminf(fmaxf(x, 0.f), 1.f); }
__device__ __forceinline__ float tanh_fast(float u){
  float e = __expf(2.f * u);
  return 1.f - 2.f / (e + 1.f);
}
__device__ __forceinline__ float gelu_f(float x){
  float u = 0.7978845608028654f * (x + 0.044715f * x * x * x);
  return 0.5f * x * (1.f + tanh_fast(u));
}
__device__ __forceinline__ float dgelu_f(float x){
  float x2 = x * x;
  float u = 0.7978845608028654f * (x + 0.044715f * x2 * x);
  float t = tanh_fast(u);
  return 0.5f * (1.f + t) + 0.5f * x * (1.f - t * t) * 0.7978845608028654f * (1.f + 0.134145f * x2);
}
__device__ __forceinline__ float clipmask(float y){ return (y == 0.f || y == 1.f) ? 0.5f : 1.f; }
__device__ __forceinline__ ushort_t f2bf(float x){
  union { float f; unsigned u; } v; v.f = x;
  unsigned r = v.u + 0x7fffu + ((v.u >> 16) & 1u);
  return (ushort_t)(r >> 16);
}
__device__ __forceinline__ float bf2f(ushort_t h){
  union { unsigned u; float f; } v; v.u = ((unsigned)h) << 16; return v.f;
}
__device__ __forceinline__ void load_lds16(const void* g, void* l){
  __builtin_amdgcn_global_load_lds((const __attribute__((address_space(1))) unsigned int*)g,
                                   (__attribute__((address_space(3))) unsigned int*)l, 16, 0, 0);
}
__device__ __forceinline__ void store16(ushort_t* dst, const float* x){
  short8v r0, r1;
#pragma unroll
  for (int i = 0; i < 8; ++i){ r0[i] = (short)f2bf(x[i]); r1[i] = (short)f2bf(x[8 + i]); }
  *(short8v*)dst = r0;
  *(short8v*)&dst[8] = r1;
}
// m204 bijective XCD swizzle
__device__ __forceinline__ void xcd_swizzle(int GX, int GY, int& bx, int& by){
  int nwg = GX * GY;
  int orig = by * GX + bx;
  int q = nwg >> 3, r = nwg & 7;
  int xcd = orig & 7, loc = orig >> 3;
  int lin = (xcd < r ? xcd * (q + 1) : r * (q + 1) + (xcd - r) * q) + loc;
  bx = lin % GX; by = lin / GX;
}

// ---------------- small kernels ----------------
__global__ void k_zero_acc(double* acc){ acc[0] = 0.0; acc[1] = 0.0; acc[2] = 0.0; }

__global__ void k_sigma(const int* __restrict__ k_idx, float* __restrict__ sigma_b){
  int b = blockIdx.x * blockDim.x + threadIdx.x;
  if (b >= B_TOT) return;
  int i = (KSTEPS - 1) - k_idx[b];
  float t = (float)i / (float)(KSTEPS - 1);
  float ang = (1.f - t) * 1.57079632679489662f;
  float c = cosf(ang);
  sigma_b[b] = 0.01f + 0.94f * c * c;
}

__global__ void k_cast(const float* __restrict__ in, ushort_t* __restrict__ out, int n){
  int gid = blockIdx.x * blockDim.x + threadIdx.x;
  if (gid < n) out[gid] = f2bf(in[gid]);
}
// W1T[h][f] (f padded to 448)
__global__ void k_w1t(const float* __restrict__ W1, ushort_t* __restrict__ W1T){
  int gid = blockIdx.x * blockDim.x + threadIdx.x;
  if (gid >= HDIM * FEATP) return;
  int h = gid / FEATP, f = gid - h * FEATP;
  W1T[gid] = (f < FEAT_REAL) ? f2bf(W1[(size_t)f * HDIM + h]) : (ushort_t)0;
}
// tiled transpose: W2T[n][k] = W2[k][n]
__global__ __launch_bounds__(256) void k_w2t(const float* __restrict__ W2, ushort_t* __restrict__ W2T){
  __shared__ float tile[32][33];
  int x0 = blockIdx.x << 5, y0 = blockIdx.y << 5;
  int tx = threadIdx.x & 31, ty = threadIdx.x >> 5;
#pragma unroll
  for (int i = 0; i < 4; ++i)
    tile[ty + i * 8][tx] = W2[(size_t)(y0 + ty + i * 8) * HDIM + (x0 + tx)];
  __syncthreads();
#pragma unroll
  for (int i = 0; i < 4; ++i)
    W2T[(size_t)(x0 + ty + i * 8) * HDIM + (y0 + tx)] = f2bf(tile[tx][ty + i * 8]);
}

// static cols of feat: 252..447 (cond, emb, zero pad)
__global__ void k_feat_static(const float* __restrict__ cond, const float* __restrict__ k_emb,
                              const int* __restrict__ k_idx, ushort_t* __restrict__ feat, int Mc){
  int gid = blockIdx.x * blockDim.x + threadIdx.x;
  if (gid >= Mc * 196) return;
  int i = gid / 196, c = gid - i * 196;
  float v;
  if (c < CELLS)            v = cond[(size_t)i * CELLS + c];
  else if (c < CELLS + EMB_DIM) v = k_emb[(size_t)k_idx[i] * EMB_DIM + (c - CELLS)];
  else                      v = 0.f;
  feat[(size_t)i * FEATP + YDIM + c] = f2bf(v);
}

// noise + direct feat write
__global__ void k_noise(const float* __restrict__ y, const float* __restrict__ eps,
                        const float* __restrict__ sigma_b, float* __restrict__ out,
                        ushort_t* __restrict__ feat, int Mc){
  int gid = blockIdx.x * blockDim.x + threadIdx.x;
  if (gid >= Mc * CELLS) return;
  int i = gid / CELLS, cell = gid - i * CELLS;
  float sigma = sigma_b[i];
  float sq = sqrtf(fmaxf(1.f - sigma * sigma, 1e-8f));
  const float* yp = y + (size_t)i * YDIM + cell;
  const float* ep = eps + (size_t)i * YDIM + cell;
  float yh[7];
#pragma unroll
  for (int ch = 0; ch < 7; ++ch){
    float e = ep[ch * CELLS] * 0.1f;
    yh[ch] = clip01(sq * yp[ch * CELLS] + sigma * e);
  }
  bool filled = yh[0] > 0.5f;
  float s = 0.f;
#pragma unroll
  for (int ch = 1; ch < 7; ++ch) s += yh[ch];
  float* op = out + (size_t)i * YDIM + cell;
  ushort_t* fp = feat + (size_t)i * FEATP + cell;
  op[0] = yh[0];
  fp[0] = f2bf(yh[0]);
#pragma unroll
  for (int ch = 1; ch < 7; ++ch){
    float v = yh[ch];
    if (filled) v = v / (s + 1e-8f);
    v = clip01(v);
    op[ch * CELLS] = v;
    fp[ch * CELLS] = f2bf(v);
  }
}

// y_neg init + feat write
__global__ void k_makeneg(const float* __restrict__ y_true, const float* __restrict__ sel,
                          const float* __restrict__ rv, float* __restrict__ y_neg,
                          ushort_t* __restrict__ feat, int b0, int Mc){
  int w = (blockIdx.x * blockDim.x + threadIdx.x) >> 6;
  int lane = threadIdx.x & 63;
  if (w >= Mc) return;
  int b = b0 + w;
  int c = lane;
  bool active = c < CELLS;
  float yt0 = active ? y_true[(size_t)b * YDIM + c] : 0.f;
  bool filled = active && (yt0 > 0.5f);
  unsigned long long bal = __ballot(filled);
  int n_filled = __popcll(bal);
  int num_c = (int)floorf((float)n_filled * 0.3f);
  int idx = num_c - 1; if (idx < 0) idx = 0;
  float score = filled ? sel[(size_t)b * CELLS + c] : 2.0f;
  int cnt_lt = 0, cnt_le = 0;
  for (int l = 0; l < CELLS; ++l){
    float sv = __shfl(score, l);
    cnt_lt += (sv < score);
    cnt_le += (sv <= score);
  }
  float cand = (active && cnt_lt <= idx && idx < cnt_le) ? score : 3.4e38f;
  for (int off = 32; off; off >>= 1) cand = fminf(cand, __shfl_xor(cand, off));
  float thr = (num_c > 0) ? cand : -1.0f;
  bool corrupt = filled && (score <= thr);
  if (active){
    float rvv[6]; float rsum = 0.f;
#pragma unroll
    for (int ch = 0; ch < 6; ++ch){ rvv[ch] = rv[(size_t)b * (6 * CELLS) + ch * CELLS + c]; rsum += rvv[ch]; }
    float v0 = corrupt ? 0.f : yt0;
    y_neg[(size_t)w * YDIM + c] = v0;
    feat[(size_t)w * FEATP + c] = f2bf(clip01(v0));
#pragma unroll
    for (int ch = 0; ch < 6; ++ch){
      float val = corrupt ? rvv[ch] / rsum : y_true[(size_t)b * YDIM + (ch + 1) * CELLS + c];
      y_neg[(size_t)w * YDIM + (ch + 1) * CELLS + c] = val;
      feat[(size_t)w * FEATP + (ch + 1) * CELLS + c] = f2bf(clip01(val));
    }
  }
}

// e[i] = b3 + sum_x e_part[x][i]
__global__ void k_esum(const float* __restrict__ e_part, const float* __restrict__ b3,
                       float* __restrict__ e_out, int Mc){
  int i = blockIdx.x * blockDim.x + threadIdx.x;
  if (i >= Mc) return;
  float s = b3[0];
#pragma unroll
  for (int x = 0; x < NPART; ++x) s += e_part[(size_t)x * Mc + i];
  e_out[i] = s;
}

// refine update from 4 split-K partials; also refresh feat
__global__ void k_upd(const float* __restrict__ part, float* __restrict__ yneg,
                      ushort_t* __restrict__ feat, int Mc){
  int gid = blockIdx.x * blockDim.x + threadIdx.x;
  int total = Mc * YDIM;
  if (gid >= total) return;
  int i = gid / YDIM, c = gid - i * YDIM;
  float g = ((part[gid] + part[(size_t)total + gid]) +
             (part[2 * (size_t)total + gid] + part[3 * (size_t)total + gid]));
  float y = yneg[gid];
  y = clip01(y + 0.15f * g * clipmask(y));
  yneg[gid] = y;
  feat[(size_t)i * FEATP + c] = f2bf(y);
}

// mse: grid-stride, block-reduce, 1 atomic per block
__global__ __launch_bounds__(256) void k_mse(const float* __restrict__ part, const float* __restrict__ yhat,
                      const float* __restrict__ y_true, const float* __restrict__ sigma_b,
                      double* __restrict__ acc, int Mc){
  int total = Mc * YDIM;
  double v = 0.0;
  for (int gid = blockIdx.x * blockDim.x + threadIdx.x; gid < total; gid += gridDim.x * blockDim.x){
    int i = gid / YDIM;
    float y = yhat[gid];
    float dy = ((part[gid] + part[(size_t)total + gid]) +
                (part[2 * (size_t)total + gid] + part[3 * (size_t)total + gid]));
    float score = dy * clipmask(y);
    float sigma = sigma_b[i];
    float tgt = (y - y_true[gid]) / (sigma + 1e-8f);
    float d = score - tgt;
    v += (double)d * (double)d;
  }
  for (int off = 32; off; off >>= 1) v += __shfl_down(v, off);
  __shared__ double wsum[4];
  int lane = threadIdx.x & 63, wid = threadIdx.x >> 6;
  if (lane == 0) wsum[wid] = v;
  __syncthreads();
  if (threadIdx.x == 0) atomicAdd(&acc[0], (wsum[0] + wsum[1]) + (wsum[2] + wsum[3]));
}

__global__ __launch_bounds__(256) void k_contrast(const float* __restrict__ e_pos, const float* __restrict__ e_neg,
                           double* __restrict__ acc){
  double con = 0.0, reg = 0.0;
  for (int b = blockIdx.x * blockDim.x + threadIdx.x; b < B_TOT; b += gridDim.x * blockDim.x){
    float ep = e_pos[b], en = e_neg[b];
    float a = -ep, bb = -en;
    float m = fmaxf(a, bb);
    float lse = m + logf(expf(a - m) + expf(bb - m));
    con += (double)(ep + lse);
    reg += (double)ep + (double)en;
  }
  for (int off = 32; off; off >>= 1){ con += __shfl_down(con, off); reg += __shfl_down(reg, off); }
  __shared__ double wc[4], wr[4];
  int lane = threadIdx.x & 63, wid = threadIdx.x >> 6;
  if (lane == 0){ wc[wid] = con; wr[wid] = reg; }
  __syncthreads();
  if (threadIdx.x == 0){
    atomicAdd(&acc[1], (wc[0] + wc[1]) + (wc[2] + wc[3]));
    atomicAdd(&acc[2], (wr[0] + wr[1]) + (wr[2] + wr[3]));
  }
}

__global__ void k_finalize(const double* __restrict__ acc, float* __restrict__ out){
  double mse = acc[0] / (double)((long long)B_TOT * YDIM);
  double con = acc[1] / (double)B_TOT;
  double reg = acc[2] / (double)B_TOT;
  out[0] = (float)(mse + con + 0.01 * reg);
}

// ============ 8-phase GEMM, barrier-minimal (2 barriers/K-step) ============
// BM=BN=256, K-step 64, 512 thr = 8 waves (2M x 4N), wave tile 128x64.
// LDS 2x(A[256][64]+B[256][64]) = 128 KiB; x2-unrolled compile-time parity.
// Rows 128B = 8 slots; slot s of row r holds k-chunk (s-r)&7; read slot (chunk+fr)&7.
// WAR analysis: only TWO barriers are required per K-step:
//  (a) end-of-ph2 — every wave's reads of cur A0/B0 are complete (each MFMA's issue
//      implies its ds_reads finished), so ph3 may stage A0/B0(t+2) into cur;
//  (b) end-of-ph3 + boundary vmcnt — gates step t+1's reads on staged data.
// ph0-ph2 free-run per wave; the compiler's fine-grained lgkmcnt(N) schedules
// reads against MFMAs (m97). lgkmcnt(0) before each kept barrier = motion fence.
// Stage plan: ph0 -> B1(t+1), ph1 -> A1(t+1), ph3 -> A0(t+2)+B0(t+2) into cur.
// modes: 0 z1: z=v+b1 -> outA=dgz1=bf(dgelu z), outB=h1=bf(gelu z)
//        1 z2: z=v+b2 -> outB?=dz2=bf(W3*dgelu z); e_part?=row sums gelu(z)*W3
//        2 dz1: v *= bf2f(dgz[o]); outA
#define STG_H(srcPtr, p0, buf, k0, h) \
  _Pragma("unroll") \
  for (int ro_ = 0; ro_ < 2; ++ro_){ \
    int r_ = (ro_ << 7) + ((h) << 6) + (t >> 3); \
    int c_ = ((t & 7) - r_) & 7; \
    load_lds16((const char*)(srcPtr) + (((size_t)((p0) + r_)) * K + (k0) + (c_ << 3)) * 2, \
               (char*)(buf) + (r_ << 7) + ((t & 7) << 4)); \
  }

// one K-step with compile-time cur/next buffers, 2 barriers
#define K_STEP(SV, CA_, CB_, NA_, NB_) do { \
  const int s_ = (SV); \
  const int kn1_ = (s_ + 1) << 6, kn2_ = (s_ + 2) << 6; \
  short8v afa[4], afb[4], afc[4], afd[4], bf0[4], bf1[4]; \
  /* ph0: (mh0,kk0); stage B1(s+1) */ \
  _Pragma("unroll") \
  for (int n = 0; n < 4; ++n) bf0[n] = *(const short8v*)((const char*)(CB_) + brow + (n << 11) + aslot0); \
  _Pragma("unroll") \
  for (int m = 0; m < 4; ++m) afa[m] = *(const short8v*)((const char*)(CA_) + arow + (m << 11) + aslot0); \
  if (s_ + 1 < NT){ STG_H(BT, n0, (NB_), kn1_, 1); } \
  __builtin_amdgcn_s_setprio(1); \
  _Pragma("unroll") \
  for (int m = 0; m < 4; ++m) \
    _Pragma("unroll") \
    for (int n = 0; n < 4; ++n) \
      acc[m][n] = __builtin_amdgcn_mfma_f32_16x16x32_bf16(afa[m], bf0[n], acc[m][n], 0, 0, 0); \
  __builtin_amdgcn_s_setprio(0); \
  /* ph1: (mh1,kk0); stage A1(s+1) */ \
  _Pragma("unroll") \
  for (int m = 0; m < 4; ++m) afb[m] = *(const short8v*)((const char*)(CA_) + arow + ((m + 4) << 11) + aslot0); \
  if (s_ + 1 < NT){ STG_H(A, m0, (NA_), kn1_, 1); } \
  __builtin_amdgcn_s_setprio(1); \
  _Pragma("unroll") \
  for (int m = 0; m < 4; ++m) \
    _Pragma("unroll") \
    for (int n = 0; n < 4; ++n) \
      acc[m + 4][n] = __builtin_amdgcn_mfma_f32_16x16x32_bf16(afb[m], bf0[n], acc[m + 4][n], 0, 0, 0); \
  __builtin_amdgcn_s_setprio(0); \
  /* ph2: (mh0,kk1) */ \
  _Pragma("unroll") \
  for (int n = 0; n < 4; ++n) bf1[n] = *(const short8v*)((const char*)(CB_) + brow + (n << 11) + aslot1); \
  _Pragma("unroll") \
  for (int m = 0; m < 4; ++m) afc[m] = *(const short8v*)((const char*)(CA_) + arow + (m << 11) + aslot1); \
  __builtin_amdgcn_s_setprio(1); \
  _Pragma("unroll") \
  for (int m = 0; m < 4; ++m) \
    _Pragma("unroll") \
    for (int n = 0; n < 4; ++n) \
      acc[m][n] = __builtin_amdgcn_mfma_f32_16x16x32_bf16(afc[m], bf1[n], acc[m][n], 0, 0, 0); \
  __builtin_amdgcn_s_setprio(0); \
  asm volatile("s_waitcnt lgkmcnt(0)" ::: "memory"); \
  __builtin_amdgcn_s_barrier();   /* (a) release cur A0/B0 for overwrite */ \
  /* ph3: (mh1,kk1); stage A0+B0(s+2) into cur parity */ \
  _Pragma("unroll") \
  for (int m = 0; m < 4; ++m) afd[m] = *(const short8v*)((const char*)(CA_) + arow + ((m + 4) << 11) + aslot1); \
  if (s_ + 2 < NT){ STG_H(A, m0, (CA_), kn2_, 0); STG_H(BT, n0, (CB_), kn2_, 0); } \
  __builtin_amdgcn_s_setprio(1); \
  _Pragma("unroll") \
  for (int m = 0; m < 4; ++m) \
    _Pragma("unroll") \
    for (int n = 0; n < 4; ++n) \
      acc[m + 4][n] = __builtin_amdgcn_mfma_f32_16x16x32_bf16(afd[m], bf1[n], acc[m + 4][n], 0, 0, 0); \
  __builtin_amdgcn_s_setprio(0); \
  asm volatile("s_waitcnt lgkmcnt(0)" ::: "memory"); \
  if (s_ + 1 < NT){ \
    if (s_ + 2 < NT) asm volatile("s_waitcnt vmcnt(4)" ::: "memory"); \
    else             asm volatile("s_waitcnt vmcnt(0)" ::: "memory"); \
  } \
  __builtin_amdgcn_s_barrier();   /* (b) K-step boundary */ \
} while (0)

__global__ __launch_bounds__(512, 1) void gemm_p(
    const ushort_t* __restrict__ A, const ushort_t* __restrict__ BT,
    int N, int K, int mode,
    const float* __restrict__ bias, const float* __restrict__ W3,
    const ushort_t* __restrict__ dgz,
    ushort_t* __restrict__ outA, ushort_t* __restrict__ outB,
    float* __restrict__ e_part, int Mrows){
  __shared__ __align__(16) ushort_t Al[2][256 * 64];
  __shared__ __align__(16) ushort_t Bl[2][256 * 64];
  const int t = threadIdx.x, lane = t & 63, w = t >> 6;
  int bx = blockIdx.x, by = blockIdx.y;
  xcd_swizzle(gridDim.x, gridDim.y, bx, by);
  const int m0 = by << 8, n0 = bx << 8;
  const int fr = lane & 15, kg = lane >> 4;
  const int wm = w >> 2, wn = w & 3;
  const int NT = K >> 6;
  const int wr = wm << 7, wc = wn << 6;
  const int aslot0 = ((kg + fr) & 7) << 4;        // kk=0: chunk=kg
  const int aslot1 = ((4 + kg + fr) & 7) << 4;    // kk=1: chunk=4+kg
  const int arow = ((wm << 7) + fr) << 7;
  const int brow = ((wn << 6) + fr) << 7;

  float4v acc[8][4];
#pragma unroll
  for (int m = 0; m < 8; ++m)
#pragma unroll
    for (int n = 0; n < 4; ++n) acc[m][n] = (float4v)0.f;

  // prologue: K-step 0 fully, then A0(1),B0(1)
  STG_H(A, m0, &Al[0][0], 0, 0); STG_H(A, m0, &Al[0][0], 0, 1);
  STG_H(BT, n0, &Bl[0][0], 0, 0); STG_H(BT, n0, &Bl[0][0], 0, 1);
  if (NT > 1){ STG_H(A, m0, &Al[1][0], 64, 0); STG_H(BT, n0, &Bl[1][0], 64, 0); }
  if (NT > 1) asm volatile("s_waitcnt vmcnt(4)" ::: "memory");
  else        asm volatile("s_waitcnt vmcnt(0)" ::: "memory");
  __builtin_amdgcn_s_barrier();

  for (int s2 = 0; s2 + 1 < NT; s2 += 2){
    K_STEP(s2,     &Al[0][0], &Bl[0][0], &Al[1][0], &Bl[1][0]);
    K_STEP(s2 + 1, &Al[1][0], &Bl[1][0], &Al[0][0], &Bl[0][0]);
  }
  if (NT & 1) K_STEP(NT - 1, &Al[0][0], &Bl[0][0], &Al[1][0], &Bl[1][0]);

  // ---- epilogue: per-wave f32 LDS slice -> coalesced 16B bf16 stores ----
  float* slice = (float*)&Al[0][0] + w * (16 * 68);
  float* e_lds = (float*)&Bl[0][0];
  const bool do_e = (mode == 1) && (e_part != nullptr);
  if (do_e){
    if (t < 256) e_lds[t] = 0.f;
    __syncthreads();
  }
  const int rrow = lane >> 2;      // 0..15
  const int rq = lane & 3;         // 16-col group
#pragma unroll
  for (int m = 0; m < 8; ++m){
    if (m) asm volatile("s_waitcnt lgkmcnt(0)" ::: "memory");  // prior reads done before overwrite
#pragma unroll
    for (int j = 0; j < 4; ++j)
#pragma unroll
      for (int n = 0; n < 4; ++n)
        slice[((kg << 2) + j) * 68 + (n << 4) + fr] = acc[m][n][j];
    asm volatile("s_waitcnt lgkmcnt(0)" ::: "memory");
    const int grow = m0 + wr + (m << 4) + rrow;
    const int gcol = n0 + wc + (rq << 4);
    float val[16];
#pragma unroll
    for (int p2 = 0; p2 < 4; ++p2){
      float4 vv = *(const float4*)&slice[rrow * 68 + (rq << 4) + (p2 << 2)];
      val[p2 * 4 + 0] = vv.x; val[p2 * 4 + 1] = vv.y;
      val[p2 * 4 + 2] = vv.z; val[p2 * 4 + 3] = vv.w;
    }
    const size_t ob = (size_t)grow * N + gcol;
    if (mode == 0){
      float o0[16], o1[16];
#pragma unroll
      for (int e = 0; e < 16; ++e){
        float z = val[e] + bias[gcol + e];
        o0[e] = dgelu_f(z);
        o1[e] = gelu_f(z);
      }
      store16(outA + ob, o0);
      store16(outB + ob, o1);
    } else if (mode == 1){
      float pe = 0.f;
      float o0[16];
#pragma unroll
      for (int e = 0; e < 16; ++e){
        float z = val[e] + bias[gcol + e];
        float w3 = W3[gcol + e];
        o0[e] = w3 * dgelu_f(z);
        if (do_e) pe += gelu_f(z) * w3;
      }
      if (outB) store16(outB + ob, o0);
      if (do_e){
        pe += __shfl_xor(pe, 1);
        pe += __shfl_xor(pe, 2);
        if (rq == 0) atomicAdd(&e_lds[wr + (m << 4) + rrow], pe);
      }
    } else {
      float o0[16];
      short8v g0 = *(const short8v*)&dgz[ob];
      short8v g1 = *(const short8v*)&dgz[ob + 8];
#pragma unroll
      for (int e = 0; e < 8; ++e){
        o0[e]     = val[e]     * bf2f((ushort_t)g0[e]);
        o0[8 + e] = val[8 + e] * bf2f((ushort_t)g1[e]);
      }
      store16(outA + ob, o0);
    }
  }
  if (do_e){
    __syncthreads();
    if (t < 256) e_part[(size_t)bx * Mrows + m0 + t] = e_lds[t];
  }
}

// ============ dy GEMM: 128x128 tile, split-K x4 ============
#define DY_STAGE(Asl_, Bsl_, k0_) do { \
  _Pragma("unroll") \
  for (int i_ = 0; i_ < 4; ++i_){ \
    int c_ = i_ * 4 + w; \
    int r_ = c_ * 8 + rsub; \
    load_lds16((const char*)A + ((size_t)(m0 + r_) * K + (k0_)) * 2 + cb, (char*)(Asl_) + c_ * 1024 + lane * 16); \
    load_lds16((const char*)BT + ((size_t)(n0 + r_) * K + (k0_)) * 2 + cb, (char*)(Bsl_) + c_ * 1024 + lane * 16); \
  } } while (0)

#define DY_MFMA(Asl_, Bsl_) do { \
  _Pragma("unroll") \
  for (int kk = 0; kk < 2; ++kk){ \
    int kb = kk * 32 + kg * 8; \
    short8v a[4], b[4]; \
    _Pragma("unroll") \
    for (int m = 0; m < 4; ++m) a[m] = *(const short8v*)&(Asl_)[(wr + m * 16 + fr) * 64 + kb]; \
    _Pragma("unroll") \
    for (int n = 0; n < 4; ++n) b[n] = *(const short8v*)&(Bsl_)[(wc + n * 16 + fr) * 64 + kb]; \
    _Pragma("unroll") \
    for (int m = 0; m < 4; ++m) \
      _Pragma("unroll") \
      for (int n = 0; n < 4; ++n) \
        acc[m][n] = __builtin_amdgcn_mfma_f32_16x16x32_bf16(a[m], b[n], acc[m][n], 0, 0, 0); \
  } } while (0)

__global__ __launch_bounds__(256) void gemm_dy4(
    const ushort_t* __restrict__ A, const ushort_t* __restrict__ BT,
    float* __restrict__ part, int Mc){
  __shared__ __align__(16) ushort_t Asl[2][128 * 64];
  __shared__ __align__(16) ushort_t Bsl[2][128 * 64];
  const int K = HDIM;
  const int t = threadIdx.x, lane = t & 63, w = t >> 6;
  int bx = blockIdx.x, by = blockIdx.y;
  xcd_swizzle(gridDim.x, gridDim.y, bx, by);
  const int m0 = by << 7, n0 = bx << 7;
  const int ks = blockIdx.z;
  const int kbeg = ks << 9, kend = kbeg + 512;
  const int fr = lane & 15, kg = lane >> 4;
  const int rsub = lane >> 3;
  const int cb = (lane & 7) * 16;
  const int wr = (w >> 1) * 64, wc = (w & 1) * 64;

  float4v acc[4][4];
#pragma unroll
  for (int m = 0; m < 4; ++m)
#pragma unroll
    for (int n = 0; n < 4; ++n) acc[m][n] = (float4v)0.f;

  DY_STAGE(Asl[0], Bsl[0], kbeg);
  __syncthreads();
  int cur = 0;
  for (int k0 = kbeg; k0 < kend; k0 += 64){
    if (k0 + 64 < kend) DY_STAGE(Asl[cur ^ 1], Bsl[cur ^ 1], k0 + 64);
    DY_MFMA(Asl[cur], Bsl[cur]);
    __syncthreads();
    cur ^= 1;
  }

  float* pp = part + (size_t)ks * Mc * YDIM;
#pragma unroll
  for (int m = 0; m < 4; ++m){
#pragma unroll
    for (int j = 0; j < 4; ++j){
      int row = m0 + wr + m * 16 + kg * 4 + j;
#pragma unroll
      for (int n = 0; n < 4; ++n){
        int col = n0 + wc + n * 16 + fr;
        if (col < YDIM) pp[(size_t)row * YDIM + col] = acc[m][n][j];
      }
    }
  }
}

// ---------------- host ----------------
static inline char* carve(char*& p, size_t bytes){
  char* r = p; p += (bytes + 255) & ~(size_t)255; return r;
}

extern "C" void kernel_launch(void* const* d_in, const int* in_sizes, int n_in,
                              void* d_out, int out_size, void* d_ws, size_t ws_size,
                              hipStream_t stream){
  (void)in_sizes; (void)n_in; (void)out_size;
  const float* y_true  = (const float*)d_in[0];
  const float* cond    = (const float*)d_in[1];
  const int*   k_idx   = (const int*)d_in[2];
  const float* eps_pos = (const float*)d_in[3];
  const float* eps_neg = (const float*)d_in[4];
  const float* sel     = (const float*)d_in[5];
  const float* rv      = (const float*)d_in[6];
  const float* W1      = (const float*)d_in[7];
  const float* b1      = (const float*)d_in[8];
  const float* W2      = (const float*)d_in[9];
  const float* b2      = (const float*)d_in[10];
  const float* W3      = (const float*)d_in[11];
  const float* b3      = (const float*)d_in[12];
  const float* k_emb   = (const float*)d_in[13];

  char* p = (char*)d_ws;
  double* accs   = (double*)carve(p, 3 * sizeof(double));
  float* sigma_b = (float*)carve(p, (size_t)B_TOT * 4);
  float* e_pos   = (float*)carve(p, (size_t)B_TOT * 4);
  float* e_neg   = (float*)carve(p, (size_t)B_TOT * 4);
  ushort_t* W1bf = (ushort_t*)carve(p, (size_t)256 * HDIM * 2);   // rows 0..255 of W1 (dy B^T)
  ushort_t* W1T  = (ushort_t*)carve(p, (size_t)HDIM * FEATP * 2);
  ushort_t* W2bf = (ushort_t*)carve(p, (size_t)HDIM * HDIM * 2);
  ushort_t* W2T  = (ushort_t*)carve(p, (size_t)HDIM * HDIM * 2);
  size_t fixed = (size_t)(p - (char*)d_ws);

  // per sample: feat 896 + 3 H-planes (dgz1,h1,dz2) 12288 + e_part 32 + yhat/yneg 2016
  // dy partials (4 x 252 f32 = 4032 B) alias dgz1 (dead after the dz1-GEMM read it).
  const size_t per_sample = FEATP * 2 + 3 * HDIM * 2 + NPART * 4 + 2 * YDIM * 4;
  int Mc = B_TOT;
  while (Mc > 256 && fixed + (size_t)Mc * per_sample + 65536 > ws_size) Mc >>= 1;

  ushort_t* feat = (ushort_t*)carve(p, (size_t)Mc * FEATP * 2);
  ushort_t* dgz1 = (ushort_t*)carve(p, (size_t)Mc * HDIM * 2);
  ushort_t* h1   = (ushort_t*)carve(p, (size_t)Mc * HDIM * 2);
  ushort_t* dz2  = (ushort_t*)carve(p, (size_t)Mc * HDIM * 2);
  float* e_part  = (float*)carve(p, (size_t)Mc * NPART * 4);
  float* yhat    = (float*)carve(p, (size_t)Mc * YDIM * 4);
  float* yneg    = (float*)carve(p, (size_t)Mc * YDIM * 4);
  ushort_t* dz1  = h1;          // alias: h1 dead once the z2-GEMM consumed it
  float* part    = (float*)dgz1; // alias: dgz1 dead once the dz1-GEMM consumed it

  dim3 blk(256);
  k_zero_acc<<<1, 1, 0, stream>>>(accs);
  k_sigma<<<(B_TOT + 255) / 256, blk, 0, stream>>>(k_idx, sigma_b);
  k_cast<<<(256 * HDIM + 255) / 256, blk, 0, stream>>>(W1, W1bf, 256 * HDIM);
  k_w1t<<<(HDIM * FEATP + 255) / 256, blk, 0, stream>>>(W1, W1T);
  k_cast<<<(HDIM * HDIM + 255) / 256, blk, 0, stream>>>(W2, W2bf, HDIM * HDIM);
  k_w2t<<<dim3(HDIM / 32, HDIM / 32), blk, 0, stream>>>(W2, W2T);

  auto G = [&](const ushort_t* Ap, const ushort_t* BTp, int K, int mode,
               const float* biasp, ushort_t* oA, ushort_t* oB, float* ep){
    gemm_p<<<dim3(HDIM / 256, Mc / 256), dim3(512), 0, stream>>>(
        Ap, BTp, HDIM, K, mode, biasp, W3, dgz1, oA, oB, ep, Mc);
  };
  auto Gdy = [&](){
    gemm_dy4<<<dim3(2, Mc / 128, 4), blk, 0, stream>>>(dz1, W1bf, part, Mc);
  };

  int nCh = B_TOT / Mc;
  for (int c = 0; c < nCh; ++c){
    int b0 = c * Mc;
    k_feat_static<<<(Mc * 196 + 255) / 256, blk, 0, stream>>>(
        cond + (size_t)b0 * CELLS, k_emb, k_idx + b0, feat, Mc);

    // ---- positive branch
    k_noise<<<(Mc * CELLS + 255) / 256, blk, 0, stream>>>(
        y_true + (size_t)b0 * YDIM, eps_pos + (size_t)b0 * YDIM, sigma_b + b0, yhat, feat, Mc);
    G(feat, W1T, FEATP, 0, b1, dgz1, h1, nullptr);
    G(h1, W2T, HDIM, 1, b2, nullptr, dz2, e_part);
    k_esum<<<(Mc + 255) / 256, blk, 0, stream>>>(e_part, b3, e_pos + b0, Mc);
    G(dz2, W2bf, HDIM, 2, nullptr, dz1, nullptr, nullptr);
    Gdy();
    k_mse<<<512, blk, 0, stream>>>(part, yhat, y_true + (size_t)b0 * YDIM, sigma_b + b0, accs, Mc);

    // ---- negative branch
    k_makeneg<<<(Mc * 64 + 255) / 256, blk, 0, stream>>>(y_true, sel, rv, yneg, feat, b0, Mc);
    for (int r = 0; r < 5; ++r){
      G(feat, W1T, FEATP, 0, b1, dgz1, h1, nullptr);
      G(h1, W2T, HDIM, 1, b2, nullptr, dz2, nullptr);
      G(dz2, W2bf, HDIM, 2, nullptr, dz1, nullptr, nullptr);
      Gdy();
      k_upd<<<(Mc * YDIM + 255) / 256, blk, 0, stream>>>(part, yneg, feat, Mc);
    }
    k_noise<<<(Mc * CELLS + 255) / 256, blk, 0, stream>>>(
        yneg, eps_neg + (size_t)b0 * YDIM, sigma_b + b0, yhat, feat, Mc);
    G(feat, W1T, FEATP, 0, b1, dgz1, h1, nullptr);
    G(h1, W2T, HDIM, 1, b2, nullptr, nullptr, e_part);
    k_esum<<<(Mc + 255) / 256, blk, 0, stream>>>(e_part, b3, e_neg + b0, Mc);
  }

  k_contrast<<<64, blk, 0, stream>>>(e_pos, e_neg, accs);
  k_finalize<<<1, 1, 0, stream>>>(accs, (float*)d_out);
}